// Round 7
// baseline (1229.867 us; speedup 1.0000x reference)
//
#include <hip/hip_runtime.h>
#include <hip/hip_bf16.h>
#include <cstdint>
#include <cstddef>

typedef __hip_bfloat16 bf16;
typedef short v8s __attribute__((ext_vector_type(8)));
typedef float v4f __attribute__((ext_vector_type(4)));
typedef unsigned short v8u __attribute__((ext_vector_type(8)));
typedef unsigned short v4u __attribute__((ext_vector_type(4)));
typedef unsigned short v2u __attribute__((ext_vector_type(2)));

#define N_NODES 50000
#define N_HE    5000
#define N_EDGE  800000
#define N_INC   400000

__device__ inline float bfh(uint32_t u) { return __uint_as_float(u << 16); }
__device__ inline uint16_t rne16(float f) {
  uint32_t u = __float_as_uint(f);
  return (uint16_t)((u + 0x7FFFu + ((u >> 16) & 1u)) >> 16);
}

// ---------------------------------------------------------------- CSR build
__global__ void zero3_kernel(int* a, int na, int* b, int nb, int* c, int nc) {
  int total = na + nb + nc;
  for (int i = blockIdx.x * blockDim.x + threadIdx.x; i < total;
       i += gridDim.x * blockDim.x) {
    if (i < na) a[i] = 0;
    else if (i < na + nb) b[i - na] = 0;
    else c[i - na - nb] = 0;
  }
}

__global__ void hist_kernel(const int* __restrict__ dst,
                            const int* __restrict__ he_node,
                            const int* __restrict__ he_edge,
                            int* cnt_dst, int* cnt_he, int* cnt_hn) {
  int i = blockIdx.x * blockDim.x + threadIdx.x;
  if (i < N_EDGE) atomicAdd(&cnt_dst[dst[i]], 1);
  if (i < N_INC) {
    atomicAdd(&cnt_he[he_edge[i]], 1);
    atomicAdd(&cnt_hn[he_node[i]], 1);
  }
}

__global__ void scales_kernel(const int* cnt_dst, const int* cnt_hn,
                              const int* cnt_he,
                              float* deg_inv, float* dinv, float* binv) {
  int i = blockIdx.x * blockDim.x + threadIdx.x;
  if (i < N_NODES) {
    int d = cnt_dst[i];
    deg_inv[i] = 1.0f / (float)(d > 1 ? d : 1);
    int h = cnt_hn[i];
    dinv[i] = h > 0 ? 1.0f / (float)h : 0.0f;
  }
  if (i < N_HE) {
    int e = cnt_he[i];
    binv[i] = e > 0 ? 1.0f / (float)e : 0.0f;
  }
}

__global__ void scan3_kernel(const int* cnt_dst, int* adj_off, int* adj_cur,
                             const int* cnt_he, int* heg_off, int* heg_cur,
                             const int* cnt_hn, int* hng_off, int* hng_cur) {
  const int* cnt; int* off; int* cur; int n;
  if (blockIdx.x == 0)      { cnt = cnt_dst; off = adj_off; cur = adj_cur; n = N_NODES; }
  else if (blockIdx.x == 1) { cnt = cnt_he;  off = heg_off; cur = heg_cur; n = N_HE; }
  else                      { cnt = cnt_hn;  off = hng_off; cur = hng_cur; n = N_NODES; }
  __shared__ int buf[1024];
  int t = threadIdx.x;
  int carry = 0;
  for (int base = 0; base < n; base += 1024) {
    int i = base + t;
    int v = (i < n) ? cnt[i] : 0;
    buf[t] = v;
    __syncthreads();
    for (int d = 1; d < 1024; d <<= 1) {
      int x = (t >= d) ? buf[t - d] : 0;
      __syncthreads();
      buf[t] += x;
      __syncthreads();
    }
    int excl = buf[t] - v;
    if (i < n) { off[i] = carry + excl; cur[i] = carry + excl; }
    int total = buf[1023];
    __syncthreads();
    carry += total;
  }
  if (t == 0) off[n] = carry;
}

__global__ void fill_kernel(const int* __restrict__ src, const int* __restrict__ dst,
                            const int* __restrict__ he_node, const int* __restrict__ he_edge,
                            int* adj_cur, uint16_t* adj_src,
                            int* heg_cur, uint16_t* heg_node,
                            int* hng_cur, uint16_t* hng_edge) {
  int i = blockIdx.x * blockDim.x + threadIdx.x;
  if (i < N_EDGE) {
    int p = atomicAdd(&adj_cur[dst[i]], 1);
    adj_src[p] = (uint16_t)src[i];
  }
  if (i < N_INC) {
    int p = atomicAdd(&heg_cur[he_edge[i]], 1);
    heg_node[p] = (uint16_t)he_node[i];
    int p2 = atomicAdd(&hng_cur[he_node[i]], 1);
    hng_edge[p2] = (uint16_t)he_edge[i];
  }
}

// ---------------------------------------------------- weight hi/lo bf16 split
#define W_TOTAL 456704
__global__ void split_w_kernel(const float* s0wl, const float* s0wr,
                               const float* s1wl, const float* s1wr,
                               const float* s2wl, const float* s2wr,
                               const float* h0w, const float* h1w,
                               const float* h2w, const float* h3w,
                               const float* h4w,
                               uint16_t* hi, uint16_t* lo) {
  int i = blockIdx.x * blockDim.x + threadIdx.x;
  if (i >= W_TOTAL) return;
  const float* src; int base;
  if (i < 32768)       { src = s0wl; base = 0; }
  else if (i < 65536)  { src = s0wr; base = 32768; }
  else if (i < 131072) { src = s1wl; base = 65536; }
  else if (i < 196608) { src = s1wr; base = 131072; }
  else if (i < 206848) { src = s2wl; base = 196608; }
  else if (i < 217088) { src = s2wr; base = 206848; }
  else if (i < 249856) { src = h0w;  base = 217088; }
  else if (i < 315392) { src = h1w;  base = 249856; }
  else if (i < 380928) { src = h2w;  base = 315392; }
  else if (i < 446464) { src = h3w;  base = 380928; }
  else                 { src = h4w;  base = 446464; }
  float v = src[i - base];
  uint16_t hb = rne16(v);
  float lf = v - bfh(hb);
  hi[i] = hb;
  lo[i] = rne16(lf);
}

// ---------------------------------------------------------- x f32 -> bf16
__global__ void cvt_kernel(const float* __restrict__ X, uint16_t* __restrict__ O, int n4) {
  int i = blockIdx.x * blockDim.x + threadIdx.x;
  if (i >= n4) return;
  v4f v = *((const v4f*)X + i);
  v4u o;
  o[0] = rne16(v[0]); o[1] = rne16(v[1]); o[2] = rne16(v[2]); o[3] = rne16(v[3]);
  *((v4u*)O + i) = o;
}

// ------------------- XCD-L2-blocked sliced gather-mean (big-table aggs)
// Feature dim split into S slices of 32 cols; slice = blockIdx & (S-1) pins a
// slice to one XCD (round-robin dispatch) so the per-XCD gather working set is
// F/S*2B*Nrows_src <= 3.2MB -> local L2. One wave per row; per iteration:
// 16 neighbors x (4 lanes * 16B). Cross-lane reduce over neighbor subgroups.
template <int F, int LOG_S>
__global__ __launch_bounds__(256) void aggs_kernel(
    const int* __restrict__ off, const uint16_t* __restrict__ idx,
    const float* __restrict__ scale, const uint16_t* __restrict__ X,
    uint16_t* __restrict__ OUT, int nrows) {
  constexpr int S = 1 << LOG_S;
  int slice = blockIdx.x & (S - 1);
  int row = (blockIdx.x >> LOG_S) * 4 + (threadIdx.x >> 6);
  if (row >= nrows) return;
  int lane = threadIdx.x & 63;
  int g = lane >> 2, c = lane & 3;
  int j0 = off[row], j1 = off[row + 1];
  float sc = scale[row];
  int colbase = slice * 32 + c * 8;

  float acc[8];
#pragma unroll
  for (int k = 0; k < 8; ++k) acc[k] = 0.f;

  for (int j = j0 + g; j < j1; j += 16) {
    int s = idx[j];
    v8u v = *(const v8u*)(X + (size_t)s * F + colbase);
#pragma unroll
    for (int k = 0; k < 8; ++k) acc[k] += bfh(v[k]);
  }
  // butterfly over the 16 neighbor subgroups (lane bits 2..5)
#pragma unroll
  for (int m = 4; m <= 32; m <<= 1)
#pragma unroll
    for (int k = 0; k < 8; ++k) acc[k] += __shfl_xor(acc[k], m);

  if (g == 0) {
    v8u o;
#pragma unroll
    for (int k = 0; k < 8; ++k) o[k] = rne16(acc[k] * sc);
    *(v8u*)(OUT + (size_t)row * F + colbase) = o;
  }
}

// ------------------------------- plain gather-mean (small, L2-resident tables)
// OUT[row,:] = rne16( act( scale[row] * sum_j X[idx[j],:] + bias ) )
template <int F>
__global__ void aggb_kernel(const int* __restrict__ off, const uint16_t* __restrict__ idx,
                            const float* __restrict__ scale,
                            const uint16_t* __restrict__ X,
                            uint16_t* __restrict__ OUT,
                            const float* __restrict__ bias, int do_relu) {
  constexpr int VEC = (F >= 256) ? 4 : 2;
  int row = blockIdx.x;
  int t = threadIdx.x;
  if (t * VEC >= F) return;
  int j0 = off[row], j1 = off[row + 1];
  float sc = scale[row];
  float acc[VEC];
#pragma unroll
  for (int k = 0; k < VEC; ++k) acc[k] = 0.f;

  int j = j0;
  for (; j + 3 < j1; j += 4) {
    int s0 = idx[j], s1 = idx[j + 1], s2 = idx[j + 2], s3 = idx[j + 3];
    if (VEC == 4) {
      v4u a = *(const v4u*)(X + (size_t)s0 * F + t * 4);
      v4u b = *(const v4u*)(X + (size_t)s1 * F + t * 4);
      v4u c = *(const v4u*)(X + (size_t)s2 * F + t * 4);
      v4u d = *(const v4u*)(X + (size_t)s3 * F + t * 4);
#pragma unroll
      for (int k = 0; k < 4; ++k)
        acc[k] += bfh(a[k]) + bfh(b[k]) + bfh(c[k]) + bfh(d[k]);
    } else {
      v2u a = *(const v2u*)(X + (size_t)s0 * F + t * 2);
      v2u b = *(const v2u*)(X + (size_t)s1 * F + t * 2);
      v2u c = *(const v2u*)(X + (size_t)s2 * F + t * 2);
      v2u d = *(const v2u*)(X + (size_t)s3 * F + t * 2);
#pragma unroll
      for (int k = 0; k < 2; ++k)
        acc[k] += bfh(a[k]) + bfh(b[k]) + bfh(c[k]) + bfh(d[k]);
    }
  }
  for (; j < j1; ++j) {
    int s = idx[j];
    if (VEC == 4) {
      v4u a = *(const v4u*)(X + (size_t)s * F + t * 4);
#pragma unroll
      for (int k = 0; k < 4; ++k) acc[k] += bfh(a[k]);
    } else {
      v2u a = *(const v2u*)(X + (size_t)s * F + t * 2);
#pragma unroll
      for (int k = 0; k < 2; ++k) acc[k] += bfh(a[k]);
    }
  }

  if (VEC == 4) {
    v4u o;
#pragma unroll
    for (int k = 0; k < 4; ++k) {
      float v = acc[k] * sc;
      if (bias) { v += bias[t * 4 + k]; if (do_relu) v = fmaxf(v, 0.f); }
      o[k] = rne16(v);
    }
    *(v4u*)(OUT + (size_t)row * F + t * 4) = o;
  } else {
    v2u o;
#pragma unroll
    for (int k = 0; k < 2; ++k) {
      float v = acc[k] * sc;
      if (bias) { v += bias[t * 2 + k]; if (do_relu) v = fmaxf(v, 0.f); }
      o[k] = rne16(v);
    }
    *(v2u*)(OUT + (size_t)row * F + t * 2) = o;
  }
}

// Final hyper agg (F=40) fused with bias, f32 out into XCAT[:,40:].
__global__ void agg40b_kernel(const int* __restrict__ off, const uint16_t* __restrict__ idx,
                              const float* __restrict__ scale,
                              const uint16_t* __restrict__ EF40,
                              const float* __restrict__ bias,
                              float* __restrict__ XCAT) {
  int row = blockIdx.x;
  int t = threadIdx.x;
  if (t >= 20) return;
  int j0 = off[row], j1 = off[row + 1];
  float sc = scale[row];
  float a0 = 0.f, a1 = 0.f;
  for (int j = j0; j < j1; ++j) {
    int s = idx[j];
    v2u v = *(const v2u*)(EF40 + (size_t)s * 40 + t * 2);
    a0 += bfh(v[0]);
    a1 += bfh(v[1]);
  }
  XCAT[(size_t)row * 80 + 40 + t * 2]     = a0 * sc + bias[t * 2];
  XCAT[(size_t)row * 80 + 40 + t * 2 + 1] = a1 * sc + bias[t * 2 + 1];
}

// ------------------------------------- bf16-A, split-W LDS-staged MFMA GEMM
template <int K1, int K2, int F, bool OUTBF>
__global__ __launch_bounds__(256, 4) void lin2b_kernel(
    const uint16_t* __restrict__ X1, const uint16_t* __restrict__ W1h, const uint16_t* __restrict__ W1l,
    const uint16_t* __restrict__ X2, const uint16_t* __restrict__ W2h, const uint16_t* __restrict__ W2l,
    const float* __restrict__ bias, const uint16_t* __restrict__ addin,
    void* __restrict__ OUTP, int out_ld, int N, int do_relu) {
  constexpr int FP  = (F + 15) & ~15;
  constexpr int NF  = FP / 16;
  constexpr int NC1 = K1 / 32;
  constexpr int NCH = (K1 + (K2 > 0 ? K2 : 0)) / 32;
  constexpr int RS  = 40;
  __shared__ short sW[2][FP][RS];

  int tid  = threadIdx.x;
  int wave = tid >> 6, lane = tid & 63;
  int r = lane & 15, q = lane >> 4;
  int row0 = blockIdx.x * 64 + wave * 16;
  int rowA = row0 + r; if (rowA > N - 1) rowA = N - 1;

  int srow = tid >> 2;
  int sj   = tid & 3;

  v4f acc[NF];
#pragma unroll
  for (int i = 0; i < NF; ++i) acc[i] = (v4f){0.f, 0.f, 0.f, 0.f};

  for (int c = 0; c < NCH; ++c) {
    const bool first = (K2 == 0) || (c < NC1);
    const uint16_t* Wh = first ? W1h : W2h;
    const uint16_t* Wl = first ? W1l : W2l;
    const uint16_t* Xs = first ? X1 : X2;
    const int K  = first ? K1 : K2;
    const int kc = (first ? c : c - NC1) * 32;

    if (c) __syncthreads();
    const v8s zz = {0, 0, 0, 0, 0, 0, 0, 0};
#pragma unroll
    for (int pass = 0; pass < (FP + 63) / 64; ++pass) {
      int row = srow + pass * 64;
      if (row < FP) {
        v8s hv = zz, lv = zz;
        if (row < F) {
          hv = *reinterpret_cast<const v8s*>(Wh + (size_t)row * K + kc + sj * 8);
          lv = *reinterpret_cast<const v8s*>(Wl + (size_t)row * K + kc + sj * 8);
        }
        *reinterpret_cast<v8s*>(&sW[0][row][sj * 8]) = hv;
        *reinterpret_cast<v8s*>(&sW[1][row][sj * 8]) = lv;
      }
    }
    v8s ah = *reinterpret_cast<const v8s*>(Xs + (size_t)rowA * K + kc + q * 8);
    __syncthreads();
#pragma unroll
    for (int ft = 0; ft < NF; ++ft) {
      v8s bh = *reinterpret_cast<const v8s*>(&sW[0][ft * 16 + r][q * 8]);
      v8s bl = *reinterpret_cast<const v8s*>(&sW[1][ft * 16 + r][q * 8]);
      acc[ft] = __builtin_amdgcn_mfma_f32_16x16x32_bf16(ah, bh, acc[ft], 0, 0, 0);
      acc[ft] = __builtin_amdgcn_mfma_f32_16x16x32_bf16(ah, bl, acc[ft], 0, 0, 0);
    }
  }

#pragma unroll
  for (int ft = 0; ft < NF; ++ft) {
    int col = ft * 16 + r;
    if (col < F) {
      float bv = bias ? bias[col] : 0.f;
#pragma unroll
      for (int i = 0; i < 4; ++i) {
        int row = row0 + q * 4 + i;
        if (row < N) {
          float v = acc[ft][i] + bv;
          if (addin) v += bfh(addin[(size_t)row * F + col]);
          if (do_relu) v = fmaxf(v, 0.f);
          size_t o = (size_t)row * out_ld + col;
          if (OUTBF) ((uint16_t*)OUTP)[o] = rne16(v);
          else ((float*)OUTP)[o] = v;
        }
      }
    }
  }
}

// ---------------------------------------------------- final linear + logsoftmax
__global__ __launch_bounds__(256) void final_ls_kernel(
    const float* __restrict__ XCAT, const float* __restrict__ lpw,
    const float* __restrict__ lpb, float* __restrict__ out) {
  int wid = (blockIdx.x * 256 + threadIdx.x) >> 6;
  int lane = threadIdx.x & 63;
  if (wid >= N_NODES) return;
  const float* xr = XCAT + (size_t)wid * 80;
  float logit = -1e30f;
  if (lane < 40) {
    float s = lpb[lane];
    const float* wr = lpw + lane * 80;
#pragma unroll 8
    for (int k = 0; k < 80; ++k) s += xr[k] * wr[k];
    logit = s;
  }
  float m = logit;
#pragma unroll
  for (int d = 1; d < 64; d <<= 1) m = fmaxf(m, __shfl_xor(m, d));
  float e = (lane < 40) ? __expf(logit - m) : 0.f;
  float ssum = e;
#pragma unroll
  for (int d = 1; d < 64; d <<= 1) ssum += __shfl_xor(ssum, d);
  if (lane < 40)
    out[(size_t)wid * 40 + lane] = logit - m - __logf(ssum);
}

// ---------------------------------------------------------------- launcher
extern "C" void kernel_launch(void* const* d_in, const int* in_sizes, int n_in,
                              void* d_out, int out_size, void* d_ws, size_t ws_size,
                              hipStream_t stream) {
  const float* x      = (const float*)d_in[0];
  const int* src      = (const int*)d_in[1];
  const int* dst      = (const int*)d_in[2];
  const int* he_node  = (const int*)d_in[3];
  const int* he_edge  = (const int*)d_in[4];
  const float* s0wl = (const float*)d_in[5],  *s0wr = (const float*)d_in[6],  *s0b = (const float*)d_in[7];
  const float* s1wl = (const float*)d_in[8],  *s1wr = (const float*)d_in[9],  *s1b = (const float*)d_in[10];
  const float* s2wl = (const float*)d_in[11], *s2wr = (const float*)d_in[12], *s2b = (const float*)d_in[13];
  const float* h0w = (const float*)d_in[14], *h0b = (const float*)d_in[15];
  const float* h1w = (const float*)d_in[16], *h1b = (const float*)d_in[17];
  const float* h2w = (const float*)d_in[18], *h2b = (const float*)d_in[19];
  const float* h3w = (const float*)d_in[20], *h3b = (const float*)d_in[21];
  const float* h4w = (const float*)d_in[22], *h4b = (const float*)d_in[23];
  const float* lpw = (const float*)d_in[24], *lpb = (const float*)d_in[25];
  float* out = (float*)d_out;

  char* p = (char*)d_ws;
  auto carve = [&](size_t bytes) -> char* {
    char* r = p;
    p += (bytes + 255) & ~(size_t)255;
    return r;
  };
  int* cnt_dst  = (int*)carve((size_t)N_NODES * 4);
  int* adj_off  = (int*)carve((size_t)(N_NODES + 1) * 4);
  int* adj_cur  = (int*)carve((size_t)N_NODES * 4);
  uint16_t* adj_src  = (uint16_t*)carve((size_t)N_EDGE * 2);
  int* cnt_he   = (int*)carve((size_t)N_HE * 4);
  int* heg_off  = (int*)carve((size_t)(N_HE + 1) * 4);
  int* heg_cur  = (int*)carve((size_t)N_HE * 4);
  uint16_t* heg_node = (uint16_t*)carve((size_t)N_INC * 2);
  int* cnt_hn   = (int*)carve((size_t)N_NODES * 4);
  int* hng_off  = (int*)carve((size_t)(N_NODES + 1) * 4);
  int* hng_cur  = (int*)carve((size_t)N_NODES * 4);
  uint16_t* hng_edge = (uint16_t*)carve((size_t)N_INC * 2);
  float* deg_inv = (float*)carve((size_t)N_NODES * 4);
  float* binv    = (float*)carve((size_t)N_HE * 4);
  float* dinv    = (float*)carve((size_t)N_NODES * 4);
  uint16_t* Wh = (uint16_t*)carve((size_t)W_TOTAL * 2);
  uint16_t* Wl = (uint16_t*)carve((size_t)W_TOTAL * 2);
  uint16_t* XB = (uint16_t*)carve((size_t)N_NODES * 128 * 2);
  uint16_t* U  = (uint16_t*)carve((size_t)N_NODES * 128 * 2);
  uint16_t* NA = (uint16_t*)carve((size_t)N_NODES * 256 * 2);
  uint16_t* NB = (uint16_t*)carve((size_t)N_NODES * 256 * 2);
  uint16_t* NC = (uint16_t*)carve((size_t)N_NODES * 256 * 2);
  uint16_t* EFa = (uint16_t*)carve((size_t)N_HE * 256 * 2);
  uint16_t* EFb = (uint16_t*)carve((size_t)N_HE * 256 * 2);
  uint16_t* T40 = (uint16_t*)carve((size_t)N_NODES * 40 * 2);
  uint16_t* S40 = (uint16_t*)carve((size_t)N_NODES * 40 * 2);
  float* XCAT = (float*)carve((size_t)N_NODES * 80 * 4);

  const int GE = (N_EDGE + 255) / 256;
  const int GN = (N_NODES + 255) / 256;
  const int GL = (N_NODES + 63) / 64;
  const int GS = (N_HE + 63) / 64;
  // sliced-agg grids: S * ceil(rows/4), 256 threads (4 waves = 4 rows)
  const int GA_N8 = 8 * ((N_NODES + 3) / 4);
  const int GA_N4 = 4 * ((N_NODES + 3) / 4);
  const int GA_H8 = 8 * ((N_HE + 3) / 4);
  const int GA_H4 = 4 * ((N_HE + 3) / 4);

  // ---- CSR build + weight split + x conversion
  zero3_kernel<<<411, 256, 0, stream>>>(cnt_dst, N_NODES, cnt_he, N_HE, cnt_hn, N_NODES);
  hist_kernel<<<GE, 256, 0, stream>>>(dst, he_node, he_edge, cnt_dst, cnt_he, cnt_hn);
  scales_kernel<<<GN, 256, 0, stream>>>(cnt_dst, cnt_hn, cnt_he, deg_inv, dinv, binv);
  scan3_kernel<<<3, 1024, 0, stream>>>(cnt_dst, adj_off, adj_cur,
                                       cnt_he, heg_off, heg_cur,
                                       cnt_hn, hng_off, hng_cur);
  fill_kernel<<<GE, 256, 0, stream>>>(src, dst, he_node, he_edge,
                                      adj_cur, adj_src, heg_cur, heg_node,
                                      hng_cur, hng_edge);
  split_w_kernel<<<(W_TOTAL + 255) / 256, 256, 0, stream>>>(
      s0wl, s0wr, s1wl, s1wr, s2wl, s2wr, h0w, h1w, h2w, h3w, h4w, Wh, Wl);
  cvt_kernel<<<(N_NODES * 32 + 255) / 256, 256, 0, stream>>>(x, XB, N_NODES * 32);

  // ---- SAGE branch
  aggs_kernel<128, 2><<<GA_N4, 256, 0, stream>>>(adj_off, adj_src, deg_inv, XB, U, N_NODES);
  lin2b_kernel<128, 128, 256, true><<<GL, 256, 0, stream>>>(
      U, Wh + 0, Wl + 0, XB, Wh + 32768, Wl + 32768, s0b, nullptr, NA, 256, N_NODES, 1);
  aggs_kernel<256, 3><<<GA_N8, 256, 0, stream>>>(adj_off, adj_src, deg_inv, NA, NB, N_NODES);
  lin2b_kernel<256, 256, 256, true><<<GL, 256, 0, stream>>>(
      NB, Wh + 65536, Wl + 65536, NA, Wh + 131072, Wl + 131072, s1b, nullptr, NC, 256, N_NODES, 1);
  lin2b_kernel<256, 0, 40, true><<<GL, 256, 0, stream>>>(
      NC, Wh + 196608, Wl + 196608, nullptr, nullptr, nullptr, nullptr, nullptr, T40, 40, N_NODES, 0);
  aggb_kernel<40><<<N_NODES, 64, 0, stream>>>(adj_off, adj_src, deg_inv, T40, S40, nullptr, 0);
  lin2b_kernel<256, 0, 40, false><<<GL, 256, 0, stream>>>(
      NC, Wh + 206848, Wl + 206848, nullptr, nullptr, nullptr, s2b, S40, XCAT, 80, N_NODES, 0);

  // ---- Hypergraph branch: heagg -> tiny GEMM (5000 rows) -> nodeagg+bias+relu
  // layer 0 (K=128)
  aggs_kernel<128, 2><<<GA_H4, 256, 0, stream>>>(heg_off, heg_node, binv, XB, EFa, N_HE);
  lin2b_kernel<128, 0, 256, true><<<GS, 256, 0, stream>>>(
      EFa, Wh + 217088, Wl + 217088, nullptr, nullptr, nullptr, nullptr, nullptr, EFb, 256, N_HE, 0);
  aggb_kernel<256><<<N_NODES, 64, 0, stream>>>(hng_off, hng_edge, dinv, EFb, NC, h0b, 1);
  // layers 1..3 (K=256)
  aggs_kernel<256, 3><<<GA_H8, 256, 0, stream>>>(heg_off, heg_node, binv, NC, EFa, N_HE);
  lin2b_kernel<256, 0, 256, true><<<GS, 256, 0, stream>>>(
      EFa, Wh + 249856, Wl + 249856, nullptr, nullptr, nullptr, nullptr, nullptr, EFb, 256, N_HE, 0);
  aggb_kernel<256><<<N_NODES, 64, 0, stream>>>(hng_off, hng_edge, dinv, EFb, NC, h1b, 1);

  aggs_kernel<256, 3><<<GA_H8, 256, 0, stream>>>(heg_off, heg_node, binv, NC, EFa, N_HE);
  lin2b_kernel<256, 0, 256, true><<<GS, 256, 0, stream>>>(
      EFa, Wh + 315392, Wl + 315392, nullptr, nullptr, nullptr, nullptr, nullptr, EFb, 256, N_HE, 0);
  aggb_kernel<256><<<N_NODES, 64, 0, stream>>>(hng_off, hng_edge, dinv, EFb, NC, h2b, 1);

  aggs_kernel<256, 3><<<GA_H8, 256, 0, stream>>>(heg_off, heg_node, binv, NC, EFa, N_HE);
  lin2b_kernel<256, 0, 256, true><<<GS, 256, 0, stream>>>(
      EFa, Wh + 380928, Wl + 380928, nullptr, nullptr, nullptr, nullptr, nullptr, EFb, 256, N_HE, 0);
  aggb_kernel<256><<<N_NODES, 64, 0, stream>>>(hng_off, hng_edge, dinv, EFb, NC, h3b, 1);
  // layer 4 (F=40): transform node features first (cheap), then aggregate
  lin2b_kernel<256, 0, 40, true><<<GL, 256, 0, stream>>>(
      NC, Wh + 446464, Wl + 446464, nullptr, nullptr, nullptr, nullptr, nullptr, T40, 40, N_NODES, 0);
  aggb_kernel<40><<<N_HE, 64, 0, stream>>>(heg_off, heg_node, binv, T40, EFa, nullptr, 0);
  agg40b_kernel<<<N_NODES, 64, 0, stream>>>(hng_off, hng_edge, dinv, EFa, h4b, XCAT);

  // ---- final linear + log_softmax
  final_ls_kernel<<<(N_NODES + 3) / 4, 256, 0, stream>>>(XCAT, lpw, lpb, out);
}

// Round 8
// 1118.400 us; speedup vs baseline: 1.0997x; 1.0997x over previous
//
#include <hip/hip_runtime.h>
#include <hip/hip_bf16.h>
#include <cstdint>
#include <cstddef>

typedef __hip_bfloat16 bf16;
typedef short v8s __attribute__((ext_vector_type(8)));
typedef float v4f __attribute__((ext_vector_type(4)));
typedef unsigned short v8u __attribute__((ext_vector_type(8)));
typedef unsigned short v4u __attribute__((ext_vector_type(4)));
typedef unsigned short v2u __attribute__((ext_vector_type(2)));

#define N_NODES 50000
#define N_HE    5000
#define N_EDGE  800000
#define N_INC   400000

__device__ inline float bfh(uint32_t u) { return __uint_as_float(u << 16); }
__device__ inline uint16_t rne16(float f) {
  uint32_t u = __float_as_uint(f);
  return (uint16_t)((u + 0x7FFFu + ((u >> 16) & 1u)) >> 16);
}

// ---------------------------------------------------------------- CSR build
__global__ void zero3_kernel(int* a, int na, int* b, int nb, int* c, int nc) {
  int total = na + nb + nc;
  for (int i = blockIdx.x * blockDim.x + threadIdx.x; i < total;
       i += gridDim.x * blockDim.x) {
    if (i < na) a[i] = 0;
    else if (i < na + nb) b[i - na] = 0;
    else c[i - na - nb] = 0;
  }
}

__global__ void hist_kernel(const int* __restrict__ dst,
                            const int* __restrict__ he_node,
                            const int* __restrict__ he_edge,
                            int* cnt_dst, int* cnt_he, int* cnt_hn) {
  int i = blockIdx.x * blockDim.x + threadIdx.x;
  if (i < N_EDGE) atomicAdd(&cnt_dst[dst[i]], 1);
  if (i < N_INC) {
    atomicAdd(&cnt_he[he_edge[i]], 1);
    atomicAdd(&cnt_hn[he_node[i]], 1);
  }
}

__global__ void scales_kernel(const int* cnt_dst, const int* cnt_hn,
                              const int* cnt_he,
                              float* deg_inv, float* dinv, float* binv) {
  int i = blockIdx.x * blockDim.x + threadIdx.x;
  if (i < N_NODES) {
    int d = cnt_dst[i];
    deg_inv[i] = 1.0f / (float)(d > 1 ? d : 1);
    int h = cnt_hn[i];
    dinv[i] = h > 0 ? 1.0f / (float)h : 0.0f;
  }
  if (i < N_HE) {
    int e = cnt_he[i];
    binv[i] = e > 0 ? 1.0f / (float)e : 0.0f;
  }
}

__global__ void scan3_kernel(const int* cnt_dst, int* adj_off, int* adj_cur,
                             const int* cnt_he, int* heg_off, int* heg_cur,
                             const int* cnt_hn, int* hng_off, int* hng_cur) {
  const int* cnt; int* off; int* cur; int n;
  if (blockIdx.x == 0)      { cnt = cnt_dst; off = adj_off; cur = adj_cur; n = N_NODES; }
  else if (blockIdx.x == 1) { cnt = cnt_he;  off = heg_off; cur = heg_cur; n = N_HE; }
  else                      { cnt = cnt_hn;  off = hng_off; cur = hng_cur; n = N_NODES; }
  __shared__ int buf[1024];
  int t = threadIdx.x;
  int carry = 0;
  for (int base = 0; base < n; base += 1024) {
    int i = base + t;
    int v = (i < n) ? cnt[i] : 0;
    buf[t] = v;
    __syncthreads();
    for (int d = 1; d < 1024; d <<= 1) {
      int x = (t >= d) ? buf[t - d] : 0;
      __syncthreads();
      buf[t] += x;
      __syncthreads();
    }
    int excl = buf[t] - v;
    if (i < n) { off[i] = carry + excl; cur[i] = carry + excl; }
    int total = buf[1023];
    __syncthreads();
    carry += total;
  }
  if (t == 0) off[n] = carry;
}

__global__ void fill_kernel(const int* __restrict__ src, const int* __restrict__ dst,
                            const int* __restrict__ he_node, const int* __restrict__ he_edge,
                            int* adj_cur, uint16_t* adj_src,
                            int* heg_cur, uint16_t* heg_node,
                            int* hng_cur, uint16_t* hng_edge) {
  int i = blockIdx.x * blockDim.x + threadIdx.x;
  if (i < N_EDGE) {
    int p = atomicAdd(&adj_cur[dst[i]], 1);
    adj_src[p] = (uint16_t)src[i];
  }
  if (i < N_INC) {
    int p = atomicAdd(&heg_cur[he_edge[i]], 1);
    heg_node[p] = (uint16_t)he_node[i];
    int p2 = atomicAdd(&hng_cur[he_node[i]], 1);
    hng_edge[p2] = (uint16_t)he_edge[i];
  }
}

// ---------------------------------------------------- weight hi/lo bf16 split
#define W_TOTAL 456704
__global__ void split_w_kernel(const float* s0wl, const float* s0wr,
                               const float* s1wl, const float* s1wr,
                               const float* s2wl, const float* s2wr,
                               const float* h0w, const float* h1w,
                               const float* h2w, const float* h3w,
                               const float* h4w,
                               uint16_t* hi, uint16_t* lo) {
  int i = blockIdx.x * blockDim.x + threadIdx.x;
  if (i >= W_TOTAL) return;
  const float* src; int base;
  if (i < 32768)       { src = s0wl; base = 0; }
  else if (i < 65536)  { src = s0wr; base = 32768; }
  else if (i < 131072) { src = s1wl; base = 65536; }
  else if (i < 196608) { src = s1wr; base = 131072; }
  else if (i < 206848) { src = s2wl; base = 196608; }
  else if (i < 217088) { src = s2wr; base = 206848; }
  else if (i < 249856) { src = h0w;  base = 217088; }
  else if (i < 315392) { src = h1w;  base = 249856; }
  else if (i < 380928) { src = h2w;  base = 315392; }
  else if (i < 446464) { src = h3w;  base = 380928; }
  else                 { src = h4w;  base = 446464; }
  float v = src[i - base];
  uint16_t hb = rne16(v);
  float lf = v - bfh(hb);
  hi[i] = hb;
  lo[i] = rne16(lf);
}

// ---------------------------------------------------------- x f32 -> bf16
__global__ void cvt_kernel(const float* __restrict__ X, uint16_t* __restrict__ O, int n4) {
  int i = blockIdx.x * blockDim.x + threadIdx.x;
  if (i >= n4) return;
  v4f v = *((const v4f*)X + i);
  v4u o;
  o[0] = rne16(v[0]); o[1] = rne16(v[1]); o[2] = rne16(v[2]); o[3] = rne16(v[3]);
  *((v4u*)O + i) = o;
}

// ------------------------------- gather-mean over bf16 rows (uint16 CSR idx)
// OUT[row,:] = rne16( act( scale[row] * sum_j X[idx[j],:] + bias ) )
template <int F>
__global__ void aggb_kernel(const int* __restrict__ off, const uint16_t* __restrict__ idx,
                            const float* __restrict__ scale,
                            const uint16_t* __restrict__ X,
                            uint16_t* __restrict__ OUT,
                            const float* __restrict__ bias, int do_relu) {
  constexpr int VEC = (F >= 256) ? 4 : 2;
  int row = blockIdx.x;
  int t = threadIdx.x;
  if (t * VEC >= F) return;
  int j0 = off[row], j1 = off[row + 1];
  float sc = scale[row];
  float acc[VEC];
#pragma unroll
  for (int k = 0; k < VEC; ++k) acc[k] = 0.f;

  int j = j0;
  for (; j + 3 < j1; j += 4) {
    int s0 = idx[j], s1 = idx[j + 1], s2 = idx[j + 2], s3 = idx[j + 3];
    if (VEC == 4) {
      v4u a = *(const v4u*)(X + (size_t)s0 * F + t * 4);
      v4u b = *(const v4u*)(X + (size_t)s1 * F + t * 4);
      v4u c = *(const v4u*)(X + (size_t)s2 * F + t * 4);
      v4u d = *(const v4u*)(X + (size_t)s3 * F + t * 4);
#pragma unroll
      for (int k = 0; k < 4; ++k)
        acc[k] += bfh(a[k]) + bfh(b[k]) + bfh(c[k]) + bfh(d[k]);
    } else {
      v2u a = *(const v2u*)(X + (size_t)s0 * F + t * 2);
      v2u b = *(const v2u*)(X + (size_t)s1 * F + t * 2);
      v2u c = *(const v2u*)(X + (size_t)s2 * F + t * 2);
      v2u d = *(const v2u*)(X + (size_t)s3 * F + t * 2);
#pragma unroll
      for (int k = 0; k < 2; ++k)
        acc[k] += bfh(a[k]) + bfh(b[k]) + bfh(c[k]) + bfh(d[k]);
    }
  }
  for (; j < j1; ++j) {
    int s = idx[j];
    if (VEC == 4) {
      v4u a = *(const v4u*)(X + (size_t)s * F + t * 4);
#pragma unroll
      for (int k = 0; k < 4; ++k) acc[k] += bfh(a[k]);
    } else {
      v2u a = *(const v2u*)(X + (size_t)s * F + t * 2);
#pragma unroll
      for (int k = 0; k < 2; ++k) acc[k] += bfh(a[k]);
    }
  }

  if (VEC == 4) {
    v4u o;
#pragma unroll
    for (int k = 0; k < 4; ++k) {
      float v = acc[k] * sc;
      if (bias) { v += bias[t * 4 + k]; if (do_relu) v = fmaxf(v, 0.f); }
      o[k] = rne16(v);
    }
    *(v4u*)(OUT + (size_t)row * F + t * 4) = o;
  } else {
    v2u o;
#pragma unroll
    for (int k = 0; k < 2; ++k) {
      float v = acc[k] * sc;
      if (bias) { v += bias[t * 2 + k]; if (do_relu) v = fmaxf(v, 0.f); }
      o[k] = rne16(v);
    }
    *(v2u*)(OUT + (size_t)row * F + t * 2) = o;
  }
}

// Hyper tail: XCAT[:,40:] = dinv*agg(EF40) + bias   (f32 out)
__global__ void agg40b_kernel(const int* __restrict__ off, const uint16_t* __restrict__ idx,
                              const float* __restrict__ scale,
                              const uint16_t* __restrict__ EF40,
                              const float* __restrict__ bias,
                              float* __restrict__ XCAT) {
  int row = blockIdx.x;
  int t = threadIdx.x;
  if (t >= 20) return;
  int j0 = off[row], j1 = off[row + 1];
  float sc = scale[row];
  float a0 = 0.f, a1 = 0.f;
  for (int j = j0; j < j1; ++j) {
    int s = idx[j];
    v2u v = *(const v2u*)(EF40 + (size_t)s * 40 + t * 2);
    a0 += bfh(v[0]);
    a1 += bfh(v[1]);
  }
  XCAT[(size_t)row * 80 + 40 + t * 2]     = a0 * sc + bias[t * 2];
  XCAT[(size_t)row * 80 + 40 + t * 2 + 1] = a1 * sc + bias[t * 2 + 1];
}

// SAGE tail: XCAT[:, :40] = deg_inv*agg(T40a) + T40b   (T40b = C*Wr + b, bf16)
__global__ void agg40s_kernel(const int* __restrict__ off, const uint16_t* __restrict__ idx,
                              const float* __restrict__ scale,
                              const uint16_t* __restrict__ T40a,
                              const uint16_t* __restrict__ T40b,
                              float* __restrict__ XCAT) {
  int row = blockIdx.x;
  int t = threadIdx.x;
  if (t >= 20) return;
  int j0 = off[row], j1 = off[row + 1];
  float sc = scale[row];
  float a0 = 0.f, a1 = 0.f;
  for (int j = j0; j < j1; ++j) {
    int s = idx[j];
    v2u v = *(const v2u*)(T40a + (size_t)s * 40 + t * 2);
    a0 += bfh(v[0]);
    a1 += bfh(v[1]);
  }
  v2u b = *(const v2u*)(T40b + (size_t)row * 40 + t * 2);
  XCAT[(size_t)row * 80 + t * 2]     = a0 * sc + bfh(b[0]);
  XCAT[(size_t)row * 80 + t * 2 + 1] = a1 * sc + bfh(b[1]);
}

// ------------------------------------- bf16-A, split-W LDS-staged MFMA GEMM
// A/B frag: row|col = lane&15, k = (lane>>4)*8+j.  C/D: col = lane&15,
// row = (lane>>4)*4 + reg  (verified gfx950 mappings).
template <int K1, int K2, int F, bool OUTBF>
__global__ __launch_bounds__(256, 4) void lin2b_kernel(
    const uint16_t* __restrict__ X1, const uint16_t* __restrict__ W1h, const uint16_t* __restrict__ W1l,
    const uint16_t* __restrict__ X2, const uint16_t* __restrict__ W2h, const uint16_t* __restrict__ W2l,
    const float* __restrict__ bias, const uint16_t* __restrict__ addin,
    void* __restrict__ OUTP, int out_ld, int N, int do_relu) {
  constexpr int FP  = (F + 15) & ~15;
  constexpr int NF  = FP / 16;
  constexpr int NC1 = K1 / 32;
  constexpr int NCH = (K1 + (K2 > 0 ? K2 : 0)) / 32;
  constexpr int RS  = 40;
  __shared__ short sW[2][FP][RS];

  int tid  = threadIdx.x;
  int wave = tid >> 6, lane = tid & 63;
  int r = lane & 15, q = lane >> 4;
  int row0 = blockIdx.x * 64 + wave * 16;
  int rowA = row0 + r; if (rowA > N - 1) rowA = N - 1;

  int srow = tid >> 2;
  int sj   = tid & 3;

  v4f acc[NF];
#pragma unroll
  for (int i = 0; i < NF; ++i) acc[i] = (v4f){0.f, 0.f, 0.f, 0.f};

  for (int c = 0; c < NCH; ++c) {
    const bool first = (K2 == 0) || (c < NC1);
    const uint16_t* Wh = first ? W1h : W2h;
    const uint16_t* Wl = first ? W1l : W2l;
    const uint16_t* Xs = first ? X1 : X2;
    const int K  = first ? K1 : K2;
    const int kc = (first ? c : c - NC1) * 32;

    if (c) __syncthreads();
    const v8s zz = {0, 0, 0, 0, 0, 0, 0, 0};
#pragma unroll
    for (int pass = 0; pass < (FP + 63) / 64; ++pass) {
      int row = srow + pass * 64;
      if (row < FP) {
        v8s hv = zz, lv = zz;
        if (row < F) {
          hv = *reinterpret_cast<const v8s*>(Wh + (size_t)row * K + kc + sj * 8);
          lv = *reinterpret_cast<const v8s*>(Wl + (size_t)row * K + kc + sj * 8);
        }
        *reinterpret_cast<v8s*>(&sW[0][row][sj * 8]) = hv;
        *reinterpret_cast<v8s*>(&sW[1][row][sj * 8]) = lv;
      }
    }
    v8s ah = *reinterpret_cast<const v8s*>(Xs + (size_t)rowA * K + kc + q * 8);
    __syncthreads();
#pragma unroll
    for (int ft = 0; ft < NF; ++ft) {
      v8s bh = *reinterpret_cast<const v8s*>(&sW[0][ft * 16 + r][q * 8]);
      v8s bl = *reinterpret_cast<const v8s*>(&sW[1][ft * 16 + r][q * 8]);
      acc[ft] = __builtin_amdgcn_mfma_f32_16x16x32_bf16(ah, bh, acc[ft], 0, 0, 0);
      acc[ft] = __builtin_amdgcn_mfma_f32_16x16x32_bf16(ah, bl, acc[ft], 0, 0, 0);
    }
  }

#pragma unroll
  for (int ft = 0; ft < NF; ++ft) {
    int col = ft * 16 + r;
    if (col < F) {
      float bv = bias ? bias[col] : 0.f;
#pragma unroll
      for (int i = 0; i < 4; ++i) {
        int row = row0 + q * 4 + i;
        if (row < N) {
          float v = acc[ft][i] + bv;
          if (addin) v += bfh(addin[(size_t)row * F + col]);
          if (do_relu) v = fmaxf(v, 0.f);
          size_t o = (size_t)row * out_ld + col;
          if (OUTBF) ((uint16_t*)OUTP)[o] = rne16(v);
          else ((float*)OUTP)[o] = v;
        }
      }
    }
  }
}

// Dual-output 40-col GEMM (K=256): OUT1 = X*W1^T, OUT2 = X*W2^T + b2.
// One pass over X instead of two.
__global__ __launch_bounds__(256, 4) void lin40ab_kernel(
    const uint16_t* __restrict__ X,
    const uint16_t* __restrict__ W1h, const uint16_t* __restrict__ W1l,
    const uint16_t* __restrict__ W2h, const uint16_t* __restrict__ W2l,
    const float* __restrict__ bias2,
    uint16_t* __restrict__ OUT1, uint16_t* __restrict__ OUT2, int N) {
  constexpr int K = 256, F = 40, FP = 48, NF = 3, RS = 40;
  __shared__ short sW[2][2][FP][RS];   // [w][hi/lo][row][k]

  int tid  = threadIdx.x;
  int wave = tid >> 6, lane = tid & 63;
  int r = lane & 15, q = lane >> 4;
  int row0 = blockIdx.x * 64 + wave * 16;
  int rowA = row0 + r; if (rowA > N - 1) rowA = N - 1;
  int srow = tid >> 2, sj = tid & 3;

  v4f acc[2][NF];
#pragma unroll
  for (int w = 0; w < 2; ++w)
#pragma unroll
    for (int i = 0; i < NF; ++i) acc[w][i] = (v4f){0.f, 0.f, 0.f, 0.f};

  for (int c = 0; c < K / 32; ++c) {
    int kc = c * 32;
    if (c) __syncthreads();
    if (srow < FP) {
      const v8s zz = {0, 0, 0, 0, 0, 0, 0, 0};
      v8s a = zz, b = zz, cc = zz, d = zz;
      if (srow < F) {
        a  = *reinterpret_cast<const v8s*>(W1h + (size_t)srow * K + kc + sj * 8);
        b  = *reinterpret_cast<const v8s*>(W1l + (size_t)srow * K + kc + sj * 8);
        cc = *reinterpret_cast<const v8s*>(W2h + (size_t)srow * K + kc + sj * 8);
        d  = *reinterpret_cast<const v8s*>(W2l + (size_t)srow * K + kc + sj * 8);
      }
      *reinterpret_cast<v8s*>(&sW[0][0][srow][sj * 8]) = a;
      *reinterpret_cast<v8s*>(&sW[0][1][srow][sj * 8]) = b;
      *reinterpret_cast<v8s*>(&sW[1][0][srow][sj * 8]) = cc;
      *reinterpret_cast<v8s*>(&sW[1][1][srow][sj * 8]) = d;
    }
    v8s ah = *reinterpret_cast<const v8s*>(X + (size_t)rowA * K + kc + q * 8);
    __syncthreads();
#pragma unroll
    for (int w = 0; w < 2; ++w)
#pragma unroll
      for (int ft = 0; ft < NF; ++ft) {
        v8s bh = *reinterpret_cast<const v8s*>(&sW[w][0][ft * 16 + r][q * 8]);
        v8s bl = *reinterpret_cast<const v8s*>(&sW[w][1][ft * 16 + r][q * 8]);
        acc[w][ft] = __builtin_amdgcn_mfma_f32_16x16x32_bf16(ah, bh, acc[w][ft], 0, 0, 0);
        acc[w][ft] = __builtin_amdgcn_mfma_f32_16x16x32_bf16(ah, bl, acc[w][ft], 0, 0, 0);
      }
  }

#pragma unroll
  for (int ft = 0; ft < NF; ++ft) {
    int col = ft * 16 + r;
    if (col < F) {
      float bv = bias2[col];
#pragma unroll
      for (int i = 0; i < 4; ++i) {
        int row = row0 + q * 4 + i;
        if (row < N) {
          OUT1[(size_t)row * F + col] = rne16(acc[0][ft][i]);
          OUT2[(size_t)row * F + col] = rne16(acc[1][ft][i] + bv);
        }
      }
    }
  }
}

// ---------------------------------------------------- final linear + logsoftmax
__global__ __launch_bounds__(256) void final_ls_kernel(
    const float* __restrict__ XCAT, const float* __restrict__ lpw,
    const float* __restrict__ lpb, float* __restrict__ out) {
  int wid = (blockIdx.x * 256 + threadIdx.x) >> 6;
  int lane = threadIdx.x & 63;
  if (wid >= N_NODES) return;
  const float* xr = XCAT + (size_t)wid * 80;
  float logit = -1e30f;
  if (lane < 40) {
    float s = lpb[lane];
    const float* wr = lpw + lane * 80;
#pragma unroll 8
    for (int k = 0; k < 80; ++k) s += xr[k] * wr[k];
    logit = s;
  }
  float m = logit;
#pragma unroll
  for (int d = 1; d < 64; d <<= 1) m = fmaxf(m, __shfl_xor(m, d));
  float e = (lane < 40) ? __expf(logit - m) : 0.f;
  float ssum = e;
#pragma unroll
  for (int d = 1; d < 64; d <<= 1) ssum += __shfl_xor(ssum, d);
  if (lane < 40)
    out[(size_t)wid * 40 + lane] = logit - m - __logf(ssum);
}

// ---------------------------------------------------------------- launcher
extern "C" void kernel_launch(void* const* d_in, const int* in_sizes, int n_in,
                              void* d_out, int out_size, void* d_ws, size_t ws_size,
                              hipStream_t stream) {
  const float* x      = (const float*)d_in[0];
  const int* src      = (const int*)d_in[1];
  const int* dst      = (const int*)d_in[2];
  const int* he_node  = (const int*)d_in[3];
  const int* he_edge  = (const int*)d_in[4];
  const float* s0wl = (const float*)d_in[5],  *s0wr = (const float*)d_in[6],  *s0b = (const float*)d_in[7];
  const float* s1wl = (const float*)d_in[8],  *s1wr = (const float*)d_in[9],  *s1b = (const float*)d_in[10];
  const float* s2wl = (const float*)d_in[11], *s2wr = (const float*)d_in[12], *s2b = (const float*)d_in[13];
  const float* h0w = (const float*)d_in[14], *h0b = (const float*)d_in[15];
  const float* h1w = (const float*)d_in[16], *h1b = (const float*)d_in[17];
  const float* h2w = (const float*)d_in[18], *h2b = (const float*)d_in[19];
  const float* h3w = (const float*)d_in[20], *h3b = (const float*)d_in[21];
  const float* h4w = (const float*)d_in[22], *h4b = (const float*)d_in[23];
  const float* lpw = (const float*)d_in[24], *lpb = (const float*)d_in[25];
  float* out = (float*)d_out;

  char* p = (char*)d_ws;
  auto carve = [&](size_t bytes) -> char* {
    char* r = p;
    p += (bytes + 255) & ~(size_t)255;
    return r;
  };
  int* cnt_dst  = (int*)carve((size_t)N_NODES * 4);
  int* adj_off  = (int*)carve((size_t)(N_NODES + 1) * 4);
  int* adj_cur  = (int*)carve((size_t)N_NODES * 4);
  uint16_t* adj_src  = (uint16_t*)carve((size_t)N_EDGE * 2);
  int* cnt_he   = (int*)carve((size_t)N_HE * 4);
  int* heg_off  = (int*)carve((size_t)(N_HE + 1) * 4);
  int* heg_cur  = (int*)carve((size_t)N_HE * 4);
  uint16_t* heg_node = (uint16_t*)carve((size_t)N_INC * 2);
  int* cnt_hn   = (int*)carve((size_t)N_NODES * 4);
  int* hng_off  = (int*)carve((size_t)(N_NODES + 1) * 4);
  int* hng_cur  = (int*)carve((size_t)N_NODES * 4);
  uint16_t* hng_edge = (uint16_t*)carve((size_t)N_INC * 2);
  float* deg_inv = (float*)carve((size_t)N_NODES * 4);
  float* binv    = (float*)carve((size_t)N_HE * 4);
  float* dinv    = (float*)carve((size_t)N_NODES * 4);
  uint16_t* Wh = (uint16_t*)carve((size_t)W_TOTAL * 2);
  uint16_t* Wl = (uint16_t*)carve((size_t)W_TOTAL * 2);
  uint16_t* XB = (uint16_t*)carve((size_t)N_NODES * 128 * 2);
  uint16_t* U  = (uint16_t*)carve((size_t)N_NODES * 128 * 2);
  uint16_t* NA = (uint16_t*)carve((size_t)N_NODES * 256 * 2);
  uint16_t* NB = (uint16_t*)carve((size_t)N_NODES * 256 * 2);
  uint16_t* NC = (uint16_t*)carve((size_t)N_NODES * 256 * 2);
  uint16_t* EFa = (uint16_t*)carve((size_t)N_HE * 256 * 2);
  uint16_t* EFb = (uint16_t*)carve((size_t)N_HE * 256 * 2);
  uint16_t* T40 = (uint16_t*)carve((size_t)N_NODES * 40 * 2);
  uint16_t* T40B = (uint16_t*)carve((size_t)N_NODES * 40 * 2);
  float* XCAT = (float*)carve((size_t)N_NODES * 80 * 4);

  const int GE = (N_EDGE + 255) / 256;
  const int GN = (N_NODES + 255) / 256;
  const int GL = (N_NODES + 63) / 64;
  const int GS = (N_HE + 63) / 64;

  // ---- CSR build + weight split + x conversion
  zero3_kernel<<<411, 256, 0, stream>>>(cnt_dst, N_NODES, cnt_he, N_HE, cnt_hn, N_NODES);
  hist_kernel<<<GE, 256, 0, stream>>>(dst, he_node, he_edge, cnt_dst, cnt_he, cnt_hn);
  scales_kernel<<<GN, 256, 0, stream>>>(cnt_dst, cnt_hn, cnt_he, deg_inv, dinv, binv);
  scan3_kernel<<<3, 1024, 0, stream>>>(cnt_dst, adj_off, adj_cur,
                                       cnt_he, heg_off, heg_cur,
                                       cnt_hn, hng_off, hng_cur);
  fill_kernel<<<GE, 256, 0, stream>>>(src, dst, he_node, he_edge,
                                      adj_cur, adj_src, heg_cur, heg_node,
                                      hng_cur, hng_edge);
  split_w_kernel<<<(W_TOTAL + 255) / 256, 256, 0, stream>>>(
      s0wl, s0wr, s1wl, s1wr, s2wl, s2wr, h0w, h1w, h2w, h3w, h4w, Wh, Wl);
  cvt_kernel<<<(N_NODES * 32 + 255) / 256, 256, 0, stream>>>(x, XB, N_NODES * 32);

  // ---- SAGE branch
  aggb_kernel<128><<<N_NODES, 64, 0, stream>>>(adj_off, adj_src, deg_inv, XB, U, nullptr, 0);
  lin2b_kernel<128, 128, 256, true><<<GL, 256, 0, stream>>>(
      U, Wh + 0, Wl + 0, XB, Wh + 32768, Wl + 32768, s0b, nullptr, NA, 256, N_NODES, 1);
  aggb_kernel<256><<<N_NODES, 64, 0, stream>>>(adj_off, adj_src, deg_inv, NA, NB, nullptr, 0);
  lin2b_kernel<256, 256, 256, true><<<GL, 256, 0, stream>>>(
      NB, Wh + 65536, Wl + 65536, NA, Wh + 131072, Wl + 131072, s1b, nullptr, NC, 256, N_NODES, 1);
  lin40ab_kernel<<<GL, 256, 0, stream>>>(
      NC, Wh + 196608, Wl + 196608, Wh + 206848, Wl + 206848, s2b, T40, T40B, N_NODES);
  agg40s_kernel<<<N_NODES, 64, 0, stream>>>(adj_off, adj_src, deg_inv, T40, T40B, XCAT);

  // ---- Hypergraph branch: heagg -> tiny GEMM (5000 rows) -> nodeagg+bias+relu
  aggb_kernel<128><<<N_HE, 64, 0, stream>>>(heg_off, heg_node, binv, XB, EFa, nullptr, 0);
  lin2b_kernel<128, 0, 256, true><<<GS, 256, 0, stream>>>(
      EFa, Wh + 217088, Wl + 217088, nullptr, nullptr, nullptr, nullptr, nullptr, EFb, 256, N_HE, 0);
  aggb_kernel<256><<<N_NODES, 64, 0, stream>>>(hng_off, hng_edge, dinv, EFb, NC, h0b, 1);

  aggb_kernel<256><<<N_HE, 64, 0, stream>>>(heg_off, heg_node, binv, NC, EFa, nullptr, 0);
  lin2b_kernel<256, 0, 256, true><<<GS, 256, 0, stream>>>(
      EFa, Wh + 249856, Wl + 249856, nullptr, nullptr, nullptr, nullptr, nullptr, EFb, 256, N_HE, 0);
  aggb_kernel<256><<<N_NODES, 64, 0, stream>>>(hng_off, hng_edge, dinv, EFb, NC, h1b, 1);

  aggb_kernel<256><<<N_HE, 64, 0, stream>>>(heg_off, heg_node, binv, NC, EFa, nullptr, 0);
  lin2b_kernel<256, 0, 256, true><<<GS, 256, 0, stream>>>(
      EFa, Wh + 315392, Wl + 315392, nullptr, nullptr, nullptr, nullptr, nullptr, EFb, 256, N_HE, 0);
  aggb_kernel<256><<<N_NODES, 64, 0, stream>>>(hng_off, hng_edge, dinv, EFb, NC, h2b, 1);

  aggb_kernel<256><<<N_HE, 64, 0, stream>>>(heg_off, heg_node, binv, NC, EFa, nullptr, 0);
  lin2b_kernel<256, 0, 256, true><<<GS, 256, 0, stream>>>(
      EFa, Wh + 380928, Wl + 380928, nullptr, nullptr, nullptr, nullptr, nullptr, EFb, 256, N_HE, 0);
  aggb_kernel<256><<<N_NODES, 64, 0, stream>>>(hng_off, hng_edge, dinv, EFb, NC, h3b, 1);

  // layer 4 (F=40): transform node features first, then two aggs
  lin2b_kernel<256, 0, 40, true><<<GL, 256, 0, stream>>>(
      NC, Wh + 446464, Wl + 446464, nullptr, nullptr, nullptr, nullptr, nullptr, T40, 40, N_NODES, 0);
  aggb_kernel<40><<<N_HE, 64, 0, stream>>>(heg_off, heg_node, binv, T40, EFa, nullptr, 0);
  agg40b_kernel<<<N_NODES, 64, 0, stream>>>(hng_off, hng_edge, dinv, EFa, h4b, XCAT);

  // ---- final linear + log_softmax
  final_ls_kernel<<<(N_NODES + 3) / 4, 256, 0, stream>>>(XCAT, lpw, lpb, out);
}

// Round 10
// 1060.777 us; speedup vs baseline: 1.1594x; 1.0543x over previous
//
#include <hip/hip_runtime.h>
#include <hip/hip_bf16.h>
#include <cstdint>
#include <cstddef>

typedef __hip_bfloat16 bf16;
typedef short v8s __attribute__((ext_vector_type(8)));
typedef float v4f __attribute__((ext_vector_type(4)));
typedef unsigned short v8u __attribute__((ext_vector_type(8)));
typedef unsigned short v4u __attribute__((ext_vector_type(4)));
typedef unsigned short v2u __attribute__((ext_vector_type(2)));

#define N_NODES 50000
#define N_HE    5000
#define N_EDGE  800000
#define N_INC   400000
#define W_TOTAL 456704

__device__ inline float bfh(uint32_t u) { return __uint_as_float(u << 16); }
__device__ inline uint16_t rne16(float f) {
  uint32_t u = __float_as_uint(f);
  return (uint16_t)((u + 0x7FFFu + ((u >> 16) & 1u)) >> 16);
}

// ---------------- prep: zero counters + split weights + cvt x (one launch)
// blocks [0,411): zero 105000 ints; [411,2195): split_w; [2195,8445): cvt
// (cvt needs 50000*128/4 = 1,600,000 v4 groups -> 6250 blocks).
__global__ void prep_kernel(int* cnt_dst, int* cnt_he, int* cnt_hn,
                            const float* s0wl, const float* s0wr,
                            const float* s1wl, const float* s1wr,
                            const float* s2wl, const float* s2wr,
                            const float* h0w, const float* h1w,
                            const float* h2w, const float* h3w, const float* h4w,
                            uint16_t* hi, uint16_t* lo,
                            const float* X, uint16_t* XB) {
  int b = blockIdx.x;
  if (b < 411) {
    int i = b * 256 + threadIdx.x;
    if (i < N_NODES) cnt_dst[i] = 0;
    else if (i < N_NODES + N_HE) cnt_he[i - N_NODES] = 0;
    else if (i < N_NODES + N_HE + N_NODES) cnt_hn[i - N_NODES - N_HE] = 0;
    return;
  }
  if (b < 2195) {
    int i = (b - 411) * 256 + threadIdx.x;
    if (i >= W_TOTAL) return;
    const float* src; int base;
    if (i < 32768)       { src = s0wl; base = 0; }
    else if (i < 65536)  { src = s0wr; base = 32768; }
    else if (i < 131072) { src = s1wl; base = 65536; }
    else if (i < 196608) { src = s1wr; base = 131072; }
    else if (i < 206848) { src = s2wl; base = 196608; }
    else if (i < 217088) { src = s2wr; base = 206848; }
    else if (i < 249856) { src = h0w;  base = 217088; }
    else if (i < 315392) { src = h1w;  base = 249856; }
    else if (i < 380928) { src = h2w;  base = 315392; }
    else if (i < 446464) { src = h3w;  base = 380928; }
    else                 { src = h4w;  base = 446464; }
    float v = src[i - base];
    uint16_t hb = rne16(v);
    hi[i] = hb;
    lo[i] = rne16(v - bfh(hb));
    return;
  }
  {
    int i = (b - 2195) * 256 + threadIdx.x;   // v4 index
    if (i >= N_NODES * 32) return;
    v4f v = *((const v4f*)X + i);
    v4u o;
    o[0] = rne16(v[0]); o[1] = rne16(v[1]); o[2] = rne16(v[2]); o[3] = rne16(v[3]);
    *((v4u*)XB + i) = o;
  }
}

// ---------------------------------------------------------------- CSR build
__global__ void hist_kernel(const int* __restrict__ dst,
                            const int* __restrict__ he_node,
                            const int* __restrict__ he_edge,
                            int* cnt_dst, int* cnt_he, int* cnt_hn) {
  int i = blockIdx.x * blockDim.x + threadIdx.x;
  if (i < N_EDGE) atomicAdd(&cnt_dst[dst[i]], 1);
  if (i < N_INC) {
    atomicAdd(&cnt_he[he_edge[i]], 1);
    atomicAdd(&cnt_hn[he_node[i]], 1);
  }
}

// shfl-based block scan, 4 elems/thread, 3 barriers/chunk; fuses the
// reciprocal-scale computation (deg_inv/binv/dinv) into the count load.
__global__ void scan3_kernel(const int* cnt_dst, int* adj_off, int* adj_cur, float* deg_inv,
                             const int* cnt_he, int* heg_off, int* heg_cur, float* binv,
                             const int* cnt_hn, int* hng_off, int* hng_cur, float* dinv) {
  const int* cnt; int* off; int* cur; float* scl; int n, mode;
  if (blockIdx.x == 0)      { cnt = cnt_dst; off = adj_off; cur = adj_cur; scl = deg_inv; n = N_NODES; mode = 0; }
  else if (blockIdx.x == 1) { cnt = cnt_he;  off = heg_off; cur = heg_cur; scl = binv;    n = N_HE;    mode = 1; }
  else                      { cnt = cnt_hn;  off = hng_off; cur = hng_cur; scl = dinv;    n = N_NODES; mode = 1; }
  __shared__ int ws[16];
  int t = threadIdx.x;               // 1024 threads
  int lane = t & 63, wave = t >> 6;
  int carry = 0;
  for (int base = 0; base < n; base += 4096) {
    int i0 = base + t * 4;
    int a[4];
#pragma unroll
    for (int k = 0; k < 4; ++k) {
      int i = i0 + k;
      a[k] = (i < n) ? cnt[i] : 0;
      if (i < n) {
        if (mode == 0) scl[i] = 1.0f / (float)(a[k] > 1 ? a[k] : 1);
        else scl[i] = a[k] > 0 ? 1.0f / (float)a[k] : 0.f;
      }
    }
    int tsum = a[0] + a[1] + a[2] + a[3];
    int val = tsum;
#pragma unroll
    for (int d = 1; d < 64; d <<= 1) {
      int x = __shfl_up(val, d);
      if (lane >= d) val += x;
    }
    if (lane == 63) ws[wave] = val;
    __syncthreads();
    if (wave == 0 && lane < 16) {
      int w = ws[lane];
#pragma unroll
      for (int d = 1; d < 16; d <<= 1) {
        int x = __shfl_up(w, d);
        if (lane >= d) w += x;
      }
      ws[lane] = w;
    }
    __syncthreads();
    int wexcl = wave ? ws[wave - 1] : 0;
    int e = carry + wexcl + (val - tsum);
#pragma unroll
    for (int k = 0; k < 4; ++k) {
      int i = i0 + k;
      if (i < n) { off[i] = e; cur[i] = e; }
      e += a[k];
    }
    carry += ws[15];
    __syncthreads();
  }
  if (t == 0) off[n] = carry;
}

__global__ void fill_kernel(const int* __restrict__ src, const int* __restrict__ dst,
                            const int* __restrict__ he_node, const int* __restrict__ he_edge,
                            int* adj_cur, uint16_t* adj_src,
                            int* heg_cur, uint16_t* heg_node,
                            int* hng_cur, uint16_t* hng_edge) {
  int i = blockIdx.x * blockDim.x + threadIdx.x;
  if (i < N_EDGE) {
    int p = atomicAdd(&adj_cur[dst[i]], 1);
    adj_src[p] = (uint16_t)src[i];
  }
  if (i < N_INC) {
    int p = atomicAdd(&heg_cur[he_edge[i]], 1);
    heg_node[p] = (uint16_t)he_node[i];
    int p2 = atomicAdd(&hng_cur[he_node[i]], 1);
    hng_edge[p2] = (uint16_t)he_edge[i];
  }
}

// ------------------------------- gather-mean row body (uint16 CSR idx)
// OUT[row,:] = rne16( act( scale[row] * sum_j X[idx[j],:] + bias ) )
template <int F>
__device__ inline void agg_row(const int* __restrict__ off, const uint16_t* __restrict__ idx,
                               const float* __restrict__ scale,
                               const uint16_t* __restrict__ X,
                               uint16_t* __restrict__ OUT, int row,
                               const float* __restrict__ bias, int do_relu) {
  constexpr int VEC = (F >= 256) ? 4 : 2;
  int t = threadIdx.x;
  if (t * VEC >= F) return;
  int j0 = off[row], j1 = off[row + 1];
  float sc = scale[row];
  float acc[VEC];
#pragma unroll
  for (int k = 0; k < VEC; ++k) acc[k] = 0.f;

  int j = j0;
  for (; j + 7 < j1; j += 8) {
    int s[8];
#pragma unroll
    for (int u = 0; u < 8; ++u) s[u] = idx[j + u];
    if (VEC == 4) {
      v4u v[8];
#pragma unroll
      for (int u = 0; u < 8; ++u) v[u] = *(const v4u*)(X + (size_t)s[u] * F + t * 4);
#pragma unroll
      for (int u = 0; u < 8; ++u)
#pragma unroll
        for (int k = 0; k < 4; ++k) acc[k] += bfh(v[u][k]);
    } else {
      v2u v[8];
#pragma unroll
      for (int u = 0; u < 8; ++u) v[u] = *(const v2u*)(X + (size_t)s[u] * F + t * 2);
#pragma unroll
      for (int u = 0; u < 8; ++u)
#pragma unroll
        for (int k = 0; k < 2; ++k) acc[k] += bfh(v[u][k]);
    }
  }
  for (; j < j1; ++j) {
    int s = idx[j];
    if (VEC == 4) {
      v4u a = *(const v4u*)(X + (size_t)s * F + t * 4);
#pragma unroll
      for (int k = 0; k < 4; ++k) acc[k] += bfh(a[k]);
    } else {
      v2u a = *(const v2u*)(X + (size_t)s * F + t * 2);
#pragma unroll
      for (int k = 0; k < 2; ++k) acc[k] += bfh(a[k]);
    }
  }

  if (VEC == 4) {
    v4u o;
#pragma unroll
    for (int k = 0; k < 4; ++k) {
      float v = acc[k] * sc;
      if (bias) { v += bias[t * 4 + k]; if (do_relu) v = fmaxf(v, 0.f); }
      o[k] = rne16(v);
    }
    *(v4u*)(OUT + (size_t)row * F + t * 4) = o;
  } else {
    v2u o;
#pragma unroll
    for (int k = 0; k < 2; ++k) {
      float v = acc[k] * sc;
      if (bias) { v += bias[t * 2 + k]; if (do_relu) v = fmaxf(v, 0.f); }
      o[k] = rne16(v);
    }
    *(v2u*)(OUT + (size_t)row * F + t * 2) = o;
  }
}

template <int F>
__global__ void aggb_kernel(const int* __restrict__ off, const uint16_t* __restrict__ idx,
                            const float* __restrict__ scale,
                            const uint16_t* __restrict__ X,
                            uint16_t* __restrict__ OUT,
                            const float* __restrict__ bias, int do_relu) {
  agg_row<F>(off, idx, scale, X, OUT, blockIdx.x, bias, do_relu);
}

// merged: SAGE node-agg (rows [0,n1)) + hyper he-agg (rows [n1, n1+n2)), same table X
template <int F>
__global__ void agg2b_kernel(const int* __restrict__ off1, const uint16_t* __restrict__ idx1,
                             const float* __restrict__ sc1, uint16_t* __restrict__ OUT1, int n1,
                             const int* __restrict__ off2, const uint16_t* __restrict__ idx2,
                             const float* __restrict__ sc2, uint16_t* __restrict__ OUT2,
                             const uint16_t* __restrict__ X) {
  int row = blockIdx.x;
  if (row < n1) agg_row<F>(off1, idx1, sc1, X, OUT1, row, nullptr, 0);
  else          agg_row<F>(off2, idx2, sc2, X, OUT2, row - n1, nullptr, 0);
}

// Hyper tail: XCAT[:,40:] = dinv*agg(EF40) + bias   (f32 out)
__global__ void agg40b_kernel(const int* __restrict__ off, const uint16_t* __restrict__ idx,
                              const float* __restrict__ scale,
                              const uint16_t* __restrict__ EF40,
                              const float* __restrict__ bias,
                              float* __restrict__ XCAT) {
  int row = blockIdx.x;
  int t = threadIdx.x;
  if (t >= 20) return;
  int j0 = off[row], j1 = off[row + 1];
  float sc = scale[row];
  float a0 = 0.f, a1 = 0.f;
  for (int j = j0; j < j1; ++j) {
    int s = idx[j];
    v2u v = *(const v2u*)(EF40 + (size_t)s * 40 + t * 2);
    a0 += bfh(v[0]);
    a1 += bfh(v[1]);
  }
  XCAT[(size_t)row * 80 + 40 + t * 2]     = a0 * sc + bias[t * 2];
  XCAT[(size_t)row * 80 + 40 + t * 2 + 1] = a1 * sc + bias[t * 2 + 1];
}

// SAGE tail: XCAT[:, :40] = deg_inv*agg(T40a) + T40b
__global__ void agg40s_kernel(const int* __restrict__ off, const uint16_t* __restrict__ idx,
                              const float* __restrict__ scale,
                              const uint16_t* __restrict__ T40a,
                              const uint16_t* __restrict__ T40b,
                              float* __restrict__ XCAT) {
  int row = blockIdx.x;
  int t = threadIdx.x;
  if (t >= 20) return;
  int j0 = off[row], j1 = off[row + 1];
  float sc = scale[row];
  float a0 = 0.f, a1 = 0.f;
  for (int j = j0; j < j1; ++j) {
    int s = idx[j];
    v2u v = *(const v2u*)(T40a + (size_t)s * 40 + t * 2);
    a0 += bfh(v[0]);
    a1 += bfh(v[1]);
  }
  v2u b = *(const v2u*)(T40b + (size_t)row * 40 + t * 2);
  XCAT[(size_t)row * 80 + t * 2]     = a0 * sc + bfh(b[0]);
  XCAT[(size_t)row * 80 + t * 2 + 1] = a1 * sc + bfh(b[1]);
}

// ------------------------------------- bf16-A, split-W LDS-staged MFMA GEMM
// A/B frag: row|col = lane&15, k = (lane>>4)*8+j.  C/D: col = lane&15,
// row = (lane>>4)*4 + reg  (verified gfx950 mappings).
template <int K1, int K2, int F, bool OUTBF>
__global__ __launch_bounds__(256, 4) void lin2b_kernel(
    const uint16_t* __restrict__ X1, const uint16_t* __restrict__ W1h, const uint16_t* __restrict__ W1l,
    const uint16_t* __restrict__ X2, const uint16_t* __restrict__ W2h, const uint16_t* __restrict__ W2l,
    const float* __restrict__ bias, const uint16_t* __restrict__ addin,
    void* __restrict__ OUTP, int out_ld, int N, int do_relu) {
  constexpr int FP  = (F + 15) & ~15;
  constexpr int NF  = FP / 16;
  constexpr int NC1 = K1 / 32;
  constexpr int NCH = (K1 + (K2 > 0 ? K2 : 0)) / 32;
  constexpr int RS  = 40;
  __shared__ short sW[2][FP][RS];

  int tid  = threadIdx.x;
  int wave = tid >> 6, lane = tid & 63;
  int r = lane & 15, q = lane >> 4;
  int row0 = blockIdx.x * 64 + wave * 16;
  int rowA = row0 + r; if (rowA > N - 1) rowA = N - 1;

  int srow = tid >> 2;
  int sj   = tid & 3;

  v4f acc[NF];
#pragma unroll
  for (int i = 0; i < NF; ++i) acc[i] = (v4f){0.f, 0.f, 0.f, 0.f};

  for (int c = 0; c < NCH; ++c) {
    const bool first = (K2 == 0) || (c < NC1);
    const uint16_t* Wh = first ? W1h : W2h;
    const uint16_t* Wl = first ? W1l : W2l;
    const uint16_t* Xs = first ? X1 : X2;
    const int K  = first ? K1 : K2;
    const int kc = (first ? c : c - NC1) * 32;

    if (c) __syncthreads();
    const v8s zz = {0, 0, 0, 0, 0, 0, 0, 0};
#pragma unroll
    for (int pass = 0; pass < (FP + 63) / 64; ++pass) {
      int row = srow + pass * 64;
      if (row < FP) {
        v8s hv = zz, lv = zz;
        if (row < F) {
          hv = *reinterpret_cast<const v8s*>(Wh + (size_t)row * K + kc + sj * 8);
          lv = *reinterpret_cast<const v8s*>(Wl + (size_t)row * K + kc + sj * 8);
        }
        *reinterpret_cast<v8s*>(&sW[0][row][sj * 8]) = hv;
        *reinterpret_cast<v8s*>(&sW[1][row][sj * 8]) = lv;
      }
    }
    v8s ah = *reinterpret_cast<const v8s*>(Xs + (size_t)rowA * K + kc + q * 8);
    __syncthreads();
#pragma unroll
    for (int ft = 0; ft < NF; ++ft) {
      v8s bh = *reinterpret_cast<const v8s*>(&sW[0][ft * 16 + r][q * 8]);
      v8s bl = *reinterpret_cast<const v8s*>(&sW[1][ft * 16 + r][q * 8]);
      acc[ft] = __builtin_amdgcn_mfma_f32_16x16x32_bf16(ah, bh, acc[ft], 0, 0, 0);
      acc[ft] = __builtin_amdgcn_mfma_f32_16x16x32_bf16(ah, bl, acc[ft], 0, 0, 0);
    }
  }

#pragma unroll
  for (int ft = 0; ft < NF; ++ft) {
    int col = ft * 16 + r;
    if (col < F) {
      float bv = bias ? bias[col] : 0.f;
#pragma unroll
      for (int i = 0; i < 4; ++i) {
        int row = row0 + q * 4 + i;
        if (row < N) {
          float v = acc[ft][i] + bv;
          if (addin) v += bfh(addin[(size_t)row * F + col]);
          if (do_relu) v = fmaxf(v, 0.f);
          size_t o = (size_t)row * out_ld + col;
          if (OUTBF) ((uint16_t*)OUTP)[o] = rne16(v);
          else ((float*)OUTP)[o] = v;
        }
      }
    }
  }
}

// Dual-output 40-col GEMM (K=256): OUT1 = X*W1^T, OUT2 = X*W2^T + b2.
__global__ __launch_bounds__(256, 4) void lin40ab_kernel(
    const uint16_t* __restrict__ X,
    const uint16_t* __restrict__ W1h, const uint16_t* __restrict__ W1l,
    const uint16_t* __restrict__ W2h, const uint16_t* __restrict__ W2l,
    const float* __restrict__ bias2,
    uint16_t* __restrict__ OUT1, uint16_t* __restrict__ OUT2, int N) {
  constexpr int K = 256, F = 40, FP = 48, NF = 3, RS = 40;
  __shared__ short sW[2][2][FP][RS];

  int tid  = threadIdx.x;
  int wave = tid >> 6, lane = tid & 63;
  int r = lane & 15, q = lane >> 4;
  int row0 = blockIdx.x * 64 + wave * 16;
  int rowA = row0 + r; if (rowA > N - 1) rowA = N - 1;
  int srow = tid >> 2, sj = tid & 3;

  v4f acc[2][NF];
#pragma unroll
  for (int w = 0; w < 2; ++w)
#pragma unroll
    for (int i = 0; i < NF; ++i) acc[w][i] = (v4f){0.f, 0.f, 0.f, 0.f};

  for (int c = 0; c < K / 32; ++c) {
    int kc = c * 32;
    if (c) __syncthreads();
    if (srow < FP) {
      const v8s zz = {0, 0, 0, 0, 0, 0, 0, 0};
      v8s a = zz, b = zz, cc = zz, d = zz;
      if (srow < F) {
        a  = *reinterpret_cast<const v8s*>(W1h + (size_t)srow * K + kc + sj * 8);
        b  = *reinterpret_cast<const v8s*>(W1l + (size_t)srow * K + kc + sj * 8);
        cc = *reinterpret_cast<const v8s*>(W2h + (size_t)srow * K + kc + sj * 8);
        d  = *reinterpret_cast<const v8s*>(W2l + (size_t)srow * K + kc + sj * 8);
      }
      *reinterpret_cast<v8s*>(&sW[0][0][srow][sj * 8]) = a;
      *reinterpret_cast<v8s*>(&sW[0][1][srow][sj * 8]) = b;
      *reinterpret_cast<v8s*>(&sW[1][0][srow][sj * 8]) = cc;
      *reinterpret_cast<v8s*>(&sW[1][1][srow][sj * 8]) = d;
    }
    v8s ah = *reinterpret_cast<const v8s*>(X + (size_t)rowA * K + kc + q * 8);
    __syncthreads();
#pragma unroll
    for (int w = 0; w < 2; ++w)
#pragma unroll
      for (int ft = 0; ft < NF; ++ft) {
        v8s bh = *reinterpret_cast<const v8s*>(&sW[w][0][ft * 16 + r][q * 8]);
        v8s bl = *reinterpret_cast<const v8s*>(&sW[w][1][ft * 16 + r][q * 8]);
        acc[w][ft] = __builtin_amdgcn_mfma_f32_16x16x32_bf16(ah, bh, acc[w][ft], 0, 0, 0);
        acc[w][ft] = __builtin_amdgcn_mfma_f32_16x16x32_bf16(ah, bl, acc[w][ft], 0, 0, 0);
      }
  }

#pragma unroll
  for (int ft = 0; ft < NF; ++ft) {
    int col = ft * 16 + r;
    if (col < F) {
      float bv = bias2[col];
#pragma unroll
      for (int i = 0; i < 4; ++i) {
        int row = row0 + q * 4 + i;
        if (row < N) {
          OUT1[(size_t)row * F + col] = rne16(acc[0][ft][i]);
          OUT2[(size_t)row * F + col] = rne16(acc[1][ft][i] + bv);
        }
      }
    }
  }
}

// ---------------------------------------------------- final linear + logsoftmax
__global__ __launch_bounds__(256) void final_ls_kernel(
    const float* __restrict__ XCAT, const float* __restrict__ lpw,
    const float* __restrict__ lpb, float* __restrict__ out) {
  int wid = (blockIdx.x * 256 + threadIdx.x) >> 6;
  int lane = threadIdx.x & 63;
  if (wid >= N_NODES) return;
  const float* xr = XCAT + (size_t)wid * 80;
  float logit = -1e30f;
  if (lane < 40) {
    float s = lpb[lane];
    const float* wr = lpw + lane * 80;
#pragma unroll 8
    for (int k = 0; k < 80; ++k) s += xr[k] * wr[k];
    logit = s;
  }
  float m = logit;
#pragma unroll
  for (int d = 1; d < 64; d <<= 1) m = fmaxf(m, __shfl_xor(m, d));
  float e = (lane < 40) ? __expf(logit - m) : 0.f;
  float ssum = e;
#pragma unroll
  for (int d = 1; d < 64; d <<= 1) ssum += __shfl_xor(ssum, d);
  if (lane < 40)
    out[(size_t)wid * 40 + lane] = logit - m - __logf(ssum);
}

// ---------------------------------------------------------------- launcher
extern "C" void kernel_launch(void* const* d_in, const int* in_sizes, int n_in,
                              void* d_out, int out_size, void* d_ws, size_t ws_size,
                              hipStream_t stream) {
  const float* x      = (const float*)d_in[0];
  const int* src      = (const int*)d_in[1];
  const int* dst      = (const int*)d_in[2];
  const int* he_node  = (const int*)d_in[3];
  const int* he_edge  = (const int*)d_in[4];
  const float* s0wl = (const float*)d_in[5],  *s0wr = (const float*)d_in[6],  *s0b = (const float*)d_in[7];
  const float* s1wl = (const float*)d_in[8],  *s1wr = (const float*)d_in[9],  *s1b = (const float*)d_in[10];
  const float* s2wl = (const float*)d_in[11], *s2wr = (const float*)d_in[12], *s2b = (const float*)d_in[13];
  const float* h0w = (const float*)d_in[14], *h0b = (const float*)d_in[15];
  const float* h1w = (const float*)d_in[16], *h1b = (const float*)d_in[17];
  const float* h2w = (const float*)d_in[18], *h2b = (const float*)d_in[19];
  const float* h3w = (const float*)d_in[20], *h3b = (const float*)d_in[21];
  const float* h4w = (const float*)d_in[22], *h4b = (const float*)d_in[23];
  const float* lpw = (const float*)d_in[24], *lpb = (const float*)d_in[25];
  float* out = (float*)d_out;

  char* p = (char*)d_ws;
  auto carve = [&](size_t bytes) -> char* {
    char* r = p;
    p += (bytes + 255) & ~(size_t)255;
    return r;
  };
  int* cnt_dst  = (int*)carve((size_t)N_NODES * 4);
  int* adj_off  = (int*)carve((size_t)(N_NODES + 1) * 4);
  int* adj_cur  = (int*)carve((size_t)N_NODES * 4);
  uint16_t* adj_src  = (uint16_t*)carve((size_t)N_EDGE * 2);
  int* cnt_he   = (int*)carve((size_t)N_HE * 4);
  int* heg_off  = (int*)carve((size_t)(N_HE + 1) * 4);
  int* heg_cur  = (int*)carve((size_t)N_HE * 4);
  uint16_t* heg_node = (uint16_t*)carve((size_t)N_INC * 2);
  int* cnt_hn   = (int*)carve((size_t)N_NODES * 4);
  int* hng_off  = (int*)carve((size_t)(N_NODES + 1) * 4);
  int* hng_cur  = (int*)carve((size_t)N_NODES * 4);
  uint16_t* hng_edge = (uint16_t*)carve((size_t)N_INC * 2);
  float* deg_inv = (float*)carve((size_t)N_NODES * 4);
  float* binv    = (float*)carve((size_t)N_HE * 4);
  float* dinv    = (float*)carve((size_t)N_NODES * 4);
  uint16_t* Wh = (uint16_t*)carve((size_t)W_TOTAL * 2);
  uint16_t* Wl = (uint16_t*)carve((size_t)W_TOTAL * 2);
  uint16_t* XB = (uint16_t*)carve((size_t)N_NODES * 128 * 2);
  uint16_t* U  = (uint16_t*)carve((size_t)N_NODES * 128 * 2);
  uint16_t* NA = (uint16_t*)carve((size_t)N_NODES * 256 * 2);
  uint16_t* NB = (uint16_t*)carve((size_t)N_NODES * 256 * 2);
  uint16_t* NC = (uint16_t*)carve((size_t)N_NODES * 256 * 2);
  uint16_t* EFa = (uint16_t*)carve((size_t)N_HE * 256 * 2);
  uint16_t* EFb = (uint16_t*)carve((size_t)N_HE * 256 * 2);
  uint16_t* T40 = (uint16_t*)carve((size_t)N_NODES * 40 * 2);
  uint16_t* T40B = (uint16_t*)carve((size_t)N_NODES * 40 * 2);
  uint16_t* T40H = (uint16_t*)carve((size_t)N_NODES * 40 * 2);
  float* XCAT = (float*)carve((size_t)N_NODES * 80 * 4);

  const int GE = (N_EDGE + 255) / 256;
  const int GL = (N_NODES + 63) / 64;
  const int GS = (N_HE + 63) / 64;

  // ---- prep (zero + weight split + x cvt) and CSR build
  prep_kernel<<<8445, 256, 0, stream>>>(cnt_dst, cnt_he, cnt_hn,
                                        s0wl, s0wr, s1wl, s1wr, s2wl, s2wr,
                                        h0w, h1w, h2w, h3w, h4w, Wh, Wl, x, XB);
  hist_kernel<<<GE, 256, 0, stream>>>(dst, he_node, he_edge, cnt_dst, cnt_he, cnt_hn);
  scan3_kernel<<<3, 1024, 0, stream>>>(cnt_dst, adj_off, adj_cur, deg_inv,
                                       cnt_he, heg_off, heg_cur, binv,
                                       cnt_hn, hng_off, hng_cur, dinv);
  fill_kernel<<<GE, 256, 0, stream>>>(src, dst, he_node, he_edge,
                                      adj_cur, adj_src, heg_cur, heg_node,
                                      hng_cur, hng_edge);

  // ---- merged layer-0 gathers (SAGE node-agg + hyper he-agg, both from XB)
  agg2b_kernel<128><<<N_NODES + N_HE, 64, 0, stream>>>(
      adj_off, adj_src, deg_inv, U, N_NODES,
      heg_off, heg_node, binv, EFa, XB);

  // ---- SAGE branch
  lin2b_kernel<128, 128, 256, true><<<GL, 256, 0, stream>>>(
      U, Wh + 0, Wl + 0, XB, Wh + 32768, Wl + 32768, s0b, nullptr, NA, 256, N_NODES, 1);
  aggb_kernel<256><<<N_NODES, 64, 0, stream>>>(adj_off, adj_src, deg_inv, NA, NB, nullptr, 0);
  lin2b_kernel<256, 256, 256, true><<<GL, 256, 0, stream>>>(
      NB, Wh + 65536, Wl + 65536, NA, Wh + 131072, Wl + 131072, s1b, nullptr, NC, 256, N_NODES, 1);
  lin40ab_kernel<<<GL, 256, 0, stream>>>(
      NC, Wh + 196608, Wl + 196608, Wh + 206848, Wl + 206848, s2b, T40, T40B, N_NODES);
  agg40s_kernel<<<N_NODES, 64, 0, stream>>>(adj_off, adj_src, deg_inv, T40, T40B, XCAT);

  // ---- Hypergraph branch: heagg -> tiny GEMM (5000 rows) -> nodeagg+bias+relu
  lin2b_kernel<128, 0, 256, true><<<GS, 256, 0, stream>>>(
      EFa, Wh + 217088, Wl + 217088, nullptr, nullptr, nullptr, nullptr, nullptr, EFb, 256, N_HE, 0);
  aggb_kernel<256><<<N_NODES, 64, 0, stream>>>(hng_off, hng_edge, dinv, EFb, NC, h0b, 1);

  aggb_kernel<256><<<N_HE, 64, 0, stream>>>(heg_off, heg_node, binv, NC, EFa, nullptr, 0);
  lin2b_kernel<256, 0, 256, true><<<GS, 256, 0, stream>>>(
      EFa, Wh + 249856, Wl + 249856, nullptr, nullptr, nullptr, nullptr, nullptr, EFb, 256, N_HE, 0);
  aggb_kernel<256><<<N_NODES, 64, 0, stream>>>(hng_off, hng_edge, dinv, EFb, NC, h1b, 1);

  aggb_kernel<256><<<N_HE, 64, 0, stream>>>(heg_off, heg_node, binv, NC, EFa, nullptr, 0);
  lin2b_kernel<256, 0, 256, true><<<GS, 256, 0, stream>>>(
      EFa, Wh + 315392, Wl + 315392, nullptr, nullptr, nullptr, nullptr, nullptr, EFb, 256, N_HE, 0);
  aggb_kernel<256><<<N_NODES, 64, 0, stream>>>(hng_off, hng_edge, dinv, EFb, NC, h2b, 1);

  aggb_kernel<256><<<N_HE, 64, 0, stream>>>(heg_off, heg_node, binv, NC, EFa, nullptr, 0);
  lin2b_kernel<256, 0, 256, true><<<GS, 256, 0, stream>>>(
      EFa, Wh + 380928, Wl + 380928, nullptr, nullptr, nullptr, nullptr, nullptr, EFb, 256, N_HE, 0);
  aggb_kernel<256><<<N_NODES, 64, 0, stream>>>(hng_off, hng_edge, dinv, EFb, NC, h3b, 1);

  // layer 4 (F=40): transform node features first, then two aggs
  lin2b_kernel<256, 0, 40, true><<<GL, 256, 0, stream>>>(
      NC, Wh + 446464, Wl + 446464, nullptr, nullptr, nullptr, nullptr, nullptr, T40H, 40, N_NODES, 0);
  aggb_kernel<40><<<N_HE, 64, 0, stream>>>(heg_off, heg_node, binv, T40H, EFa, nullptr, 0);
  agg40b_kernel<<<N_NODES, 64, 0, stream>>>(hng_off, hng_edge, dinv, EFa, h4b, XCAT);

  // ---- final linear + log_softmax
  final_ls_kernel<<<(N_NODES + 3) / 4, 256, 0, stream>>>(XCAT, lpw, lpb, out);
}

// Round 11
// 1007.091 us; speedup vs baseline: 1.2212x; 1.0533x over previous
//
#include <hip/hip_runtime.h>
#include <hip/hip_bf16.h>
#include <cstdint>
#include <cstddef>

typedef __hip_bfloat16 bf16;
typedef short v8s __attribute__((ext_vector_type(8)));
typedef float v4f __attribute__((ext_vector_type(4)));
typedef unsigned short v8u __attribute__((ext_vector_type(8)));
typedef unsigned short v4u __attribute__((ext_vector_type(4)));
typedef unsigned short v2u __attribute__((ext_vector_type(2)));

#define N_NODES 50000
#define N_HE    5000
#define N_EDGE  800000
#define N_INC   400000
#define W_TOTAL 456704
#define NBREL   275   // 98 adj + 79 heg + 98 hng bucket cursors

__device__ inline float bfh(uint32_t u) { return __uint_as_float(u << 16); }
__device__ inline uint16_t rne16(float f) {
  uint32_t u = __float_as_uint(f);
  return (uint16_t)((u + 0x7FFFu + ((u >> 16) & 1u)) >> 16);
}

// ---------------- prep: zero counters+bucket cursors + split weights + cvt x
// blocks [0,412): zero 105275 ints; [412,2196): split_w; [2196,8446): cvt.
__global__ void prep_kernel(int* cnt_dst, int* cnt_he, int* cnt_hn, int* brel,
                            const float* s0wl, const float* s0wr,
                            const float* s1wl, const float* s1wr,
                            const float* s2wl, const float* s2wr,
                            const float* h0w, const float* h1w,
                            const float* h2w, const float* h3w, const float* h4w,
                            uint16_t* hi, uint16_t* lo,
                            const float* X, uint16_t* XB) {
  int b = blockIdx.x;
  if (b < 412) {
    int i = b * 256 + threadIdx.x;
    if (i < N_NODES) cnt_dst[i] = 0;
    else if (i < N_NODES + N_HE) cnt_he[i - N_NODES] = 0;
    else if (i < 2 * N_NODES + N_HE) cnt_hn[i - N_NODES - N_HE] = 0;
    else if (i < 2 * N_NODES + N_HE + NBREL) brel[i - 2 * N_NODES - N_HE] = 0;
    return;
  }
  if (b < 2196) {
    int i = (b - 412) * 256 + threadIdx.x;
    if (i >= W_TOTAL) return;
    const float* src; int base;
    if (i < 32768)       { src = s0wl; base = 0; }
    else if (i < 65536)  { src = s0wr; base = 32768; }
    else if (i < 131072) { src = s1wl; base = 65536; }
    else if (i < 196608) { src = s1wr; base = 131072; }
    else if (i < 206848) { src = s2wl; base = 196608; }
    else if (i < 217088) { src = s2wr; base = 206848; }
    else if (i < 249856) { src = h0w;  base = 217088; }
    else if (i < 315392) { src = h1w;  base = 249856; }
    else if (i < 380928) { src = h2w;  base = 315392; }
    else if (i < 446464) { src = h3w;  base = 380928; }
    else                 { src = h4w;  base = 446464; }
    float v = src[i - base];
    uint16_t hb = rne16(v);
    hi[i] = hb;
    lo[i] = rne16(v - bfh(hb));
    return;
  }
  {
    int i = (b - 2196) * 256 + threadIdx.x;   // v4 index
    if (i >= N_NODES * 32) return;
    v4f v = *((const v4f*)X + i);
    v4u o;
    o[0] = rne16(v[0]); o[1] = rne16(v[1]); o[2] = rne16(v[2]); o[3] = rne16(v[3]);
    *((v4u*)XB + i) = o;
  }
}

// ---------------------------------------------------------------- CSR build
__global__ void hist_kernel(const int* __restrict__ dst,
                            const int* __restrict__ he_node,
                            const int* __restrict__ he_edge,
                            int* cnt_dst, int* cnt_he, int* cnt_hn) {
  int i = blockIdx.x * blockDim.x + threadIdx.x;
  if (i < N_EDGE) atomicAdd(&cnt_dst[dst[i]], 1);
  if (i < N_INC) {
    atomicAdd(&cnt_he[he_edge[i]], 1);
    atomicAdd(&cnt_hn[he_node[i]], 1);
  }
}

// shfl-based block scan (4 elems/thread) + fused reciprocal scales.
__global__ void scan3_kernel(const int* cnt_dst, int* adj_off, float* deg_inv,
                             const int* cnt_he, int* heg_off, float* binv,
                             const int* cnt_hn, int* hng_off, float* dinv) {
  const int* cnt; int* off; float* scl; int n, mode;
  if (blockIdx.x == 0)      { cnt = cnt_dst; off = adj_off; scl = deg_inv; n = N_NODES; mode = 0; }
  else if (blockIdx.x == 1) { cnt = cnt_he;  off = heg_off; scl = binv;    n = N_HE;    mode = 1; }
  else                      { cnt = cnt_hn;  off = hng_off; scl = dinv;    n = N_NODES; mode = 1; }
  __shared__ int ws[16];
  int t = threadIdx.x;               // 1024 threads
  int lane = t & 63, wave = t >> 6;
  int carry = 0;
  for (int base = 0; base < n; base += 4096) {
    int i0 = base + t * 4;
    int a[4];
#pragma unroll
    for (int k = 0; k < 4; ++k) {
      int i = i0 + k;
      a[k] = (i < n) ? cnt[i] : 0;
      if (i < n) {
        if (mode == 0) scl[i] = 1.0f / (float)(a[k] > 1 ? a[k] : 1);
        else scl[i] = a[k] > 0 ? 1.0f / (float)a[k] : 0.f;
      }
    }
    int tsum = a[0] + a[1] + a[2] + a[3];
    int val = tsum;
#pragma unroll
    for (int d = 1; d < 64; d <<= 1) {
      int x = __shfl_up(val, d);
      if (lane >= d) val += x;
    }
    if (lane == 63) ws[wave] = val;
    __syncthreads();
    if (wave == 0 && lane < 16) {
      int w = ws[lane];
#pragma unroll
      for (int d = 1; d < 16; d <<= 1) {
        int x = __shfl_up(w, d);
        if (lane >= d) w += x;
      }
      ws[lane] = w;
    }
    __syncthreads();
    int wexcl = wave ? ws[wave - 1] : 0;
    int e = carry + wexcl + (val - tsum);
#pragma unroll
    for (int k = 0; k < 4; ++k) {
      int i = i0 + k;
      if (i < n) off[i] = e;
      e += a[k];
    }
    carry += ws[15];
    __syncthreads();
  }
  if (t == 0) off[n] = carry;
}

// ---------------- binned two-phase fill (kills scatter write amplification)
// Pass A: per-block LDS binning -> bucket-contiguous staged (pay<<16|key) runs.
template <int NB, int SH>
__device__ inline void binA_section(const int* __restrict__ key_arr,
                                    const int* __restrict__ pay_arr, int n, int blk,
                                    const int* __restrict__ off, int nkeys,
                                    int* brel, uint32_t* __restrict__ stg) {
  __shared__ int lcnt[128], lscan[128], lcnt2[128], gbase[128];
  __shared__ uint32_t sstage[4096];
  int t = threadIdx.x;
  int e0 = blk * 4096;
  int cnt = min(4096, n - e0);
  for (int k = t; k < NB; k += 256) { lcnt[k] = 0; lcnt2[k] = 0; }
  __syncthreads();
  for (int k = t; k < cnt; k += 256) atomicAdd(&lcnt[key_arr[e0 + k] >> SH], 1);
  __syncthreads();
  if (t == 0) {
    int s = 0;
    for (int b = 0; b < NB; ++b) { lscan[b] = s; s += lcnt[b]; }
  }
  __syncthreads();
  if (t < NB) {
    int base = off[min(t << SH, nkeys)];
    gbase[t] = base + atomicAdd(&brel[t], lcnt[t]);
  }
  __syncthreads();
  for (int k = t; k < cnt; k += 256) {
    int key = key_arr[e0 + k];
    int pay = pay_arr[e0 + k];
    int b = key >> SH;
    int r = atomicAdd(&lcnt2[b], 1);
    sstage[lscan[b] + r] = ((uint32_t)pay << 16) | (uint32_t)key;
  }
  __syncthreads();
  for (int b = 0; b < NB; ++b) {
    int len = lcnt[b], ls = lscan[b], gb = gbase[b];
    for (int k = t; k < len; k += 256) stg[gb + k] = sstage[ls + k];
  }
}

__global__ __launch_bounds__(256) void binA_kernel(
    const int* __restrict__ src, const int* __restrict__ dst,
    const int* __restrict__ he_node, const int* __restrict__ he_edge,
    const int* __restrict__ adj_off, const int* __restrict__ heg_off,
    const int* __restrict__ hng_off, int* brel,
    uint32_t* stg_adj, uint32_t* stg_heg, uint32_t* stg_hng) {
  int b = blockIdx.x;
  if (b < 196)      binA_section<98, 9>(dst, src, N_EDGE, b, adj_off, N_NODES, brel, stg_adj);
  else if (b < 294) binA_section<79, 6>(he_edge, he_node, N_INC, b - 196, heg_off, N_HE, brel + 98, stg_heg);
  else              binA_section<98, 9>(he_node, he_edge, N_INC, b - 294, hng_off, N_NODES, brel + 177, stg_hng);
}

// Pass B: one block per bucket; LDS cursors; block-private contiguous payload region.
template <int BS, int SH>
__device__ inline void binB_section(int bkt, const int* __restrict__ off, int nkeys,
                                    const uint32_t* __restrict__ stg,
                                    uint16_t* __restrict__ out) {
  __shared__ int lcur[512];
  int t = threadIdx.x;
  int nb0 = bkt << SH;
  int nb1 = min(nb0 + BS, nkeys);
  int nn = nb1 - nb0;
  for (int k = t; k < nn; k += 256) lcur[k] = off[nb0 + k];
  __syncthreads();
  int e0 = off[nb0], e1 = off[nb1];
  for (int e = e0 + t; e < e1; e += 256) {
    uint32_t v = stg[e];
    int key = (int)(v & 0xFFFFu);
    int p = atomicAdd(&lcur[key - nb0], 1);
    out[p] = (uint16_t)(v >> 16);
  }
}

__global__ __launch_bounds__(256) void binB_kernel(
    const int* __restrict__ adj_off, const int* __restrict__ heg_off,
    const int* __restrict__ hng_off,
    const uint32_t* __restrict__ stg_adj, const uint32_t* __restrict__ stg_heg,
    const uint32_t* __restrict__ stg_hng,
    uint16_t* adj_src, uint16_t* heg_node, uint16_t* hng_edge) {
  int b = blockIdx.x;
  if (b < 98)       binB_section<512, 9>(b, adj_off, N_NODES, stg_adj, adj_src);
  else if (b < 177) binB_section<64, 6>(b - 98, heg_off, N_HE, stg_heg, heg_node);
  else              binB_section<512, 9>(b - 177, hng_off, N_NODES, stg_hng, hng_edge);
}

// ------------------------------- gather-mean row body (uint16 CSR idx)
template <int F>
__device__ inline void agg_row(const int* __restrict__ off, const uint16_t* __restrict__ idx,
                               const float* __restrict__ scale,
                               const uint16_t* __restrict__ X,
                               uint16_t* __restrict__ OUT, int row,
                               const float* __restrict__ bias, int do_relu) {
  constexpr int VEC = (F >= 256) ? 4 : 2;
  int t = threadIdx.x;
  if (t * VEC >= F) return;
  int j0 = off[row], j1 = off[row + 1];
  float sc = scale[row];
  float acc[VEC];
#pragma unroll
  for (int k = 0; k < VEC; ++k) acc[k] = 0.f;

  int j = j0;
  for (; j + 7 < j1; j += 8) {
    int s[8];
#pragma unroll
    for (int u = 0; u < 8; ++u) s[u] = idx[j + u];
    if (VEC == 4) {
      v4u v[8];
#pragma unroll
      for (int u = 0; u < 8; ++u) v[u] = *(const v4u*)(X + (size_t)s[u] * F + t * 4);
#pragma unroll
      for (int u = 0; u < 8; ++u)
#pragma unroll
        for (int k = 0; k < 4; ++k) acc[k] += bfh(v[u][k]);
    } else {
      v2u v[8];
#pragma unroll
      for (int u = 0; u < 8; ++u) v[u] = *(const v2u*)(X + (size_t)s[u] * F + t * 2);
#pragma unroll
      for (int u = 0; u < 8; ++u)
#pragma unroll
        for (int k = 0; k < 2; ++k) acc[k] += bfh(v[u][k]);
    }
  }
  for (; j < j1; ++j) {
    int s = idx[j];
    if (VEC == 4) {
      v4u a = *(const v4u*)(X + (size_t)s * F + t * 4);
#pragma unroll
      for (int k = 0; k < 4; ++k) acc[k] += bfh(a[k]);
    } else {
      v2u a = *(const v2u*)(X + (size_t)s * F + t * 2);
#pragma unroll
      for (int k = 0; k < 2; ++k) acc[k] += bfh(a[k]);
    }
  }

  if (VEC == 4) {
    v4u o;
#pragma unroll
    for (int k = 0; k < 4; ++k) {
      float v = acc[k] * sc;
      if (bias) { v += bias[t * 4 + k]; if (do_relu) v = fmaxf(v, 0.f); }
      o[k] = rne16(v);
    }
    *(v4u*)(OUT + (size_t)row * F + t * 4) = o;
  } else {
    v2u o;
#pragma unroll
    for (int k = 0; k < 2; ++k) {
      float v = acc[k] * sc;
      if (bias) { v += bias[t * 2 + k]; if (do_relu) v = fmaxf(v, 0.f); }
      o[k] = rne16(v);
    }
    *(v2u*)(OUT + (size_t)row * F + t * 2) = o;
  }
}

template <int F>
__global__ void aggb_kernel(const int* __restrict__ off, const uint16_t* __restrict__ idx,
                            const float* __restrict__ scale,
                            const uint16_t* __restrict__ X,
                            uint16_t* __restrict__ OUT,
                            const float* __restrict__ bias, int do_relu) {
  agg_row<F>(off, idx, scale, X, OUT, blockIdx.x, bias, do_relu);
}

template <int F>
__global__ void agg2b_kernel(const int* __restrict__ off1, const uint16_t* __restrict__ idx1,
                             const float* __restrict__ sc1, uint16_t* __restrict__ OUT1, int n1,
                             const int* __restrict__ off2, const uint16_t* __restrict__ idx2,
                             const float* __restrict__ sc2, uint16_t* __restrict__ OUT2,
                             const uint16_t* __restrict__ X) {
  int row = blockIdx.x;
  if (row < n1) agg_row<F>(off1, idx1, sc1, X, OUT1, row, nullptr, 0);
  else          agg_row<F>(off2, idx2, sc2, X, OUT2, row - n1, nullptr, 0);
}

// Hyper tail: XCAT[:,40:] = dinv*agg(EF40) + bias   (f32 out)
__global__ void agg40b_kernel(const int* __restrict__ off, const uint16_t* __restrict__ idx,
                              const float* __restrict__ scale,
                              const uint16_t* __restrict__ EF40,
                              const float* __restrict__ bias,
                              float* __restrict__ XCAT) {
  int row = blockIdx.x;
  int t = threadIdx.x;
  if (t >= 20) return;
  int j0 = off[row], j1 = off[row + 1];
  float sc = scale[row];
  float a0 = 0.f, a1 = 0.f;
  for (int j = j0; j < j1; ++j) {
    int s = idx[j];
    v2u v = *(const v2u*)(EF40 + (size_t)s * 40 + t * 2);
    a0 += bfh(v[0]);
    a1 += bfh(v[1]);
  }
  XCAT[(size_t)row * 80 + 40 + t * 2]     = a0 * sc + bias[t * 2];
  XCAT[(size_t)row * 80 + 40 + t * 2 + 1] = a1 * sc + bias[t * 2 + 1];
}

// SAGE tail: XCAT[:, :40] = deg_inv*agg(T40a) + T40b
__global__ void agg40s_kernel(const int* __restrict__ off, const uint16_t* __restrict__ idx,
                              const float* __restrict__ scale,
                              const uint16_t* __restrict__ T40a,
                              const uint16_t* __restrict__ T40b,
                              float* __restrict__ XCAT) {
  int row = blockIdx.x;
  int t = threadIdx.x;
  if (t >= 20) return;
  int j0 = off[row], j1 = off[row + 1];
  float sc = scale[row];
  float a0 = 0.f, a1 = 0.f;
  for (int j = j0; j < j1; ++j) {
    int s = idx[j];
    v2u v = *(const v2u*)(T40a + (size_t)s * 40 + t * 2);
    a0 += bfh(v[0]);
    a1 += bfh(v[1]);
  }
  v2u b = *(const v2u*)(T40b + (size_t)row * 40 + t * 2);
  XCAT[(size_t)row * 80 + t * 2]     = a0 * sc + bfh(b[0]);
  XCAT[(size_t)row * 80 + t * 2 + 1] = a1 * sc + bfh(b[1]);
}

// ------------------------------------- bf16-A, split-W LDS-staged MFMA GEMM
// A/B frag: row|col = lane&15, k = (lane>>4)*8+j.  C/D: col = lane&15,
// row = (lane>>4)*4 + reg  (verified gfx950 mappings).
template <int K1, int K2, int F, bool OUTBF>
__global__ __launch_bounds__(256, 4) void lin2b_kernel(
    const uint16_t* __restrict__ X1, const uint16_t* __restrict__ W1h, const uint16_t* __restrict__ W1l,
    const uint16_t* __restrict__ X2, const uint16_t* __restrict__ W2h, const uint16_t* __restrict__ W2l,
    const float* __restrict__ bias, const uint16_t* __restrict__ addin,
    void* __restrict__ OUTP, int out_ld, int N, int do_relu) {
  constexpr int FP  = (F + 15) & ~15;
  constexpr int NF  = FP / 16;
  constexpr int NC1 = K1 / 32;
  constexpr int NCH = (K1 + (K2 > 0 ? K2 : 0)) / 32;
  constexpr int RS  = 40;
  __shared__ short sW[2][FP][RS];

  int tid  = threadIdx.x;
  int wave = tid >> 6, lane = tid & 63;
  int r = lane & 15, q = lane >> 4;
  int row0 = blockIdx.x * 64 + wave * 16;
  int rowA = row0 + r; if (rowA > N - 1) rowA = N - 1;

  int srow = tid >> 2;
  int sj   = tid & 3;

  v4f acc[NF];
#pragma unroll
  for (int i = 0; i < NF; ++i) acc[i] = (v4f){0.f, 0.f, 0.f, 0.f};

  for (int c = 0; c < NCH; ++c) {
    const bool first = (K2 == 0) || (c < NC1);
    const uint16_t* Wh = first ? W1h : W2h;
    const uint16_t* Wl = first ? W1l : W2l;
    const uint16_t* Xs = first ? X1 : X2;
    const int K  = first ? K1 : K2;
    const int kc = (first ? c : c - NC1) * 32;

    if (c) __syncthreads();
    const v8s zz = {0, 0, 0, 0, 0, 0, 0, 0};
#pragma unroll
    for (int pass = 0; pass < (FP + 63) / 64; ++pass) {
      int row = srow + pass * 64;
      if (row < FP) {
        v8s hv = zz, lv = zz;
        if (row < F) {
          hv = *reinterpret_cast<const v8s*>(Wh + (size_t)row * K + kc + sj * 8);
          lv = *reinterpret_cast<const v8s*>(Wl + (size_t)row * K + kc + sj * 8);
        }
        *reinterpret_cast<v8s*>(&sW[0][row][sj * 8]) = hv;
        *reinterpret_cast<v8s*>(&sW[1][row][sj * 8]) = lv;
      }
    }
    v8s ah = *reinterpret_cast<const v8s*>(Xs + (size_t)rowA * K + kc + q * 8);
    __syncthreads();
#pragma unroll
    for (int ft = 0; ft < NF; ++ft) {
      v8s bh = *reinterpret_cast<const v8s*>(&sW[0][ft * 16 + r][q * 8]);
      v8s bl = *reinterpret_cast<const v8s*>(&sW[1][ft * 16 + r][q * 8]);
      acc[ft] = __builtin_amdgcn_mfma_f32_16x16x32_bf16(ah, bh, acc[ft], 0, 0, 0);
      acc[ft] = __builtin_amdgcn_mfma_f32_16x16x32_bf16(ah, bl, acc[ft], 0, 0, 0);
    }
  }

#pragma unroll
  for (int ft = 0; ft < NF; ++ft) {
    int col = ft * 16 + r;
    if (col < F) {
      float bv = bias ? bias[col] : 0.f;
#pragma unroll
      for (int i = 0; i < 4; ++i) {
        int row = row0 + q * 4 + i;
        if (row < N) {
          float v = acc[ft][i] + bv;
          if (addin) v += bfh(addin[(size_t)row * F + col]);
          if (do_relu) v = fmaxf(v, 0.f);
          size_t o = (size_t)row * out_ld + col;
          if (OUTBF) ((uint16_t*)OUTP)[o] = rne16(v);
          else ((float*)OUTP)[o] = v;
        }
      }
    }
  }
}

// Dual-output 40-col GEMM (K=256): OUT1 = X*W1^T, OUT2 = X*W2^T + b2.
__global__ __launch_bounds__(256, 4) void lin40ab_kernel(
    const uint16_t* __restrict__ X,
    const uint16_t* __restrict__ W1h, const uint16_t* __restrict__ W1l,
    const uint16_t* __restrict__ W2h, const uint16_t* __restrict__ W2l,
    const float* __restrict__ bias2,
    uint16_t* __restrict__ OUT1, uint16_t* __restrict__ OUT2, int N) {
  constexpr int K = 256, F = 40, FP = 48, NF = 3, RS = 40;
  __shared__ short sW[2][2][FP][RS];

  int tid  = threadIdx.x;
  int wave = tid >> 6, lane = tid & 63;
  int r = lane & 15, q = lane >> 4;
  int row0 = blockIdx.x * 64 + wave * 16;
  int rowA = row0 + r; if (rowA > N - 1) rowA = N - 1;
  int srow = tid >> 2, sj = tid & 3;

  v4f acc[2][NF];
#pragma unroll
  for (int w = 0; w < 2; ++w)
#pragma unroll
    for (int i = 0; i < NF; ++i) acc[w][i] = (v4f){0.f, 0.f, 0.f, 0.f};

  for (int c = 0; c < K / 32; ++c) {
    int kc = c * 32;
    if (c) __syncthreads();
    if (srow < FP) {
      const v8s zz = {0, 0, 0, 0, 0, 0, 0, 0};
      v8s a = zz, b = zz, cc = zz, d = zz;
      if (srow < F) {
        a  = *reinterpret_cast<const v8s*>(W1h + (size_t)srow * K + kc + sj * 8);
        b  = *reinterpret_cast<const v8s*>(W1l + (size_t)srow * K + kc + sj * 8);
        cc = *reinterpret_cast<const v8s*>(W2h + (size_t)srow * K + kc + sj * 8);
        d  = *reinterpret_cast<const v8s*>(W2l + (size_t)srow * K + kc + sj * 8);
      }
      *reinterpret_cast<v8s*>(&sW[0][0][srow][sj * 8]) = a;
      *reinterpret_cast<v8s*>(&sW[0][1][srow][sj * 8]) = b;
      *reinterpret_cast<v8s*>(&sW[1][0][srow][sj * 8]) = cc;
      *reinterpret_cast<v8s*>(&sW[1][1][srow][sj * 8]) = d;
    }
    v8s ah = *reinterpret_cast<const v8s*>(X + (size_t)rowA * K + kc + q * 8);
    __syncthreads();
#pragma unroll
    for (int w = 0; w < 2; ++w)
#pragma unroll
      for (int ft = 0; ft < NF; ++ft) {
        v8s bh = *reinterpret_cast<const v8s*>(&sW[w][0][ft * 16 + r][q * 8]);
        v8s bl = *reinterpret_cast<const v8s*>(&sW[w][1][ft * 16 + r][q * 8]);
        acc[w][ft] = __builtin_amdgcn_mfma_f32_16x16x32_bf16(ah, bh, acc[w][ft], 0, 0, 0);
        acc[w][ft] = __builtin_amdgcn_mfma_f32_16x16x32_bf16(ah, bl, acc[w][ft], 0, 0, 0);
      }
  }

#pragma unroll
  for (int ft = 0; ft < NF; ++ft) {
    int col = ft * 16 + r;
    if (col < F) {
      float bv = bias2[col];
#pragma unroll
      for (int i = 0; i < 4; ++i) {
        int row = row0 + q * 4 + i;
        if (row < N) {
          OUT1[(size_t)row * F + col] = rne16(acc[0][ft][i]);
          OUT2[(size_t)row * F + col] = rne16(acc[1][ft][i] + bv);
        }
      }
    }
  }
}

// ---------------------------------------------------- final linear + logsoftmax
__global__ __launch_bounds__(256) void final_ls_kernel(
    const float* __restrict__ XCAT, const float* __restrict__ lpw,
    const float* __restrict__ lpb, float* __restrict__ out) {
  int wid = (blockIdx.x * 256 + threadIdx.x) >> 6;
  int lane = threadIdx.x & 63;
  if (wid >= N_NODES) return;
  const float* xr = XCAT + (size_t)wid * 80;
  float logit = -1e30f;
  if (lane < 40) {
    float s = lpb[lane];
    const float* wr = lpw + lane * 80;
#pragma unroll 8
    for (int k = 0; k < 80; ++k) s += xr[k] * wr[k];
    logit = s;
  }
  float m = logit;
#pragma unroll
  for (int d = 1; d < 64; d <<= 1) m = fmaxf(m, __shfl_xor(m, d));
  float e = (lane < 40) ? __expf(logit - m) : 0.f;
  float ssum = e;
#pragma unroll
  for (int d = 1; d < 64; d <<= 1) ssum += __shfl_xor(ssum, d);
  if (lane < 40)
    out[(size_t)wid * 40 + lane] = logit - m - __logf(ssum);
}

// ---------------------------------------------------------------- launcher
extern "C" void kernel_launch(void* const* d_in, const int* in_sizes, int n_in,
                              void* d_out, int out_size, void* d_ws, size_t ws_size,
                              hipStream_t stream) {
  const float* x      = (const float*)d_in[0];
  const int* src      = (const int*)d_in[1];
  const int* dst      = (const int*)d_in[2];
  const int* he_node  = (const int*)d_in[3];
  const int* he_edge  = (const int*)d_in[4];
  const float* s0wl = (const float*)d_in[5],  *s0wr = (const float*)d_in[6],  *s0b = (const float*)d_in[7];
  const float* s1wl = (const float*)d_in[8],  *s1wr = (const float*)d_in[9],  *s1b = (const float*)d_in[10];
  const float* s2wl = (const float*)d_in[11], *s2wr = (const float*)d_in[12], *s2b = (const float*)d_in[13];
  const float* h0w = (const float*)d_in[14], *h0b = (const float*)d_in[15];
  const float* h1w = (const float*)d_in[16], *h1b = (const float*)d_in[17];
  const float* h2w = (const float*)d_in[18], *h2b = (const float*)d_in[19];
  const float* h3w = (const float*)d_in[20], *h3b = (const float*)d_in[21];
  const float* h4w = (const float*)d_in[22], *h4b = (const float*)d_in[23];
  const float* lpw = (const float*)d_in[24], *lpb = (const float*)d_in[25];
  float* out = (float*)d_out;

  char* p = (char*)d_ws;
  auto carve = [&](size_t bytes) -> char* {
    char* r = p;
    p += (bytes + 255) & ~(size_t)255;
    return r;
  };
  int* cnt_dst  = (int*)carve((size_t)N_NODES * 4);
  int* adj_off  = (int*)carve((size_t)(N_NODES + 1) * 4);
  uint16_t* adj_src  = (uint16_t*)carve((size_t)N_EDGE * 2);
  int* cnt_he   = (int*)carve((size_t)N_HE * 4);
  int* heg_off  = (int*)carve((size_t)(N_HE + 1) * 4);
  uint16_t* heg_node = (uint16_t*)carve((size_t)N_INC * 2);
  int* cnt_hn   = (int*)carve((size_t)N_NODES * 4);
  int* hng_off  = (int*)carve((size_t)(N_NODES + 1) * 4);
  uint16_t* hng_edge = (uint16_t*)carve((size_t)N_INC * 2);
  int* brel     = (int*)carve((size_t)NBREL * 4);
  uint32_t* stg_adj = (uint32_t*)carve((size_t)N_EDGE * 4);
  uint32_t* stg_heg = (uint32_t*)carve((size_t)N_INC * 4);
  uint32_t* stg_hng = (uint32_t*)carve((size_t)N_INC * 4);
  float* deg_inv = (float*)carve((size_t)N_NODES * 4);
  float* binv    = (float*)carve((size_t)N_HE * 4);
  float* dinv    = (float*)carve((size_t)N_NODES * 4);
  uint16_t* Wh = (uint16_t*)carve((size_t)W_TOTAL * 2);
  uint16_t* Wl = (uint16_t*)carve((size_t)W_TOTAL * 2);
  uint16_t* XB = (uint16_t*)carve((size_t)N_NODES * 128 * 2);
  uint16_t* U  = (uint16_t*)carve((size_t)N_NODES * 128 * 2);
  uint16_t* NA = (uint16_t*)carve((size_t)N_NODES * 256 * 2);
  uint16_t* NB_ = (uint16_t*)carve((size_t)N_NODES * 256 * 2);
  uint16_t* NC = (uint16_t*)carve((size_t)N_NODES * 256 * 2);
  uint16_t* EFa = (uint16_t*)carve((size_t)N_HE * 256 * 2);
  uint16_t* EFb = (uint16_t*)carve((size_t)N_HE * 256 * 2);
  uint16_t* T40 = (uint16_t*)carve((size_t)N_NODES * 40 * 2);
  uint16_t* T40B = (uint16_t*)carve((size_t)N_NODES * 40 * 2);
  uint16_t* T40H = (uint16_t*)carve((size_t)N_NODES * 40 * 2);
  float* XCAT = (float*)carve((size_t)N_NODES * 80 * 4);

  const int GE = (N_EDGE + 255) / 256;
  const int GL = (N_NODES + 63) / 64;
  const int GS = (N_HE + 63) / 64;

  // ---- prep (zero + weight split + x cvt) and binned CSR build
  prep_kernel<<<8446, 256, 0, stream>>>(cnt_dst, cnt_he, cnt_hn, brel,
                                        s0wl, s0wr, s1wl, s1wr, s2wl, s2wr,
                                        h0w, h1w, h2w, h3w, h4w, Wh, Wl, x, XB);
  hist_kernel<<<GE, 256, 0, stream>>>(dst, he_node, he_edge, cnt_dst, cnt_he, cnt_hn);
  scan3_kernel<<<3, 1024, 0, stream>>>(cnt_dst, adj_off, deg_inv,
                                       cnt_he, heg_off, binv,
                                       cnt_hn, hng_off, dinv);
  binA_kernel<<<392, 256, 0, stream>>>(src, dst, he_node, he_edge,
                                       adj_off, heg_off, hng_off, brel,
                                       stg_adj, stg_heg, stg_hng);
  binB_kernel<<<275, 256, 0, stream>>>(adj_off, heg_off, hng_off,
                                       stg_adj, stg_heg, stg_hng,
                                       adj_src, heg_node, hng_edge);

  // ---- merged layer-0 gathers (SAGE node-agg + hyper he-agg, both from XB)
  agg2b_kernel<128><<<N_NODES + N_HE, 64, 0, stream>>>(
      adj_off, adj_src, deg_inv, U, N_NODES,
      heg_off, heg_node, binv, EFa, XB);

  // ---- SAGE branch
  lin2b_kernel<128, 128, 256, true><<<GL, 256, 0, stream>>>(
      U, Wh + 0, Wl + 0, XB, Wh + 32768, Wl + 32768, s0b, nullptr, NA, 256, N_NODES, 1);
  aggb_kernel<256><<<N_NODES, 64, 0, stream>>>(adj_off, adj_src, deg_inv, NA, NB_, nullptr, 0);
  lin2b_kernel<256, 256, 256, true><<<GL, 256, 0, stream>>>(
      NB_, Wh + 65536, Wl + 65536, NA, Wh + 131072, Wl + 131072, s1b, nullptr, NC, 256, N_NODES, 1);
  lin40ab_kernel<<<GL, 256, 0, stream>>>(
      NC, Wh + 196608, Wl + 196608, Wh + 206848, Wl + 206848, s2b, T40, T40B, N_NODES);
  agg40s_kernel<<<N_NODES, 64, 0, stream>>>(adj_off, adj_src, deg_inv, T40, T40B, XCAT);

  // ---- Hypergraph branch: heagg -> tiny GEMM (5000 rows) -> nodeagg+bias+relu
  lin2b_kernel<128, 0, 256, true><<<GS, 256, 0, stream>>>(
      EFa, Wh + 217088, Wl + 217088, nullptr, nullptr, nullptr, nullptr, nullptr, EFb, 256, N_HE, 0);
  aggb_kernel<256><<<N_NODES, 64, 0, stream>>>(hng_off, hng_edge, dinv, EFb, NC, h0b, 1);

  aggb_kernel<256><<<N_HE, 64, 0, stream>>>(heg_off, heg_node, binv, NC, EFa, nullptr, 0);
  lin2b_kernel<256, 0, 256, true><<<GS, 256, 0, stream>>>(
      EFa, Wh + 249856, Wl + 249856, nullptr, nullptr, nullptr, nullptr, nullptr, EFb, 256, N_HE, 0);
  aggb_kernel<256><<<N_NODES, 64, 0, stream>>>(hng_off, hng_edge, dinv, EFb, NC, h1b, 1);

  aggb_kernel<256><<<N_HE, 64, 0, stream>>>(heg_off, heg_node, binv, NC, EFa, nullptr, 0);
  lin2b_kernel<256, 0, 256, true><<<GS, 256, 0, stream>>>(
      EFa, Wh + 315392, Wl + 315392, nullptr, nullptr, nullptr, nullptr, nullptr, EFb, 256, N_HE, 0);
  aggb_kernel<256><<<N_NODES, 64, 0, stream>>>(hng_off, hng_edge, dinv, EFb, NC, h2b, 1);

  aggb_kernel<256><<<N_HE, 64, 0, stream>>>(heg_off, heg_node, binv, NC, EFa, nullptr, 0);
  lin2b_kernel<256, 0, 256, true><<<GS, 256, 0, stream>>>(
      EFa, Wh + 380928, Wl + 380928, nullptr, nullptr, nullptr, nullptr, nullptr, EFb, 256, N_HE, 0);
  aggb_kernel<256><<<N_NODES, 64, 0, stream>>>(hng_off, hng_edge, dinv, EFb, NC, h3b, 1);

  // layer 4 (F=40): transform node features first, then two aggs
  lin2b_kernel<256, 0, 40, true><<<GL, 256, 0, stream>>>(
      NC, Wh + 446464, Wl + 446464, nullptr, nullptr, nullptr, nullptr, nullptr, T40H, 40, N_NODES, 0);
  aggb_kernel<40><<<N_HE, 64, 0, stream>>>(heg_off, heg_node, binv, T40H, EFa, nullptr, 0);
  agg40b_kernel<<<N_NODES, 64, 0, stream>>>(hng_off, hng_edge, dinv, EFa, h4b, XCAT);

  // ---- final linear + log_softmax
  final_ls_kernel<<<(N_NODES + 3) / 4, 256, 0, stream>>>(XCAT, lpw, lpb, out);
}

// Round 12
// 936.070 us; speedup vs baseline: 1.3139x; 1.0759x over previous
//
#include <hip/hip_runtime.h>
#include <hip/hip_bf16.h>
#include <cstdint>
#include <cstddef>

typedef __hip_bfloat16 bf16;
typedef short v8s __attribute__((ext_vector_type(8)));
typedef float v4f __attribute__((ext_vector_type(4)));
typedef unsigned short v8u __attribute__((ext_vector_type(8)));
typedef unsigned short v4u __attribute__((ext_vector_type(4)));
typedef unsigned short v2u __attribute__((ext_vector_type(2)));

#define N_NODES 50000
#define N_HE    5000
#define N_EDGE  800000
#define N_INC   400000
#define W_TOTAL 456704
#define NBREL   275   // 98 adj + 79 heg + 98 hng bucket cursors

__device__ inline float bfh(uint32_t u) { return __uint_as_float(u << 16); }
__device__ inline uint16_t rne16(float f) {
  uint32_t u = __float_as_uint(f);
  return (uint16_t)((u + 0x7FFFu + ((u >> 16) & 1u)) >> 16);
}

// ---- prep: zero counters+cursors + split weights (incl lpw, stride 96) + cvt x
// blocks [0,412): zero; [412,2196): split_w; [2196,2211): lpw split; [2211,8461): cvt.
__global__ void prep_kernel(int* cnt_dst, int* cnt_he, int* cnt_hn, int* brel,
                            const float* s0wl, const float* s0wr,
                            const float* s1wl, const float* s1wr,
                            const float* s2wl, const float* s2wr,
                            const float* h0w, const float* h1w,
                            const float* h2w, const float* h3w, const float* h4w,
                            uint16_t* hi, uint16_t* lo,
                            const float* lpw, uint16_t* lpWh, uint16_t* lpWl,
                            const float* X, uint16_t* XB) {
  int b = blockIdx.x;
  if (b < 412) {
    int i = b * 256 + threadIdx.x;
    if (i < N_NODES) cnt_dst[i] = 0;
    else if (i < N_NODES + N_HE) cnt_he[i - N_NODES] = 0;
    else if (i < 2 * N_NODES + N_HE) cnt_hn[i - N_NODES - N_HE] = 0;
    else if (i < 2 * N_NODES + N_HE + NBREL) brel[i - 2 * N_NODES - N_HE] = 0;
    return;
  }
  if (b < 2196) {
    int i = (b - 412) * 256 + threadIdx.x;
    if (i >= W_TOTAL) return;
    const float* src; int base;
    if (i < 32768)       { src = s0wl; base = 0; }
    else if (i < 65536)  { src = s0wr; base = 32768; }
    else if (i < 131072) { src = s1wl; base = 65536; }
    else if (i < 196608) { src = s1wr; base = 131072; }
    else if (i < 206848) { src = s2wl; base = 196608; }
    else if (i < 217088) { src = s2wr; base = 206848; }
    else if (i < 249856) { src = h0w;  base = 217088; }
    else if (i < 315392) { src = h1w;  base = 249856; }
    else if (i < 380928) { src = h2w;  base = 315392; }
    else if (i < 446464) { src = h3w;  base = 380928; }
    else                 { src = h4w;  base = 446464; }
    float v = src[i - base];
    uint16_t hb = rne16(v);
    hi[i] = hb;
    lo[i] = rne16(v - bfh(hb));
    return;
  }
  if (b < 2211) {
    int i = (b - 2196) * 256 + threadIdx.x;   // 40 rows x 96 cols
    if (i >= 40 * 96) return;
    int row = i / 96, col = i - row * 96;
    float v = (col < 80) ? lpw[row * 80 + col] : 0.f;
    uint16_t hb = rne16(v);
    lpWh[i] = hb;
    lpWl[i] = rne16(v - bfh(hb));
    return;
  }
  {
    int i = (b - 2211) * 256 + threadIdx.x;   // v4 index
    if (i >= N_NODES * 32) return;
    v4f v = *((const v4f*)X + i);
    v4u o;
    o[0] = rne16(v[0]); o[1] = rne16(v[1]); o[2] = rne16(v[2]); o[3] = rne16(v[3]);
    *((v4u*)XB + i) = o;
  }
}

// ---------------------------------------------------------------- CSR build
__global__ void hist_kernel(const int* __restrict__ dst,
                            const int* __restrict__ he_node,
                            const int* __restrict__ he_edge,
                            int* cnt_dst, int* cnt_he, int* cnt_hn) {
  int i = blockIdx.x * blockDim.x + threadIdx.x;
  if (i < N_EDGE) atomicAdd(&cnt_dst[dst[i]], 1);
  if (i < N_INC) {
    atomicAdd(&cnt_he[he_edge[i]], 1);
    atomicAdd(&cnt_hn[he_node[i]], 1);
  }
}

// shfl-based block scan (4 elems/thread) + fused reciprocal scales.
__global__ void scan3_kernel(const int* cnt_dst, int* adj_off, float* deg_inv,
                             const int* cnt_he, int* heg_off, float* binv,
                             const int* cnt_hn, int* hng_off, float* dinv) {
  const int* cnt; int* off; float* scl; int n, mode;
  if (blockIdx.x == 0)      { cnt = cnt_dst; off = adj_off; scl = deg_inv; n = N_NODES; mode = 0; }
  else if (blockIdx.x == 1) { cnt = cnt_he;  off = heg_off; scl = binv;    n = N_HE;    mode = 1; }
  else                      { cnt = cnt_hn;  off = hng_off; scl = dinv;    n = N_NODES; mode = 1; }
  __shared__ int ws[16];
  int t = threadIdx.x;               // 1024 threads
  int lane = t & 63, wave = t >> 6;
  int carry = 0;
  for (int base = 0; base < n; base += 4096) {
    int i0 = base + t * 4;
    int a[4];
#pragma unroll
    for (int k = 0; k < 4; ++k) {
      int i = i0 + k;
      a[k] = (i < n) ? cnt[i] : 0;
      if (i < n) {
        if (mode == 0) scl[i] = 1.0f / (float)(a[k] > 1 ? a[k] : 1);
        else scl[i] = a[k] > 0 ? 1.0f / (float)a[k] : 0.f;
      }
    }
    int tsum = a[0] + a[1] + a[2] + a[3];
    int val = tsum;
#pragma unroll
    for (int d = 1; d < 64; d <<= 1) {
      int x = __shfl_up(val, d);
      if (lane >= d) val += x;
    }
    if (lane == 63) ws[wave] = val;
    __syncthreads();
    if (wave == 0 && lane < 16) {
      int w = ws[lane];
#pragma unroll
      for (int d = 1; d < 16; d <<= 1) {
        int x = __shfl_up(w, d);
        if (lane >= d) w += x;
      }
      ws[lane] = w;
    }
    __syncthreads();
    int wexcl = wave ? ws[wave - 1] : 0;
    int e = carry + wexcl + (val - tsum);
#pragma unroll
    for (int k = 0; k < 4; ++k) {
      int i = i0 + k;
      if (i < n) off[i] = e;
      e += a[k];
    }
    carry += ws[15];
    __syncthreads();
  }
  if (t == 0) off[n] = carry;
}

// ---------------- binned two-phase fill (kills scatter write amplification)
template <int NB, int SH>
__device__ inline void binA_section(const int* __restrict__ key_arr,
                                    const int* __restrict__ pay_arr, int n, int blk,
                                    const int* __restrict__ off, int nkeys,
                                    int* brel, uint32_t* __restrict__ stg) {
  __shared__ int lcnt[128], lscan[128], lcnt2[128], gbase[128];
  __shared__ uint32_t sstage[4096];
  int t = threadIdx.x;
  int e0 = blk * 4096;
  int cnt = min(4096, n - e0);
  for (int k = t; k < NB; k += 256) { lcnt[k] = 0; lcnt2[k] = 0; }
  __syncthreads();
  for (int k = t; k < cnt; k += 256) atomicAdd(&lcnt[key_arr[e0 + k] >> SH], 1);
  __syncthreads();
  if (t == 0) {
    int s = 0;
    for (int b = 0; b < NB; ++b) { lscan[b] = s; s += lcnt[b]; }
  }
  __syncthreads();
  if (t < NB) {
    int base = off[min(t << SH, nkeys)];
    gbase[t] = base + atomicAdd(&brel[t], lcnt[t]);
  }
  __syncthreads();
  for (int k = t; k < cnt; k += 256) {
    int key = key_arr[e0 + k];
    int pay = pay_arr[e0 + k];
    int b = key >> SH;
    int r = atomicAdd(&lcnt2[b], 1);
    sstage[lscan[b] + r] = ((uint32_t)pay << 16) | (uint32_t)key;
  }
  __syncthreads();
  for (int b = 0; b < NB; ++b) {
    int len = lcnt[b], ls = lscan[b], gb = gbase[b];
    for (int k = t; k < len; k += 256) stg[gb + k] = sstage[ls + k];
  }
}

__global__ __launch_bounds__(256) void binA_kernel(
    const int* __restrict__ src, const int* __restrict__ dst,
    const int* __restrict__ he_node, const int* __restrict__ he_edge,
    const int* __restrict__ adj_off, const int* __restrict__ heg_off,
    const int* __restrict__ hng_off, int* brel,
    uint32_t* stg_adj, uint32_t* stg_heg, uint32_t* stg_hng) {
  int b = blockIdx.x;
  if (b < 196)      binA_section<98, 9>(dst, src, N_EDGE, b, adj_off, N_NODES, brel, stg_adj);
  else if (b < 294) binA_section<79, 6>(he_edge, he_node, N_INC, b - 196, heg_off, N_HE, brel + 98, stg_heg);
  else              binA_section<98, 9>(he_node, he_edge, N_INC, b - 294, hng_off, N_NODES, brel + 177, stg_hng);
}

template <int BS, int SH>
__device__ inline void binB_section(int bkt, const int* __restrict__ off, int nkeys,
                                    const uint32_t* __restrict__ stg,
                                    uint16_t* __restrict__ out) {
  __shared__ int lcur[512];
  int t = threadIdx.x;
  int nb0 = bkt << SH;
  int nb1 = min(nb0 + BS, nkeys);
  int nn = nb1 - nb0;
  for (int k = t; k < nn; k += 256) lcur[k] = off[nb0 + k];
  __syncthreads();
  int e0 = off[nb0], e1 = off[nb1];
  for (int e = e0 + t; e < e1; e += 256) {
    uint32_t v = stg[e];
    int key = (int)(v & 0xFFFFu);
    int p = atomicAdd(&lcur[key - nb0], 1);
    out[p] = (uint16_t)(v >> 16);
  }
}

__global__ __launch_bounds__(256) void binB_kernel(
    const int* __restrict__ adj_off, const int* __restrict__ heg_off,
    const int* __restrict__ hng_off,
    const uint32_t* __restrict__ stg_adj, const uint32_t* __restrict__ stg_heg,
    const uint32_t* __restrict__ stg_hng,
    uint16_t* adj_src, uint16_t* heg_node, uint16_t* hng_edge) {
  int b = blockIdx.x;
  if (b < 98)       binB_section<512, 9>(b, adj_off, N_NODES, stg_adj, adj_src);
  else if (b < 177) binB_section<64, 6>(b - 98, heg_off, N_HE, stg_heg, heg_node);
  else              binB_section<512, 9>(b - 177, hng_off, N_NODES, stg_hng, hng_edge);
}

// ------------------------------- gather-mean row body (uint16 CSR idx)
template <int F>
__device__ inline void agg_row(const int* __restrict__ off, const uint16_t* __restrict__ idx,
                               const float* __restrict__ scale,
                               const uint16_t* __restrict__ X,
                               uint16_t* __restrict__ OUT, int row,
                               const float* __restrict__ bias, int do_relu) {
  constexpr int VEC = (F >= 256) ? 4 : 2;
  int t = threadIdx.x;
  if (t * VEC >= F) return;
  int j0 = off[row], j1 = off[row + 1];
  float sc = scale[row];
  float acc[VEC];
#pragma unroll
  for (int k = 0; k < VEC; ++k) acc[k] = 0.f;

  int j = j0;
  for (; j + 7 < j1; j += 8) {
    int s[8];
#pragma unroll
    for (int u = 0; u < 8; ++u) s[u] = idx[j + u];
    if (VEC == 4) {
      v4u v[8];
#pragma unroll
      for (int u = 0; u < 8; ++u) v[u] = *(const v4u*)(X + (size_t)s[u] * F + t * 4);
#pragma unroll
      for (int u = 0; u < 8; ++u)
#pragma unroll
        for (int k = 0; k < 4; ++k) acc[k] += bfh(v[u][k]);
    } else {
      v2u v[8];
#pragma unroll
      for (int u = 0; u < 8; ++u) v[u] = *(const v2u*)(X + (size_t)s[u] * F + t * 2);
#pragma unroll
      for (int u = 0; u < 8; ++u)
#pragma unroll
        for (int k = 0; k < 2; ++k) acc[k] += bfh(v[u][k]);
    }
  }
  for (; j < j1; ++j) {
    int s = idx[j];
    if (VEC == 4) {
      v4u a = *(const v4u*)(X + (size_t)s * F + t * 4);
#pragma unroll
      for (int k = 0; k < 4; ++k) acc[k] += bfh(a[k]);
    } else {
      v2u a = *(const v2u*)(X + (size_t)s * F + t * 2);
#pragma unroll
      for (int k = 0; k < 2; ++k) acc[k] += bfh(a[k]);
    }
  }

  if (VEC == 4) {
    v4u o;
#pragma unroll
    for (int k = 0; k < 4; ++k) {
      float v = acc[k] * sc;
      if (bias) { v += bias[t * 4 + k]; if (do_relu) v = fmaxf(v, 0.f); }
      o[k] = rne16(v);
    }
    *(v4u*)(OUT + (size_t)row * F + t * 4) = o;
  } else {
    v2u o;
#pragma unroll
    for (int k = 0; k < 2; ++k) {
      float v = acc[k] * sc;
      if (bias) { v += bias[t * 2 + k]; if (do_relu) v = fmaxf(v, 0.f); }
      o[k] = rne16(v);
    }
    *(v2u*)(OUT + (size_t)row * F + t * 2) = o;
  }
}

template <int F>
__global__ void aggb_kernel(const int* __restrict__ off, const uint16_t* __restrict__ idx,
                            const float* __restrict__ scale,
                            const uint16_t* __restrict__ X,
                            uint16_t* __restrict__ OUT,
                            const float* __restrict__ bias, int do_relu) {
  agg_row<F>(off, idx, scale, X, OUT, blockIdx.x, bias, do_relu);
}

template <int F>
__global__ void agg2b_kernel(const int* __restrict__ off1, const uint16_t* __restrict__ idx1,
                             const float* __restrict__ sc1, uint16_t* __restrict__ OUT1, int n1,
                             const int* __restrict__ off2, const uint16_t* __restrict__ idx2,
                             const float* __restrict__ sc2, uint16_t* __restrict__ OUT2,
                             const uint16_t* __restrict__ X) {
  int row = blockIdx.x;
  if (row < n1) agg_row<F>(off1, idx1, sc1, X, OUT1, row, nullptr, 0);
  else          agg_row<F>(off2, idx2, sc2, X, OUT2, row - n1, nullptr, 0);
}

// Hyper tail: XCATB[:,40:80] = bf16(dinv*agg(EF40) + bias); also zeros pad 80:96.
__global__ void agg40b_kernel(const int* __restrict__ off, const uint16_t* __restrict__ idx,
                              const float* __restrict__ scale,
                              const uint16_t* __restrict__ EF40,
                              const float* __restrict__ bias,
                              uint16_t* __restrict__ XCATB) {
  int row = blockIdx.x;
  int t = threadIdx.x;
  if (t < 8) {
    v2u z = {0, 0};
    *(v2u*)(XCATB + (size_t)row * 96 + 80 + t * 2) = z;
  }
  if (t >= 20) return;
  int j0 = off[row], j1 = off[row + 1];
  float sc = scale[row];
  float a0 = 0.f, a1 = 0.f;
  for (int j = j0; j < j1; ++j) {
    int s = idx[j];
    v2u v = *(const v2u*)(EF40 + (size_t)s * 40 + t * 2);
    a0 += bfh(v[0]);
    a1 += bfh(v[1]);
  }
  v2u o;
  o[0] = rne16(a0 * sc + bias[t * 2]);
  o[1] = rne16(a1 * sc + bias[t * 2 + 1]);
  *(v2u*)(XCATB + (size_t)row * 96 + 40 + t * 2) = o;
}

// SAGE tail: XCATB[:, :40] = bf16(deg_inv*agg(T40a) + T40b)
__global__ void agg40s_kernel(const int* __restrict__ off, const uint16_t* __restrict__ idx,
                              const float* __restrict__ scale,
                              const uint16_t* __restrict__ T40a,
                              const uint16_t* __restrict__ T40b,
                              uint16_t* __restrict__ XCATB) {
  int row = blockIdx.x;
  int t = threadIdx.x;
  if (t >= 20) return;
  int j0 = off[row], j1 = off[row + 1];
  float sc = scale[row];
  float a0 = 0.f, a1 = 0.f;
  for (int j = j0; j < j1; ++j) {
    int s = idx[j];
    v2u v = *(const v2u*)(T40a + (size_t)s * 40 + t * 2);
    a0 += bfh(v[0]);
    a1 += bfh(v[1]);
  }
  v2u b = *(const v2u*)(T40b + (size_t)row * 40 + t * 2);
  v2u o;
  o[0] = rne16(a0 * sc + bfh(b[0]));
  o[1] = rne16(a1 * sc + bfh(b[1]));
  *(v2u*)(XCATB + (size_t)row * 96 + t * 2) = o;
}

// ------------------------------------- bf16-A, split-W LDS-staged MFMA GEMM
// A/B frag: row|col = lane&15, k = (lane>>4)*8+j.  C/D: col = lane&15,
// row = (lane>>4)*4 + reg  (verified gfx950 mappings).
template <int K1, int K2, int F, bool OUTBF>
__global__ __launch_bounds__(256, 4) void lin2b_kernel(
    const uint16_t* __restrict__ X1, const uint16_t* __restrict__ W1h, const uint16_t* __restrict__ W1l,
    const uint16_t* __restrict__ X2, const uint16_t* __restrict__ W2h, const uint16_t* __restrict__ W2l,
    const float* __restrict__ bias, const uint16_t* __restrict__ addin,
    void* __restrict__ OUTP, int out_ld, int N, int do_relu) {
  constexpr int FP  = (F + 15) & ~15;
  constexpr int NF  = FP / 16;
  constexpr int NC1 = K1 / 32;
  constexpr int NCH = (K1 + (K2 > 0 ? K2 : 0)) / 32;
  constexpr int RS  = 40;
  __shared__ short sW[2][FP][RS];

  int tid  = threadIdx.x;
  int wave = tid >> 6, lane = tid & 63;
  int r = lane & 15, q = lane >> 4;
  int row0 = blockIdx.x * 64 + wave * 16;
  int rowA = row0 + r; if (rowA > N - 1) rowA = N - 1;

  int srow = tid >> 2;
  int sj   = tid & 3;

  v4f acc[NF];
#pragma unroll
  for (int i = 0; i < NF; ++i) acc[i] = (v4f){0.f, 0.f, 0.f, 0.f};

  for (int c = 0; c < NCH; ++c) {
    const bool first = (K2 == 0) || (c < NC1);
    const uint16_t* Wh = first ? W1h : W2h;
    const uint16_t* Wl = first ? W1l : W2l;
    const uint16_t* Xs = first ? X1 : X2;
    const int K  = first ? K1 : K2;
    const int kc = (first ? c : c - NC1) * 32;

    if (c) __syncthreads();
    const v8s zz = {0, 0, 0, 0, 0, 0, 0, 0};
#pragma unroll
    for (int pass = 0; pass < (FP + 63) / 64; ++pass) {
      int row = srow + pass * 64;
      if (row < FP) {
        v8s hv = zz, lv = zz;
        if (row < F) {
          hv = *reinterpret_cast<const v8s*>(Wh + (size_t)row * K + kc + sj * 8);
          lv = *reinterpret_cast<const v8s*>(Wl + (size_t)row * K + kc + sj * 8);
        }
        *reinterpret_cast<v8s*>(&sW[0][row][sj * 8]) = hv;
        *reinterpret_cast<v8s*>(&sW[1][row][sj * 8]) = lv;
      }
    }
    v8s ah = *reinterpret_cast<const v8s*>(Xs + (size_t)rowA * K + kc + q * 8);
    __syncthreads();
#pragma unroll
    for (int ft = 0; ft < NF; ++ft) {
      v8s bh = *reinterpret_cast<const v8s*>(&sW[0][ft * 16 + r][q * 8]);
      v8s bl = *reinterpret_cast<const v8s*>(&sW[1][ft * 16 + r][q * 8]);
      acc[ft] = __builtin_amdgcn_mfma_f32_16x16x32_bf16(ah, bh, acc[ft], 0, 0, 0);
      acc[ft] = __builtin_amdgcn_mfma_f32_16x16x32_bf16(ah, bl, acc[ft], 0, 0, 0);
    }
  }

#pragma unroll
  for (int ft = 0; ft < NF; ++ft) {
    int col = ft * 16 + r;
    if (col < F) {
      float bv = bias ? bias[col] : 0.f;
#pragma unroll
      for (int i = 0; i < 4; ++i) {
        int row = row0 + q * 4 + i;
        if (row < N) {
          float v = acc[ft][i] + bv;
          if (addin) v += bfh(addin[(size_t)row * F + col]);
          if (do_relu) v = fmaxf(v, 0.f);
          size_t o = (size_t)row * out_ld + col;
          if (OUTBF) ((uint16_t*)OUTP)[o] = rne16(v);
          else ((float*)OUTP)[o] = v;
        }
      }
    }
  }
}

// Dual-output 40-col GEMM (K=256): OUT1 = X*W1^T, OUT2 = X*W2^T + b2.
__global__ __launch_bounds__(256, 4) void lin40ab_kernel(
    const uint16_t* __restrict__ X,
    const uint16_t* __restrict__ W1h, const uint16_t* __restrict__ W1l,
    const uint16_t* __restrict__ W2h, const uint16_t* __restrict__ W2l,
    const float* __restrict__ bias2,
    uint16_t* __restrict__ OUT1, uint16_t* __restrict__ OUT2, int N) {
  constexpr int K = 256, F = 40, FP = 48, NF = 3, RS = 40;
  __shared__ short sW[2][2][FP][RS];

  int tid  = threadIdx.x;
  int wave = tid >> 6, lane = tid & 63;
  int r = lane & 15, q = lane >> 4;
  int row0 = blockIdx.x * 64 + wave * 16;
  int rowA = row0 + r; if (rowA > N - 1) rowA = N - 1;
  int srow = tid >> 2, sj = tid & 3;

  v4f acc[2][NF];
#pragma unroll
  for (int w = 0; w < 2; ++w)
#pragma unroll
    for (int i = 0; i < NF; ++i) acc[w][i] = (v4f){0.f, 0.f, 0.f, 0.f};

  for (int c = 0; c < K / 32; ++c) {
    int kc = c * 32;
    if (c) __syncthreads();
    if (srow < FP) {
      const v8s zz = {0, 0, 0, 0, 0, 0, 0, 0};
      v8s a = zz, b = zz, cc = zz, d = zz;
      if (srow < F) {
        a  = *reinterpret_cast<const v8s*>(W1h + (size_t)srow * K + kc + sj * 8);
        b  = *reinterpret_cast<const v8s*>(W1l + (size_t)srow * K + kc + sj * 8);
        cc = *reinterpret_cast<const v8s*>(W2h + (size_t)srow * K + kc + sj * 8);
        d  = *reinterpret_cast<const v8s*>(W2l + (size_t)srow * K + kc + sj * 8);
      }
      *reinterpret_cast<v8s*>(&sW[0][0][srow][sj * 8]) = a;
      *reinterpret_cast<v8s*>(&sW[0][1][srow][sj * 8]) = b;
      *reinterpret_cast<v8s*>(&sW[1][0][srow][sj * 8]) = cc;
      *reinterpret_cast<v8s*>(&sW[1][1][srow][sj * 8]) = d;
    }
    v8s ah = *reinterpret_cast<const v8s*>(X + (size_t)rowA * K + kc + q * 8);
    __syncthreads();
#pragma unroll
    for (int w = 0; w < 2; ++w)
#pragma unroll
      for (int ft = 0; ft < NF; ++ft) {
        v8s bh = *reinterpret_cast<const v8s*>(&sW[w][0][ft * 16 + r][q * 8]);
        v8s bl = *reinterpret_cast<const v8s*>(&sW[w][1][ft * 16 + r][q * 8]);
        acc[w][ft] = __builtin_amdgcn_mfma_f32_16x16x32_bf16(ah, bh, acc[w][ft], 0, 0, 0);
        acc[w][ft] = __builtin_amdgcn_mfma_f32_16x16x32_bf16(ah, bl, acc[w][ft], 0, 0, 0);
      }
  }

#pragma unroll
  for (int ft = 0; ft < NF; ++ft) {
    int col = ft * 16 + r;
    if (col < F) {
      float bv = bias2[col];
#pragma unroll
      for (int i = 0; i < 4; ++i) {
        int row = row0 + q * 4 + i;
        if (row < N) {
          OUT1[(size_t)row * F + col] = rne16(acc[0][ft][i]);
          OUT2[(size_t)row * F + col] = rne16(acc[1][ft][i] + bv);
        }
      }
    }
  }
}

// ---------------- final: MFMA GEMM (K=96, F=40) + fused log-softmax
// C-layout: row's cols live across the 16 lanes of a quad (col=ft*16+r);
// max/sum reduce with shfl_xor d=1,2,4,8 (stays inside the quad).
__global__ __launch_bounds__(256, 4) void final_mfma_kernel(
    const uint16_t* __restrict__ XB96,
    const uint16_t* __restrict__ Wh, const uint16_t* __restrict__ Wl,
    const float* __restrict__ lpb, float* __restrict__ out, int N) {
  constexpr int K = 96, F = 40, FP = 48, NF = 3, RS = 40;
  __shared__ short sW[2][FP][RS];

  int tid  = threadIdx.x;
  int wave = tid >> 6, lane = tid & 63;
  int r = lane & 15, q = lane >> 4;
  int row0 = blockIdx.x * 64 + wave * 16;
  int rowA = row0 + r; if (rowA > N - 1) rowA = N - 1;
  int srow = tid >> 2, sj = tid & 3;

  v4f acc[NF];
#pragma unroll
  for (int i = 0; i < NF; ++i) acc[i] = (v4f){0.f, 0.f, 0.f, 0.f};

  for (int c = 0; c < 3; ++c) {
    int kc = c * 32;
    if (c) __syncthreads();
    if (srow < FP) {
      const v8s zz = {0, 0, 0, 0, 0, 0, 0, 0};
      v8s hv = zz, lv = zz;
      if (srow < F) {
        hv = *reinterpret_cast<const v8s*>(Wh + (size_t)srow * K + kc + sj * 8);
        lv = *reinterpret_cast<const v8s*>(Wl + (size_t)srow * K + kc + sj * 8);
      }
      *reinterpret_cast<v8s*>(&sW[0][srow][sj * 8]) = hv;
      *reinterpret_cast<v8s*>(&sW[1][srow][sj * 8]) = lv;
    }
    v8s ah = *reinterpret_cast<const v8s*>(XB96 + (size_t)rowA * K + kc + q * 8);
    __syncthreads();
#pragma unroll
    for (int ft = 0; ft < NF; ++ft) {
      v8s bh = *reinterpret_cast<const v8s*>(&sW[0][ft * 16 + r][q * 8]);
      v8s bl = *reinterpret_cast<const v8s*>(&sW[1][ft * 16 + r][q * 8]);
      acc[ft] = __builtin_amdgcn_mfma_f32_16x16x32_bf16(ah, bh, acc[ft], 0, 0, 0);
      acc[ft] = __builtin_amdgcn_mfma_f32_16x16x32_bf16(ah, bl, acc[ft], 0, 0, 0);
    }
  }

  float b0 = lpb[r], b1 = lpb[16 + r];
  float b2 = (r < 8) ? lpb[32 + r] : 0.f;
#pragma unroll
  for (int i = 0; i < 4; ++i) {
    int row = row0 + q * 4 + i;
    float l0 = acc[0][i] + b0;
    float l1 = acc[1][i] + b1;
    float l2 = (r < 8) ? (acc[2][i] + b2) : -1e30f;
    float m = fmaxf(fmaxf(l0, l1), l2);
#pragma unroll
    for (int d = 1; d < 16; d <<= 1) m = fmaxf(m, __shfl_xor(m, d));
    float e = __expf(l0 - m) + __expf(l1 - m) + ((r < 8) ? __expf(l2 - m) : 0.f);
#pragma unroll
    for (int d = 1; d < 16; d <<= 1) e += __shfl_xor(e, d);
    if (row < N) {
      float ls = m + __logf(e);
      out[(size_t)row * 40 + r]      = l0 - ls;
      out[(size_t)row * 40 + 16 + r] = l1 - ls;
      if (r < 8) out[(size_t)row * 40 + 32 + r] = l2 - ls;
    }
  }
}

// ---------------------------------------------------------------- launcher
extern "C" void kernel_launch(void* const* d_in, const int* in_sizes, int n_in,
                              void* d_out, int out_size, void* d_ws, size_t ws_size,
                              hipStream_t stream) {
  const float* x      = (const float*)d_in[0];
  const int* src      = (const int*)d_in[1];
  const int* dst      = (const int*)d_in[2];
  const int* he_node  = (const int*)d_in[3];
  const int* he_edge  = (const int*)d_in[4];
  const float* s0wl = (const float*)d_in[5],  *s0wr = (const float*)d_in[6],  *s0b = (const float*)d_in[7];
  const float* s1wl = (const float*)d_in[8],  *s1wr = (const float*)d_in[9],  *s1b = (const float*)d_in[10];
  const float* s2wl = (const float*)d_in[11], *s2wr = (const float*)d_in[12], *s2b = (const float*)d_in[13];
  const float* h0w = (const float*)d_in[14], *h0b = (const float*)d_in[15];
  const float* h1w = (const float*)d_in[16], *h1b = (const float*)d_in[17];
  const float* h2w = (const float*)d_in[18], *h2b = (const float*)d_in[19];
  const float* h3w = (const float*)d_in[20], *h3b = (const float*)d_in[21];
  const float* h4w = (const float*)d_in[22], *h4b = (const float*)d_in[23];
  const float* lpw = (const float*)d_in[24], *lpb = (const float*)d_in[25];
  float* out = (float*)d_out;

  char* p = (char*)d_ws;
  auto carve = [&](size_t bytes) -> char* {
    char* r = p;
    p += (bytes + 255) & ~(size_t)255;
    return r;
  };
  int* cnt_dst  = (int*)carve((size_t)N_NODES * 4);
  int* adj_off  = (int*)carve((size_t)(N_NODES + 1) * 4);
  uint16_t* adj_src  = (uint16_t*)carve((size_t)N_EDGE * 2);
  int* cnt_he   = (int*)carve((size_t)N_HE * 4);
  int* heg_off  = (int*)carve((size_t)(N_HE + 1) * 4);
  uint16_t* heg_node = (uint16_t*)carve((size_t)N_INC * 2);
  int* cnt_hn   = (int*)carve((size_t)N_NODES * 4);
  int* hng_off  = (int*)carve((size_t)(N_NODES + 1) * 4);
  uint16_t* hng_edge = (uint16_t*)carve((size_t)N_INC * 2);
  int* brel     = (int*)carve((size_t)NBREL * 4);
  uint32_t* stg_adj = (uint32_t*)carve((size_t)N_EDGE * 4);
  uint32_t* stg_heg = (uint32_t*)carve((size_t)N_INC * 4);
  uint32_t* stg_hng = (uint32_t*)carve((size_t)N_INC * 4);
  float* deg_inv = (float*)carve((size_t)N_NODES * 4);
  float* binv    = (float*)carve((size_t)N_HE * 4);
  float* dinv    = (float*)carve((size_t)N_NODES * 4);
  uint16_t* Wh = (uint16_t*)carve((size_t)W_TOTAL * 2);
  uint16_t* Wl = (uint16_t*)carve((size_t)W_TOTAL * 2);
  uint16_t* lpWh = (uint16_t*)carve((size_t)40 * 96 * 2);
  uint16_t* lpWl = (uint16_t*)carve((size_t)40 * 96 * 2);
  uint16_t* XB = (uint16_t*)carve((size_t)N_NODES * 128 * 2);
  uint16_t* U  = (uint16_t*)carve((size_t)N_NODES * 128 * 2);
  uint16_t* NA = (uint16_t*)carve((size_t)N_NODES * 256 * 2);
  uint16_t* NB_ = (uint16_t*)carve((size_t)N_NODES * 256 * 2);
  uint16_t* NC = (uint16_t*)carve((size_t)N_NODES * 256 * 2);
  uint16_t* EFa = (uint16_t*)carve((size_t)N_HE * 256 * 2);
  uint16_t* EFb = (uint16_t*)carve((size_t)N_HE * 256 * 2);
  uint16_t* T40 = (uint16_t*)carve((size_t)N_NODES * 40 * 2);
  uint16_t* T40B = (uint16_t*)carve((size_t)N_NODES * 40 * 2);
  uint16_t* T40H = (uint16_t*)carve((size_t)N_NODES * 40 * 2);
  uint16_t* XCATB = (uint16_t*)carve((size_t)N_NODES * 96 * 2);

  const int GE = (N_EDGE + 255) / 256;
  const int GL = (N_NODES + 63) / 64;
  const int GS = (N_HE + 63) / 64;

  // ---- prep (zero + weight split + lpw split + x cvt) and binned CSR build
  prep_kernel<<<8461, 256, 0, stream>>>(cnt_dst, cnt_he, cnt_hn, brel,
                                        s0wl, s0wr, s1wl, s1wr, s2wl, s2wr,
                                        h0w, h1w, h2w, h3w, h4w, Wh, Wl,
                                        lpw, lpWh, lpWl, x, XB);
  hist_kernel<<<GE, 256, 0, stream>>>(dst, he_node, he_edge, cnt_dst, cnt_he, cnt_hn);
  scan3_kernel<<<3, 1024, 0, stream>>>(cnt_dst, adj_off, deg_inv,
                                       cnt_he, heg_off, binv,
                                       cnt_hn, hng_off, dinv);
  binA_kernel<<<392, 256, 0, stream>>>(src, dst, he_node, he_edge,
                                       adj_off, heg_off, hng_off, brel,
                                       stg_adj, stg_heg, stg_hng);
  binB_kernel<<<275, 256, 0, stream>>>(adj_off, heg_off, hng_off,
                                       stg_adj, stg_heg, stg_hng,
                                       adj_src, heg_node, hng_edge);

  // ---- merged layer-0 gathers (SAGE node-agg + hyper he-agg, both from XB)
  agg2b_kernel<128><<<N_NODES + N_HE, 64, 0, stream>>>(
      adj_off, adj_src, deg_inv, U, N_NODES,
      heg_off, heg_node, binv, EFa, XB);

  // ---- SAGE branch
  lin2b_kernel<128, 128, 256, true><<<GL, 256, 0, stream>>>(
      U, Wh + 0, Wl + 0, XB, Wh + 32768, Wl + 32768, s0b, nullptr, NA, 256, N_NODES, 1);
  aggb_kernel<256><<<N_NODES, 64, 0, stream>>>(adj_off, adj_src, deg_inv, NA, NB_, nullptr, 0);
  lin2b_kernel<256, 256, 256, true><<<GL, 256, 0, stream>>>(
      NB_, Wh + 65536, Wl + 65536, NA, Wh + 131072, Wl + 131072, s1b, nullptr, NC, 256, N_NODES, 1);
  lin40ab_kernel<<<GL, 256, 0, stream>>>(
      NC, Wh + 196608, Wl + 196608, Wh + 206848, Wl + 206848, s2b, T40, T40B, N_NODES);
  agg40s_kernel<<<N_NODES, 64, 0, stream>>>(adj_off, adj_src, deg_inv, T40, T40B, XCATB);

  // ---- Hypergraph branch: heagg -> tiny GEMM (5000 rows) -> nodeagg+bias+relu
  lin2b_kernel<128, 0, 256, true><<<GS, 256, 0, stream>>>(
      EFa, Wh + 217088, Wl + 217088, nullptr, nullptr, nullptr, nullptr, nullptr, EFb, 256, N_HE, 0);
  aggb_kernel<256><<<N_NODES, 64, 0, stream>>>(hng_off, hng_edge, dinv, EFb, NC, h0b, 1);

  aggb_kernel<256><<<N_HE, 64, 0, stream>>>(heg_off, heg_node, binv, NC, EFa, nullptr, 0);
  lin2b_kernel<256, 0, 256, true><<<GS, 256, 0, stream>>>(
      EFa, Wh + 249856, Wl + 249856, nullptr, nullptr, nullptr, nullptr, nullptr, EFb, 256, N_HE, 0);
  aggb_kernel<256><<<N_NODES, 64, 0, stream>>>(hng_off, hng_edge, dinv, EFb, NC, h1b, 1);

  aggb_kernel<256><<<N_HE, 64, 0, stream>>>(heg_off, heg_node, binv, NC, EFa, nullptr, 0);
  lin2b_kernel<256, 0, 256, true><<<GS, 256, 0, stream>>>(
      EFa, Wh + 315392, Wl + 315392, nullptr, nullptr, nullptr, nullptr, nullptr, EFb, 256, N_HE, 0);
  aggb_kernel<256><<<N_NODES, 64, 0, stream>>>(hng_off, hng_edge, dinv, EFb, NC, h2b, 1);

  aggb_kernel<256><<<N_HE, 64, 0, stream>>>(heg_off, heg_node, binv, NC, EFa, nullptr, 0);
  lin2b_kernel<256, 0, 256, true><<<GS, 256, 0, stream>>>(
      EFa, Wh + 380928, Wl + 380928, nullptr, nullptr, nullptr, nullptr, nullptr, EFb, 256, N_HE, 0);
  aggb_kernel<256><<<N_NODES, 64, 0, stream>>>(hng_off, hng_edge, dinv, EFb, NC, h3b, 1);

  // layer 4 (F=40): transform node features first, then two aggs
  lin2b_kernel<256, 0, 40, true><<<GL, 256, 0, stream>>>(
      NC, Wh + 446464, Wl + 446464, nullptr, nullptr, nullptr, nullptr, nullptr, T40H, 40, N_NODES, 0);
  aggb_kernel<40><<<N_HE, 64, 0, stream>>>(heg_off, heg_node, binv, T40H, EFa, nullptr, 0);
  agg40b_kernel<<<N_NODES, 64, 0, stream>>>(hng_off, hng_edge, dinv, EFa, h4b, XCATB);

  // ---- final MFMA linear + fused log_softmax
  final_mfma_kernel<<<GL, 256, 0, stream>>>(XCATB, lpWh, lpWl, lpb, out, N_NODES);
}

// Round 13
// 869.319 us; speedup vs baseline: 1.4147x; 1.0768x over previous
//
#include <hip/hip_runtime.h>
#include <hip/hip_bf16.h>
#include <cstdint>
#include <cstddef>

typedef __hip_bfloat16 bf16;
typedef short v8s __attribute__((ext_vector_type(8)));
typedef float v4f __attribute__((ext_vector_type(4)));
typedef unsigned short v8u __attribute__((ext_vector_type(8)));
typedef unsigned short v4u __attribute__((ext_vector_type(4)));
typedef unsigned short v2u __attribute__((ext_vector_type(2)));

#define N_NODES 50000
#define N_HE    5000
#define N_EDGE  800000
#define N_INC   400000
#define W_TOTAL 456704
#define NBREL   275   // 98 adj + 79 heg + 98 hng bucket cursors

__device__ inline float bfh(uint32_t u) { return __uint_as_float(u << 16); }
__device__ inline uint16_t rne16(float f) {
  uint32_t u = __float_as_uint(f);
  return (uint16_t)((u + 0x7FFFu + ((u >> 16) & 1u)) >> 16);
}

// ---- prep: zero gcnt+brel + split weights (incl lpw, stride 96) + cvt x
// blocks [0,3): zero 550 ints; [3,1787): split_w; [1787,1802): lpw; [1802,8052): cvt.
__global__ void prep_kernel(int* gcnt, int* brel,
                            const float* s0wl, const float* s0wr,
                            const float* s1wl, const float* s1wr,
                            const float* s2wl, const float* s2wr,
                            const float* h0w, const float* h1w,
                            const float* h2w, const float* h3w, const float* h4w,
                            uint16_t* hi, uint16_t* lo,
                            const float* lpw, uint16_t* lpWh, uint16_t* lpWl,
                            const float* X, uint16_t* XB) {
  int b = blockIdx.x;
  if (b < 3) {
    int i = b * 256 + threadIdx.x;
    if (i < NBREL) gcnt[i] = 0;
    else if (i < 2 * NBREL) brel[i - NBREL] = 0;
    return;
  }
  if (b < 1787) {
    int i = (b - 3) * 256 + threadIdx.x;
    if (i >= W_TOTAL) return;
    const float* src; int base;
    if (i < 32768)       { src = s0wl; base = 0; }
    else if (i < 65536)  { src = s0wr; base = 32768; }
    else if (i < 131072) { src = s1wl; base = 65536; }
    else if (i < 196608) { src = s1wr; base = 131072; }
    else if (i < 206848) { src = s2wl; base = 196608; }
    else if (i < 217088) { src = s2wr; base = 206848; }
    else if (i < 249856) { src = h0w;  base = 217088; }
    else if (i < 315392) { src = h1w;  base = 249856; }
    else if (i < 380928) { src = h2w;  base = 315392; }
    else if (i < 446464) { src = h3w;  base = 380928; }
    else                 { src = h4w;  base = 446464; }
    float v = src[i - base];
    uint16_t hb = rne16(v);
    hi[i] = hb;
    lo[i] = rne16(v - bfh(hb));
    return;
  }
  if (b < 1802) {
    int i = (b - 1787) * 256 + threadIdx.x;   // 40 rows x 96 cols
    if (i >= 40 * 96) return;
    int row = i / 96, col = i - row * 96;
    float v = (col < 80) ? lpw[row * 80 + col] : 0.f;
    uint16_t hb = rne16(v);
    lpWh[i] = hb;
    lpWl[i] = rne16(v - bfh(hb));
    return;
  }
  {
    int i = (b - 1802) * 256 + threadIdx.x;   // v4 index
    if (i >= N_NODES * 32) return;
    v4f v = *((const v4f*)X + i);
    v4u o;
    o[0] = rne16(v[0]); o[1] = rne16(v[1]); o[2] = rne16(v[2]); o[3] = rne16(v[3]);
    *((v4u*)XB + i) = o;
  }
}

// ---------------- bucket-level histogram (LDS-local; replaces hist_kernel)
template <int NB, int SH>
__device__ inline void bhist_section(const int* __restrict__ key_arr, int n, int blk,
                                     int* __restrict__ gcnt) {
  __shared__ int h[128];
  int t = threadIdx.x;
  for (int k = t; k < NB; k += 256) h[k] = 0;
  __syncthreads();
  int e0 = blk * 4096;
  int cnt = min(4096, n - e0);
  for (int k = t; k < cnt; k += 256) atomicAdd(&h[key_arr[e0 + k] >> SH], 1);
  __syncthreads();
  for (int k = t; k < NB; k += 256) atomicAdd(&gcnt[k], h[k]);
}

__global__ __launch_bounds__(256) void bhist_kernel(
    const int* __restrict__ dst, const int* __restrict__ he_edge,
    const int* __restrict__ he_node, int* gcnt) {
  int b = blockIdx.x;
  if (b < 196)      bhist_section<98, 9>(dst, N_EDGE, b, gcnt);
  else if (b < 294) bhist_section<79, 6>(he_edge, N_INC, b - 196, gcnt + 98);
  else              bhist_section<98, 9>(he_node, N_INC, b - 294, gcnt + 177);
}

// ---------------- bucket-base scan (one wave per section) + CSR sentinels
__global__ void bscan_kernel(const int* __restrict__ gcnt, int* gbb,
                             int* adj_off, int* heg_off, int* hng_off) {
  int t = threadIdx.x;
  if (t == 0)        { int s = 0; for (int b = 0; b < 98; ++b) { gbb[b] = s; s += gcnt[b]; } gbb[98] = s; }
  else if (t == 64)  { int s = 0; for (int b = 0; b < 79; ++b) { gbb[99 + b] = s; s += gcnt[98 + b]; } gbb[99 + 79] = s; }
  else if (t == 128) { int s = 0; for (int b = 0; b < 98; ++b) { gbb[179 + b] = s; s += gcnt[177 + b]; } gbb[179 + 98] = s; }
  else if (t == 192) { adj_off[N_NODES] = N_EDGE; heg_off[N_HE] = N_INC; hng_off[N_NODES] = N_INC; }
}

// ---------------- binned two-phase fill (no scatter write amplification)
template <int NB, int SH>
__device__ inline void binA_section(const int* __restrict__ key_arr,
                                    const int* __restrict__ pay_arr, int n, int blk,
                                    const int* __restrict__ bb,
                                    int* brel, uint32_t* __restrict__ stg) {
  __shared__ int lcnt[128], lscan[128], lcnt2[128], gbase[128];
  __shared__ uint32_t sstage[4096];
  int t = threadIdx.x;
  int e0 = blk * 4096;
  int cnt = min(4096, n - e0);
  for (int k = t; k < NB; k += 256) { lcnt[k] = 0; lcnt2[k] = 0; }
  __syncthreads();
  for (int k = t; k < cnt; k += 256) atomicAdd(&lcnt[key_arr[e0 + k] >> SH], 1);
  __syncthreads();
  if (t == 0) {
    int s = 0;
    for (int b = 0; b < NB; ++b) { lscan[b] = s; s += lcnt[b]; }
  }
  __syncthreads();
  if (t < NB) gbase[t] = bb[t] + atomicAdd(&brel[t], lcnt[t]);
  __syncthreads();
  for (int k = t; k < cnt; k += 256) {
    int key = key_arr[e0 + k];
    int pay = pay_arr[e0 + k];
    int b = key >> SH;
    int r = atomicAdd(&lcnt2[b], 1);
    sstage[lscan[b] + r] = ((uint32_t)pay << 16) | (uint32_t)key;
  }
  __syncthreads();
  for (int b = 0; b < NB; ++b) {
    int len = lcnt[b], ls = lscan[b], gb = gbase[b];
    for (int k = t; k < len; k += 256) stg[gb + k] = sstage[ls + k];
  }
}

__global__ __launch_bounds__(256) void binA_kernel(
    const int* __restrict__ src, const int* __restrict__ dst,
    const int* __restrict__ he_node, const int* __restrict__ he_edge,
    const int* __restrict__ gbb, int* brel,
    uint32_t* stg_adj, uint32_t* stg_heg, uint32_t* stg_hng) {
  int b = blockIdx.x;
  if (b < 196)      binA_section<98, 9>(dst, src, N_EDGE, b, gbb, brel, stg_adj);
  else if (b < 294) binA_section<79, 6>(he_edge, he_node, N_INC, b - 196, gbb + 99, brel + 98, stg_heg);
  else              binA_section<98, 9>(he_node, he_edge, N_INC, b - 294, gbb + 179, brel + 177, stg_hng);
}

// Pass B + per-node count/scan: writes CSR offsets, reciprocal scales, payloads.
template <int BS, int SH, int MODE>
__device__ inline void binB2_section(int bkt, const int* __restrict__ bb, int nkeys,
                                     const uint32_t* __restrict__ stg,
                                     int* __restrict__ off_out,
                                     float* __restrict__ scl,
                                     uint16_t* __restrict__ out) {
  __shared__ int lcnt[512], loff[512], lcur[512];
  __shared__ int ws[4];
  int t = threadIdx.x;
  int nb0 = bkt << SH;
  int nb1 = min(nb0 + BS, nkeys);
  int nn = nb1 - nb0;
  int e0 = bb[bkt], e1 = bb[bkt + 1];
  for (int k = t; k < nn; k += 256) lcnt[k] = 0;
  __syncthreads();
  for (int e = e0 + t; e < e1; e += 256)
    atomicAdd(&lcnt[(int)(stg[e] & 0xFFFFu) - nb0], 1);
  __syncthreads();
  // exclusive scan over nn counts (2 per thread, shfl within wave, 4 waves)
  int lane = t & 63, wv = t >> 6;
  int i0 = 2 * t;
  int a0 = (i0 < nn) ? lcnt[i0] : 0;
  int a1 = (i0 + 1 < nn) ? lcnt[i0 + 1] : 0;
  int ts = a0 + a1;
  int val = ts;
#pragma unroll
  for (int d = 1; d < 64; d <<= 1) {
    int x = __shfl_up(val, d);
    if (lane >= d) val += x;
  }
  if (lane == 63) ws[wv] = val;
  __syncthreads();
  if (t == 0) {
    int s = 0;
#pragma unroll
    for (int w = 0; w < 4; ++w) { int v = ws[w]; ws[w] = s; s += v; }
  }
  __syncthreads();
  int excl = ws[wv] + (val - ts);
  if (i0 < nn) loff[i0] = excl;
  if (i0 + 1 < nn) loff[i0 + 1] = excl + a0;
  __syncthreads();
  for (int k = t; k < nn; k += 256) {
    int base = e0 + loff[k];
    off_out[nb0 + k] = base;
    lcur[k] = base;
    int c = lcnt[k];
    scl[nb0 + k] = (MODE == 0) ? 1.0f / (float)(c > 1 ? c : 1)
                               : (c > 0 ? 1.0f / (float)c : 0.f);
  }
  __syncthreads();
  for (int e = e0 + t; e < e1; e += 256) {
    uint32_t v = stg[e];
    int key = (int)(v & 0xFFFFu);
    int p = atomicAdd(&lcur[key - nb0], 1);
    out[p] = (uint16_t)(v >> 16);
  }
}

__global__ __launch_bounds__(256) void binB2_kernel(
    const int* __restrict__ gbb,
    const uint32_t* __restrict__ stg_adj, const uint32_t* __restrict__ stg_heg,
    const uint32_t* __restrict__ stg_hng,
    int* adj_off, int* heg_off, int* hng_off,
    float* deg_inv, float* binv, float* dinv,
    uint16_t* adj_src, uint16_t* heg_node, uint16_t* hng_edge) {
  int b = blockIdx.x;
  if (b < 98)       binB2_section<512, 9, 0>(b, gbb, N_NODES, stg_adj, adj_off, deg_inv, adj_src);
  else if (b < 177) binB2_section<64, 6, 1>(b - 98, gbb + 99, N_HE, stg_heg, heg_off, binv, heg_node);
  else              binB2_section<512, 9, 1>(b - 177, gbb + 179, N_NODES, stg_hng, hng_off, dinv, hng_edge);
}

// ------------------------------- gather-mean row body (uint16 CSR idx)
template <int F>
__device__ inline void agg_row(const int* __restrict__ off, const uint16_t* __restrict__ idx,
                               const float* __restrict__ scale,
                               const uint16_t* __restrict__ X,
                               uint16_t* __restrict__ OUT, int row,
                               const float* __restrict__ bias, int do_relu) {
  constexpr int VEC = (F >= 256) ? 4 : 2;
  int t = threadIdx.x;
  if (t * VEC >= F) return;
  int j0 = off[row], j1 = off[row + 1];
  float sc = scale[row];
  float acc[VEC];
#pragma unroll
  for (int k = 0; k < VEC; ++k) acc[k] = 0.f;

  int j = j0;
  for (; j + 7 < j1; j += 8) {
    int s[8];
#pragma unroll
    for (int u = 0; u < 8; ++u) s[u] = idx[j + u];
    if (VEC == 4) {
      v4u v[8];
#pragma unroll
      for (int u = 0; u < 8; ++u) v[u] = *(const v4u*)(X + (size_t)s[u] * F + t * 4);
#pragma unroll
      for (int u = 0; u < 8; ++u)
#pragma unroll
        for (int k = 0; k < 4; ++k) acc[k] += bfh(v[u][k]);
    } else {
      v2u v[8];
#pragma unroll
      for (int u = 0; u < 8; ++u) v[u] = *(const v2u*)(X + (size_t)s[u] * F + t * 2);
#pragma unroll
      for (int u = 0; u < 8; ++u)
#pragma unroll
        for (int k = 0; k < 2; ++k) acc[k] += bfh(v[u][k]);
    }
  }
  for (; j < j1; ++j) {
    int s = idx[j];
    if (VEC == 4) {
      v4u a = *(const v4u*)(X + (size_t)s * F + t * 4);
#pragma unroll
      for (int k = 0; k < 4; ++k) acc[k] += bfh(a[k]);
    } else {
      v2u a = *(const v2u*)(X + (size_t)s * F + t * 2);
#pragma unroll
      for (int k = 0; k < 2; ++k) acc[k] += bfh(a[k]);
    }
  }

  if (VEC == 4) {
    v4u o;
#pragma unroll
    for (int k = 0; k < 4; ++k) {
      float v = acc[k] * sc;
      if (bias) { v += bias[t * 4 + k]; if (do_relu) v = fmaxf(v, 0.f); }
      o[k] = rne16(v);
    }
    *(v4u*)(OUT + (size_t)row * F + t * 4) = o;
  } else {
    v2u o;
#pragma unroll
    for (int k = 0; k < 2; ++k) {
      float v = acc[k] * sc;
      if (bias) { v += bias[t * 2 + k]; if (do_relu) v = fmaxf(v, 0.f); }
      o[k] = rne16(v);
    }
    *(v2u*)(OUT + (size_t)row * F + t * 2) = o;
  }
}

template <int F>
__global__ void aggb_kernel(const int* __restrict__ off, const uint16_t* __restrict__ idx,
                            const float* __restrict__ scale,
                            const uint16_t* __restrict__ X,
                            uint16_t* __restrict__ OUT,
                            const float* __restrict__ bias, int do_relu) {
  agg_row<F>(off, idx, scale, X, OUT, blockIdx.x, bias, do_relu);
}

template <int F>
__global__ void agg2b_kernel(const int* __restrict__ off1, const uint16_t* __restrict__ idx1,
                             const float* __restrict__ sc1, uint16_t* __restrict__ OUT1, int n1,
                             const int* __restrict__ off2, const uint16_t* __restrict__ idx2,
                             const float* __restrict__ sc2, uint16_t* __restrict__ OUT2,
                             const uint16_t* __restrict__ X) {
  int row = blockIdx.x;
  if (row < n1) agg_row<F>(off1, idx1, sc1, X, OUT1, row, nullptr, 0);
  else          agg_row<F>(off2, idx2, sc2, X, OUT2, row - n1, nullptr, 0);
}

// Hyper tail: XCATB[:,40:80] = bf16(dinv*agg(EF40) + bias); zeros pad 80:96.
__global__ void agg40b_kernel(const int* __restrict__ off, const uint16_t* __restrict__ idx,
                              const float* __restrict__ scale,
                              const uint16_t* __restrict__ EF40,
                              const float* __restrict__ bias,
                              uint16_t* __restrict__ XCATB) {
  int row = blockIdx.x;
  int t = threadIdx.x;
  if (t < 8) {
    v2u z = {0, 0};
    *(v2u*)(XCATB + (size_t)row * 96 + 80 + t * 2) = z;
  }
  if (t >= 20) return;
  int j0 = off[row], j1 = off[row + 1];
  float sc = scale[row];
  float a0 = 0.f, a1 = 0.f;
  for (int j = j0; j < j1; ++j) {
    int s = idx[j];
    v2u v = *(const v2u*)(EF40 + (size_t)s * 40 + t * 2);
    a0 += bfh(v[0]);
    a1 += bfh(v[1]);
  }
  v2u o;
  o[0] = rne16(a0 * sc + bias[t * 2]);
  o[1] = rne16(a1 * sc + bias[t * 2 + 1]);
  *(v2u*)(XCATB + (size_t)row * 96 + 40 + t * 2) = o;
}

// SAGE tail: XCATB[:, :40] = bf16(deg_inv*agg(T40a) + T40b)
__global__ void agg40s_kernel(const int* __restrict__ off, const uint16_t* __restrict__ idx,
                              const float* __restrict__ scale,
                              const uint16_t* __restrict__ T40a,
                              const uint16_t* __restrict__ T40b,
                              uint16_t* __restrict__ XCATB) {
  int row = blockIdx.x;
  int t = threadIdx.x;
  if (t >= 20) return;
  int j0 = off[row], j1 = off[row + 1];
  float sc = scale[row];
  float a0 = 0.f, a1 = 0.f;
  for (int j = j0; j < j1; ++j) {
    int s = idx[j];
    v2u v = *(const v2u*)(T40a + (size_t)s * 40 + t * 2);
    a0 += bfh(v[0]);
    a1 += bfh(v[1]);
  }
  v2u b = *(const v2u*)(T40b + (size_t)row * 40 + t * 2);
  v2u o;
  o[0] = rne16(a0 * sc + bfh(b[0]));
  o[1] = rne16(a1 * sc + bfh(b[1]));
  *(v2u*)(XCATB + (size_t)row * 96 + t * 2) = o;
}

// ------------------------------------- bf16-A, split-W LDS-staged MFMA GEMM
// A/B frag: row|col = lane&15, k = (lane>>4)*8+j.  C/D: col = lane&15,
// row = (lane>>4)*4 + reg  (verified gfx950 mappings).
template <int K1, int K2, int F, bool OUTBF>
__global__ __launch_bounds__(256, 4) void lin2b_kernel(
    const uint16_t* __restrict__ X1, const uint16_t* __restrict__ W1h, const uint16_t* __restrict__ W1l,
    const uint16_t* __restrict__ X2, const uint16_t* __restrict__ W2h, const uint16_t* __restrict__ W2l,
    const float* __restrict__ bias, const uint16_t* __restrict__ addin,
    void* __restrict__ OUTP, int out_ld, int N, int do_relu) {
  constexpr int FP  = (F + 15) & ~15;
  constexpr int NF  = FP / 16;
  constexpr int NC1 = K1 / 32;
  constexpr int NCH = (K1 + (K2 > 0 ? K2 : 0)) / 32;
  constexpr int RS  = 40;
  __shared__ short sW[2][FP][RS];

  int tid  = threadIdx.x;
  int wave = tid >> 6, lane = tid & 63;
  int r = lane & 15, q = lane >> 4;
  int row0 = blockIdx.x * 64 + wave * 16;
  int rowA = row0 + r; if (rowA > N - 1) rowA = N - 1;

  int srow = tid >> 2;
  int sj   = tid & 3;

  v4f acc[NF];
#pragma unroll
  for (int i = 0; i < NF; ++i) acc[i] = (v4f){0.f, 0.f, 0.f, 0.f};

  for (int c = 0; c < NCH; ++c) {
    const bool first = (K2 == 0) || (c < NC1);
    const uint16_t* Wh = first ? W1h : W2h;
    const uint16_t* Wl = first ? W1l : W2l;
    const uint16_t* Xs = first ? X1 : X2;
    const int K  = first ? K1 : K2;
    const int kc = (first ? c : c - NC1) * 32;

    if (c) __syncthreads();
    const v8s zz = {0, 0, 0, 0, 0, 0, 0, 0};
#pragma unroll
    for (int pass = 0; pass < (FP + 63) / 64; ++pass) {
      int row = srow + pass * 64;
      if (row < FP) {
        v8s hv = zz, lv = zz;
        if (row < F) {
          hv = *reinterpret_cast<const v8s*>(Wh + (size_t)row * K + kc + sj * 8);
          lv = *reinterpret_cast<const v8s*>(Wl + (size_t)row * K + kc + sj * 8);
        }
        *reinterpret_cast<v8s*>(&sW[0][row][sj * 8]) = hv;
        *reinterpret_cast<v8s*>(&sW[1][row][sj * 8]) = lv;
      }
    }
    v8s ah = *reinterpret_cast<const v8s*>(Xs + (size_t)rowA * K + kc + q * 8);
    __syncthreads();
#pragma unroll
    for (int ft = 0; ft < NF; ++ft) {
      v8s bh = *reinterpret_cast<const v8s*>(&sW[0][ft * 16 + r][q * 8]);
      v8s bl = *reinterpret_cast<const v8s*>(&sW[1][ft * 16 + r][q * 8]);
      acc[ft] = __builtin_amdgcn_mfma_f32_16x16x32_bf16(ah, bh, acc[ft], 0, 0, 0);
      acc[ft] = __builtin_amdgcn_mfma_f32_16x16x32_bf16(ah, bl, acc[ft], 0, 0, 0);
    }
  }

#pragma unroll
  for (int ft = 0; ft < NF; ++ft) {
    int col = ft * 16 + r;
    if (col < F) {
      float bv = bias ? bias[col] : 0.f;
#pragma unroll
      for (int i = 0; i < 4; ++i) {
        int row = row0 + q * 4 + i;
        if (row < N) {
          float v = acc[ft][i] + bv;
          if (addin) v += bfh(addin[(size_t)row * F + col]);
          if (do_relu) v = fmaxf(v, 0.f);
          size_t o = (size_t)row * out_ld + col;
          if (OUTBF) ((uint16_t*)OUTP)[o] = rne16(v);
          else ((float*)OUTP)[o] = v;
        }
      }
    }
  }
}

// Dual-output 40-col GEMM (K=256): OUT1 = X*W1^T, OUT2 = X*W2^T + b2.
__global__ __launch_bounds__(256, 4) void lin40ab_kernel(
    const uint16_t* __restrict__ X,
    const uint16_t* __restrict__ W1h, const uint16_t* __restrict__ W1l,
    const uint16_t* __restrict__ W2h, const uint16_t* __restrict__ W2l,
    const float* __restrict__ bias2,
    uint16_t* __restrict__ OUT1, uint16_t* __restrict__ OUT2, int N) {
  constexpr int K = 256, F = 40, FP = 48, NF = 3, RS = 40;
  __shared__ short sW[2][2][FP][RS];

  int tid  = threadIdx.x;
  int wave = tid >> 6, lane = tid & 63;
  int r = lane & 15, q = lane >> 4;
  int row0 = blockIdx.x * 64 + wave * 16;
  int rowA = row0 + r; if (rowA > N - 1) rowA = N - 1;
  int srow = tid >> 2, sj = tid & 3;

  v4f acc[2][NF];
#pragma unroll
  for (int w = 0; w < 2; ++w)
#pragma unroll
    for (int i = 0; i < NF; ++i) acc[w][i] = (v4f){0.f, 0.f, 0.f, 0.f};

  for (int c = 0; c < K / 32; ++c) {
    int kc = c * 32;
    if (c) __syncthreads();
    if (srow < FP) {
      const v8s zz = {0, 0, 0, 0, 0, 0, 0, 0};
      v8s a = zz, b = zz, cc = zz, d = zz;
      if (srow < F) {
        a  = *reinterpret_cast<const v8s*>(W1h + (size_t)srow * K + kc + sj * 8);
        b  = *reinterpret_cast<const v8s*>(W1l + (size_t)srow * K + kc + sj * 8);
        cc = *reinterpret_cast<const v8s*>(W2h + (size_t)srow * K + kc + sj * 8);
        d  = *reinterpret_cast<const v8s*>(W2l + (size_t)srow * K + kc + sj * 8);
      }
      *reinterpret_cast<v8s*>(&sW[0][0][srow][sj * 8]) = a;
      *reinterpret_cast<v8s*>(&sW[0][1][srow][sj * 8]) = b;
      *reinterpret_cast<v8s*>(&sW[1][0][srow][sj * 8]) = cc;
      *reinterpret_cast<v8s*>(&sW[1][1][srow][sj * 8]) = d;
    }
    v8s ah = *reinterpret_cast<const v8s*>(X + (size_t)rowA * K + kc + q * 8);
    __syncthreads();
#pragma unroll
    for (int w = 0; w < 2; ++w)
#pragma unroll
      for (int ft = 0; ft < NF; ++ft) {
        v8s bh = *reinterpret_cast<const v8s*>(&sW[w][0][ft * 16 + r][q * 8]);
        v8s bl = *reinterpret_cast<const v8s*>(&sW[w][1][ft * 16 + r][q * 8]);
        acc[w][ft] = __builtin_amdgcn_mfma_f32_16x16x32_bf16(ah, bh, acc[w][ft], 0, 0, 0);
        acc[w][ft] = __builtin_amdgcn_mfma_f32_16x16x32_bf16(ah, bl, acc[w][ft], 0, 0, 0);
      }
  }

#pragma unroll
  for (int ft = 0; ft < NF; ++ft) {
    int col = ft * 16 + r;
    if (col < F) {
      float bv = bias2[col];
#pragma unroll
      for (int i = 0; i < 4; ++i) {
        int row = row0 + q * 4 + i;
        if (row < N) {
          OUT1[(size_t)row * F + col] = rne16(acc[0][ft][i]);
          OUT2[(size_t)row * F + col] = rne16(acc[1][ft][i] + bv);
        }
      }
    }
  }
}

// ---------------- final: MFMA GEMM (K=96, F=40) + fused log-softmax
__global__ __launch_bounds__(256, 4) void final_mfma_kernel(
    const uint16_t* __restrict__ XB96,
    const uint16_t* __restrict__ Wh, const uint16_t* __restrict__ Wl,
    const float* __restrict__ lpb, float* __restrict__ out, int N) {
  constexpr int K = 96, F = 40, FP = 48, NF = 3, RS = 40;
  __shared__ short sW[2][FP][RS];

  int tid  = threadIdx.x;
  int wave = tid >> 6, lane = tid & 63;
  int r = lane & 15, q = lane >> 4;
  int row0 = blockIdx.x * 64 + wave * 16;
  int rowA = row0 + r; if (rowA > N - 1) rowA = N - 1;
  int srow = tid >> 2, sj = tid & 3;

  v4f acc[NF];
#pragma unroll
  for (int i = 0; i < NF; ++i) acc[i] = (v4f){0.f, 0.f, 0.f, 0.f};

  for (int c = 0; c < 3; ++c) {
    int kc = c * 32;
    if (c) __syncthreads();
    if (srow < FP) {
      const v8s zz = {0, 0, 0, 0, 0, 0, 0, 0};
      v8s hv = zz, lv = zz;
      if (srow < F) {
        hv = *reinterpret_cast<const v8s*>(Wh + (size_t)srow * K + kc + sj * 8);
        lv = *reinterpret_cast<const v8s*>(Wl + (size_t)srow * K + kc + sj * 8);
      }
      *reinterpret_cast<v8s*>(&sW[0][srow][sj * 8]) = hv;
      *reinterpret_cast<v8s*>(&sW[1][srow][sj * 8]) = lv;
    }
    v8s ah = *reinterpret_cast<const v8s*>(XB96 + (size_t)rowA * K + kc + q * 8);
    __syncthreads();
#pragma unroll
    for (int ft = 0; ft < NF; ++ft) {
      v8s bh = *reinterpret_cast<const v8s*>(&sW[0][ft * 16 + r][q * 8]);
      v8s bl = *reinterpret_cast<const v8s*>(&sW[1][ft * 16 + r][q * 8]);
      acc[ft] = __builtin_amdgcn_mfma_f32_16x16x32_bf16(ah, bh, acc[ft], 0, 0, 0);
      acc[ft] = __builtin_amdgcn_mfma_f32_16x16x32_bf16(ah, bl, acc[ft], 0, 0, 0);
    }
  }

  float b0 = lpb[r], b1 = lpb[16 + r];
  float b2 = (r < 8) ? lpb[32 + r] : 0.f;
#pragma unroll
  for (int i = 0; i < 4; ++i) {
    int row = row0 + q * 4 + i;
    float l0 = acc[0][i] + b0;
    float l1 = acc[1][i] + b1;
    float l2 = (r < 8) ? (acc[2][i] + b2) : -1e30f;
    float m = fmaxf(fmaxf(l0, l1), l2);
#pragma unroll
    for (int d = 1; d < 16; d <<= 1) m = fmaxf(m, __shfl_xor(m, d));
    float e = __expf(l0 - m) + __expf(l1 - m) + ((r < 8) ? __expf(l2 - m) : 0.f);
#pragma unroll
    for (int d = 1; d < 16; d <<= 1) e += __shfl_xor(e, d);
    if (row < N) {
      float ls = m + __logf(e);
      out[(size_t)row * 40 + r]      = l0 - ls;
      out[(size_t)row * 40 + 16 + r] = l1 - ls;
      if (r < 8) out[(size_t)row * 40 + 32 + r] = l2 - ls;
    }
  }
}

// ---------------------------------------------------------------- launcher
extern "C" void kernel_launch(void* const* d_in, const int* in_sizes, int n_in,
                              void* d_out, int out_size, void* d_ws, size_t ws_size,
                              hipStream_t stream) {
  const float* x      = (const float*)d_in[0];
  const int* src      = (const int*)d_in[1];
  const int* dst      = (const int*)d_in[2];
  const int* he_node  = (const int*)d_in[3];
  const int* he_edge  = (const int*)d_in[4];
  const float* s0wl = (const float*)d_in[5],  *s0wr = (const float*)d_in[6],  *s0b = (const float*)d_in[7];
  const float* s1wl = (const float*)d_in[8],  *s1wr = (const float*)d_in[9],  *s1b = (const float*)d_in[10];
  const float* s2wl = (const float*)d_in[11], *s2wr = (const float*)d_in[12], *s2b = (const float*)d_in[13];
  const float* h0w = (const float*)d_in[14], *h0b = (const float*)d_in[15];
  const float* h1w = (const float*)d_in[16], *h1b = (const float*)d_in[17];
  const float* h2w = (const float*)d_in[18], *h2b = (const float*)d_in[19];
  const float* h3w = (const float*)d_in[20], *h3b = (const float*)d_in[21];
  const float* h4w = (const float*)d_in[22], *h4b = (const float*)d_in[23];
  const float* lpw = (const float*)d_in[24], *lpb = (const float*)d_in[25];
  float* out = (float*)d_out;

  char* p = (char*)d_ws;
  auto carve = [&](size_t bytes) -> char* {
    char* r = p;
    p += (bytes + 255) & ~(size_t)255;
    return r;
  };
  int* adj_off  = (int*)carve((size_t)(N_NODES + 1) * 4);
  uint16_t* adj_src  = (uint16_t*)carve((size_t)N_EDGE * 2);
  int* heg_off  = (int*)carve((size_t)(N_HE + 1) * 4);
  uint16_t* heg_node = (uint16_t*)carve((size_t)N_INC * 2);
  int* hng_off  = (int*)carve((size_t)(N_NODES + 1) * 4);
  uint16_t* hng_edge = (uint16_t*)carve((size_t)N_INC * 2);
  int* gcnt     = (int*)carve((size_t)NBREL * 4);
  int* brel     = (int*)carve((size_t)NBREL * 4);
  int* gbb      = (int*)carve((size_t)278 * 4);
  uint32_t* stg_adj = (uint32_t*)carve((size_t)N_EDGE * 4);
  uint32_t* stg_heg = (uint32_t*)carve((size_t)N_INC * 4);
  uint32_t* stg_hng = (uint32_t*)carve((size_t)N_INC * 4);
  float* deg_inv = (float*)carve((size_t)N_NODES * 4);
  float* binv    = (float*)carve((size_t)N_HE * 4);
  float* dinv    = (float*)carve((size_t)N_NODES * 4);
  uint16_t* Wh = (uint16_t*)carve((size_t)W_TOTAL * 2);
  uint16_t* Wl = (uint16_t*)carve((size_t)W_TOTAL * 2);
  uint16_t* lpWh = (uint16_t*)carve((size_t)40 * 96 * 2);
  uint16_t* lpWl = (uint16_t*)carve((size_t)40 * 96 * 2);
  uint16_t* XB = (uint16_t*)carve((size_t)N_NODES * 128 * 2);
  uint16_t* U  = (uint16_t*)carve((size_t)N_NODES * 128 * 2);
  uint16_t* NA = (uint16_t*)carve((size_t)N_NODES * 256 * 2);
  uint16_t* NB_ = (uint16_t*)carve((size_t)N_NODES * 256 * 2);
  uint16_t* NC = (uint16_t*)carve((size_t)N_NODES * 256 * 2);
  uint16_t* EFa = (uint16_t*)carve((size_t)N_HE * 256 * 2);
  uint16_t* EFb = (uint16_t*)carve((size_t)N_HE * 256 * 2);
  uint16_t* T40 = (uint16_t*)carve((size_t)N_NODES * 40 * 2);
  uint16_t* T40B = (uint16_t*)carve((size_t)N_NODES * 40 * 2);
  uint16_t* T40H = (uint16_t*)carve((size_t)N_NODES * 40 * 2);
  uint16_t* XCATB = (uint16_t*)carve((size_t)N_NODES * 96 * 2);

  const int GL = (N_NODES + 63) / 64;
  const int GS = (N_HE + 63) / 64;

  // ---- prep (zero + weight split + lpw split + x cvt) and binned CSR build
  prep_kernel<<<8052, 256, 0, stream>>>(gcnt, brel,
                                        s0wl, s0wr, s1wl, s1wr, s2wl, s2wr,
                                        h0w, h1w, h2w, h3w, h4w, Wh, Wl,
                                        lpw, lpWh, lpWl, x, XB);
  bhist_kernel<<<392, 256, 0, stream>>>(dst, he_edge, he_node, gcnt);
  bscan_kernel<<<1, 256, 0, stream>>>(gcnt, gbb, adj_off, heg_off, hng_off);
  binA_kernel<<<392, 256, 0, stream>>>(src, dst, he_node, he_edge,
                                       gbb, brel, stg_adj, stg_heg, stg_hng);
  binB2_kernel<<<275, 256, 0, stream>>>(gbb, stg_adj, stg_heg, stg_hng,
                                        adj_off, heg_off, hng_off,
                                        deg_inv, binv, dinv,
                                        adj_src, heg_node, hng_edge);

  // ---- merged layer-0 gathers (SAGE node-agg + hyper he-agg, both from XB)
  agg2b_kernel<128><<<N_NODES + N_HE, 64, 0, stream>>>(
      adj_off, adj_src, deg_inv, U, N_NODES,
      heg_off, heg_node, binv, EFa, XB);

  // ---- SAGE branch
  lin2b_kernel<128, 128, 256, true><<<GL, 256, 0, stream>>>(
      U, Wh + 0, Wl + 0, XB, Wh + 32768, Wl + 32768, s0b, nullptr, NA, 256, N_NODES, 1);
  aggb_kernel<256><<<N_NODES, 64, 0, stream>>>(adj_off, adj_src, deg_inv, NA, NB_, nullptr, 0);
  lin2b_kernel<256, 256, 256, true><<<GL, 256, 0, stream>>>(
      NB_, Wh + 65536, Wl + 65536, NA, Wh + 131072, Wl + 131072, s1b, nullptr, NC, 256, N_NODES, 1);
  lin40ab_kernel<<<GL, 256, 0, stream>>>(
      NC, Wh + 196608, Wl + 196608, Wh + 206848, Wl + 206848, s2b, T40, T40B, N_NODES);
  agg40s_kernel<<<N_NODES, 64, 0, stream>>>(adj_off, adj_src, deg_inv, T40, T40B, XCATB);

  // ---- Hypergraph branch: heagg -> tiny GEMM (5000 rows) -> nodeagg+bias+relu
  lin2b_kernel<128, 0, 256, true><<<GS, 256, 0, stream>>>(
      EFa, Wh + 217088, Wl + 217088, nullptr, nullptr, nullptr, nullptr, nullptr, EFb, 256, N_HE, 0);
  aggb_kernel<256><<<N_NODES, 64, 0, stream>>>(hng_off, hng_edge, dinv, EFb, NC, h0b, 1);

  aggb_kernel<256><<<N_HE, 64, 0, stream>>>(heg_off, heg_node, binv, NC, EFa, nullptr, 0);
  lin2b_kernel<256, 0, 256, true><<<GS, 256, 0, stream>>>(
      EFa, Wh + 249856, Wl + 249856, nullptr, nullptr, nullptr, nullptr, nullptr, EFb, 256, N_HE, 0);
  aggb_kernel<256><<<N_NODES, 64, 0, stream>>>(hng_off, hng_edge, dinv, EFb, NC, h1b, 1);

  aggb_kernel<256><<<N_HE, 64, 0, stream>>>(heg_off, heg_node, binv, NC, EFa, nullptr, 0);
  lin2b_kernel<256, 0, 256, true><<<GS, 256, 0, stream>>>(
      EFa, Wh + 315392, Wl + 315392, nullptr, nullptr, nullptr, nullptr, nullptr, EFb, 256, N_HE, 0);
  aggb_kernel<256><<<N_NODES, 64, 0, stream>>>(hng_off, hng_edge, dinv, EFb, NC, h2b, 1);

  aggb_kernel<256><<<N_HE, 64, 0, stream>>>(heg_off, heg_node, binv, NC, EFa, nullptr, 0);
  lin2b_kernel<256, 0, 256, true><<<GS, 256, 0, stream>>>(
      EFa, Wh + 380928, Wl + 380928, nullptr, nullptr, nullptr, nullptr, nullptr, EFb, 256, N_HE, 0);
  aggb_kernel<256><<<N_NODES, 64, 0, stream>>>(hng_off, hng_edge, dinv, EFb, NC, h3b, 1);

  // layer 4 (F=40): transform node features first, then two aggs
  lin2b_kernel<256, 0, 40, true><<<GL, 256, 0, stream>>>(
      NC, Wh + 446464, Wl + 446464, nullptr, nullptr, nullptr, nullptr, nullptr, T40H, 40, N_NODES, 0);
  aggb_kernel<40><<<N_HE, 64, 0, stream>>>(heg_off, heg_node, binv, T40H, EFa, nullptr, 0);
  agg40b_kernel<<<N_NODES, 64, 0, stream>>>(hng_off, hng_edge, dinv, EFa, h4b, XCATB);

  // ---- final MFMA linear + fused log_softmax
  final_mfma_kernel<<<GL, 256, 0, stream>>>(XCATB, lpWh, lpWl, lpb, out, N_NODES);
}